// Round 1
// baseline (42427.725 us; speedup 1.0000x reference)
//
#include <hip/hip_runtime.h>
#include <math.h>

#define NNODES 10000
#define NEDGES 160000
#define DIM    256
#define BATCH  4

__device__ __forceinline__ float leakyf(float x){ return x > 0.f ? x : 0.01f*x; }
__device__ __forceinline__ float sigmoidf_(float x){ return 1.f/(1.f+expf(-x)); }

// out[k*F + f] = in[f*K + k]
__global__ void transpose_kernel(const float* __restrict__ in, float* __restrict__ out, int F, int K){
  int idx = blockIdx.x*256 + threadIdx.x;
  if (idx < F*K){ int k = idx / F, f = idx - k*F; out[idx] = in[(size_t)f*K + k]; }
}

// Fused gather -> (leaky(G@W1^T+b1))@W2^T+b2 -> atomic scatter-add.
// Block: 256 threads, 32 edges x 256 features. Wt pre-transposed to [k][f].
__global__ __launch_bounds__(256) void edge_kernel(
    const float* __restrict__ h, const int* __restrict__ edges,
    const float* __restrict__ wt1, const float* __restrict__ wt2,
    const float* __restrict__ eb1, const float* __restrict__ eb2,
    float* __restrict__ incoming)
{
  __shared__ float As[32*17];     // [edge][k] pad 17
  __shared__ float Ws[16*256];    // [kk][f]
  __shared__ float Y1[32*260];    // [edge][f] pad 260
  __shared__ int srcs[32];
  __shared__ int dsts[32];

  const int si = blockIdx.y;
  const int r0 = blockIdx.x * 32;          // row in [0, B*E)
  const int b  = r0 / NEDGES;
  const int e0 = r0 - b*NEDGES;
  const int t  = threadIdx.x;
  const int tx = t & 15, ty = t >> 4;

  if (t < 32){
    const int* ep = edges + ((size_t)((b*2 + si)*(size_t)NEDGES + e0 + t))*2;
    dsts[t] = ep[0];
    srcs[t] = ep[1];
  }
  __syncthreads();

  const int le = t >> 3, kload = (t & 7)*2;
  const float* arow = h + ((size_t)b*NNODES + srcs[le])*DIM + kload;
  const float* wt   = wt1 + si*(DIM*DIM);

  float4 acc0[4], acc1[4];
  #pragma unroll
  for (int i=0;i<4;i++){ acc0[i]=make_float4(0.f,0.f,0.f,0.f); acc1[i]=make_float4(0.f,0.f,0.f,0.f); }

  // ---- layer 1 ----
  for (int k0=0;k0<DIM;k0+=16){
    __syncthreads();
    As[le*17+kload]   = arow[k0];
    As[le*17+kload+1] = arow[k0+1];
    #pragma unroll
    for (int i=0;i<4;i++){
      int q = t + i*256; int kk = q >> 6; int f = (q & 63)*4;
      *(float4*)&Ws[kk*256+f] = *(const float4*)&wt[(size_t)(k0+kk)*DIM + f];
    }
    __syncthreads();
    #pragma unroll
    for (int kk=0;kk<16;kk++){
      float x0 = As[(2*ty)*17+kk], x1 = As[(2*ty+1)*17+kk];
      #pragma unroll
      for (int i=0;i<4;i++){
        float4 w = *(float4*)&Ws[kk*256 + tx*4 + 64*i];
        acc0[i].x += x0*w.x; acc0[i].y += x0*w.y; acc0[i].z += x0*w.z; acc0[i].w += x0*w.w;
        acc1[i].x += x1*w.x; acc1[i].y += x1*w.y; acc1[i].z += x1*w.z; acc1[i].w += x1*w.w;
      }
    }
  }
  // bias + leaky -> Y1
  {
    const float* bias = eb1 + si*DIM;
    #pragma unroll
    for (int i=0;i<4;i++){
      int f = tx*4 + 64*i;
      float4 bb = *(const float4*)&bias[f];
      float4 v0, v1;
      v0.x = leakyf(acc0[i].x+bb.x); v0.y = leakyf(acc0[i].y+bb.y);
      v0.z = leakyf(acc0[i].z+bb.z); v0.w = leakyf(acc0[i].w+bb.w);
      v1.x = leakyf(acc1[i].x+bb.x); v1.y = leakyf(acc1[i].y+bb.y);
      v1.z = leakyf(acc1[i].z+bb.z); v1.w = leakyf(acc1[i].w+bb.w);
      *(float4*)&Y1[(2*ty)*260 + f]   = v0;
      *(float4*)&Y1[(2*ty+1)*260 + f] = v1;
    }
  }
  // ---- layer 2 ----
  wt = wt2 + si*(DIM*DIM);
  #pragma unroll
  for (int i=0;i<4;i++){ acc0[i]=make_float4(0.f,0.f,0.f,0.f); acc1[i]=make_float4(0.f,0.f,0.f,0.f); }
  for (int k0=0;k0<DIM;k0+=16){
    __syncthreads();   // Y1 writes visible before first use; Ws safe to overwrite
    #pragma unroll
    for (int i=0;i<4;i++){
      int q = t + i*256; int kk = q >> 6; int f = (q & 63)*4;
      *(float4*)&Ws[kk*256+f] = *(const float4*)&wt[(size_t)(k0+kk)*DIM + f];
    }
    __syncthreads();
    #pragma unroll
    for (int kk=0;kk<16;kk++){
      int k = k0+kk;
      float x0 = Y1[(2*ty)*260 + k], x1 = Y1[(2*ty+1)*260 + k];
      #pragma unroll
      for (int i=0;i<4;i++){
        float4 w = *(float4*)&Ws[kk*256 + tx*4 + 64*i];
        acc0[i].x += x0*w.x; acc0[i].y += x0*w.y; acc0[i].z += x0*w.z; acc0[i].w += x0*w.w;
        acc1[i].x += x1*w.x; acc1[i].y += x1*w.y; acc1[i].z += x1*w.z; acc1[i].w += x1*w.w;
      }
    }
  }
  // scatter-add
  {
    const float* bias = eb2 + si*DIM;
    const int d0 = dsts[2*ty], d1 = dsts[2*ty+1];
    float* o0 = incoming + ((size_t)b*NNODES + d0)*DIM;
    float* o1 = incoming + ((size_t)b*NNODES + d1)*DIM;
    #pragma unroll
    for (int i=0;i<4;i++){
      int f = tx*4 + 64*i;
      float4 bb = *(const float4*)&bias[f];
      atomicAdd(&o0[f+0], acc0[i].x+bb.x); atomicAdd(&o0[f+1], acc0[i].y+bb.y);
      atomicAdd(&o0[f+2], acc0[i].z+bb.z); atomicAdd(&o0[f+3], acc0[i].w+bb.w);
      atomicAdd(&o1[f+0], acc1[i].x+bb.x); atomicAdd(&o1[f+1], acc1[i].y+bb.y);
      atomicAdd(&o1[f+2], acc1[i].z+bb.z); atomicAdd(&o1[f+3], acc1[i].w+bb.w);
    }
  }
}

// C[r][colOff+f] = A[r][:] @ Wt[:][colOff+f] + bias.  A: rows x 256, Wt: 256 x Ntot.
__global__ __launch_bounds__(256) void gemm256_kernel(
    const float* __restrict__ A, const float* __restrict__ Wt,
    const float* __restrict__ bias, float* __restrict__ C, int Ntot)
{
  __shared__ float As[32*17];
  __shared__ float Ws[16*256];
  const int colOff = blockIdx.y * 256;
  const int r0 = blockIdx.x * 32;
  const int t = threadIdx.x;
  const int tx = t & 15, ty = t >> 4;
  const int le = t >> 3, kload = (t & 7)*2;
  const float* arow = A + ((size_t)(r0 + le))*DIM + kload;

  float4 acc0[4], acc1[4];
  #pragma unroll
  for (int i=0;i<4;i++){ acc0[i]=make_float4(0.f,0.f,0.f,0.f); acc1[i]=make_float4(0.f,0.f,0.f,0.f); }

  for (int k0=0;k0<DIM;k0+=16){
    __syncthreads();
    As[le*17+kload]   = arow[k0];
    As[le*17+kload+1] = arow[k0+1];
    #pragma unroll
    for (int i=0;i<4;i++){
      int q = t + i*256; int kk = q >> 6; int f = (q & 63)*4;
      *(float4*)&Ws[kk*256+f] = *(const float4*)&Wt[(size_t)(k0+kk)*Ntot + colOff + f];
    }
    __syncthreads();
    #pragma unroll
    for (int kk=0;kk<16;kk++){
      float x0 = As[(2*ty)*17+kk], x1 = As[(2*ty+1)*17+kk];
      #pragma unroll
      for (int i=0;i<4;i++){
        float4 w = *(float4*)&Ws[kk*256 + tx*4 + 64*i];
        acc0[i].x += x0*w.x; acc0[i].y += x0*w.y; acc0[i].z += x0*w.z; acc0[i].w += x0*w.w;
        acc1[i].x += x1*w.x; acc1[i].y += x1*w.y; acc1[i].z += x1*w.z; acc1[i].w += x1*w.w;
      }
    }
  }
  #pragma unroll
  for (int i=0;i<4;i++){
    int f = tx*4 + 64*i;
    float4 bb = *(const float4*)&bias[colOff+f];
    float4 v0, v1;
    v0.x = acc0[i].x+bb.x; v0.y = acc0[i].y+bb.y; v0.z = acc0[i].z+bb.z; v0.w = acc0[i].w+bb.w;
    v1.x = acc1[i].x+bb.x; v1.y = acc1[i].y+bb.y; v1.z = acc1[i].z+bb.z; v1.w = acc1[i].w+bb.w;
    *(float4*)&C[((size_t)(r0+2*ty))*Ntot + colOff + f]   = v0;
    *(float4*)&C[((size_t)(r0+2*ty+1))*Ntot + colOff + f] = v1;
  }
}

__global__ void gate_kernel(const float* __restrict__ gi, const float* __restrict__ gh,
                            float* __restrict__ hrow)
{
  int idx = blockIdx.x*256 + threadIdx.x;
  int r = idx >> 8, d = idx & 255;
  size_t base = (size_t)r*768;
  float ir = gi[base + d];
  float iz = gi[base + 256 + d];
  float inn= gi[base + 512 + d];
  float hr = gh[base + d];
  float hz = gh[base + 256 + d];
  float hn = gh[base + 512 + d];
  float hv = hrow[idx];
  float rg = sigmoidf_(ir+hr);
  float zg = sigmoidf_(iz+hz);
  float ng = tanhf(inn + rg*hn);
  hrow[idx] = (1.f-zg)*ng + zg*hv;
}

__global__ void reduce_kernel(const float* __restrict__ h, float* __restrict__ sbuf){
  int b  = blockIdx.x / 50;
  int s0 = (blockIdx.x % 50) * 200;
  int d  = threadIdx.x;
  const float* p = h + ((size_t)b*NNODES + s0)*DIM + d;
  float acc = 0.f;
  for (int i=0;i<200;i++) acc += p[(size_t)i*DIM];
  atomicAdd(&sbuf[b*DIM + d], acc);
}

__global__ __launch_bounds__(320) void head_kernel(
    const float* __restrict__ sbuf, const float* __restrict__ pt,
    const float* __restrict__ fc1w, const float* __restrict__ fc1b,
    const float* __restrict__ fc2w, const float* __restrict__ fc2b,
    const float* __restrict__ fc3w, const float* __restrict__ fc3b,
    float* __restrict__ out)
{
  __shared__ float L[4][257];
  __shared__ float T1[4][80];
  __shared__ float T2[4][80];
  __shared__ float fmx[4];
  int t = threadIdx.x;
  if (t < 256){
    for (int b=0;b<4;b++){
      float v = sbuf[b*DIM + t];
      float ll = logf(v);
      if (ll != ll) ll = 0.f;       // NaN -> 0
      ll = fmaxf(ll, 0.f);          // relu
      L[b][t] = ll;
    }
  }
  __syncthreads();
  int w = t >> 6, lane = t & 63;
  if (w < 4){
    float m = -INFINITY;
    for (int i=lane;i<256;i+=64){ float v = L[w][i]; if (v != INFINITY) m = fmaxf(m, v); }
    #pragma unroll
    for (int o=32;o>=1;o>>=1) m = fmaxf(m, __shfl_xor(m, o, 64));
    if (lane==0) fmx[w] = m;
  }
  __syncthreads();
  if (t < 256){
    for (int b=0;b<4;b++) if (L[b][t] == INFINITY) L[b][t] = fmx[b];
  }
  if (t < 4) L[t][256] = pt[t];
  __syncthreads();
  if (t < 320){
    int b = t/80, i = t%80;
    float a = fc1b[i];
    for (int k=0;k<257;k++) a += L[b][k]*fc1w[i*257+k];
    T1[b][i] = leakyf(a);
  }
  __syncthreads();
  if (t < 320){
    int b = t/80, i = t%80;
    float a = fc2b[i];
    for (int k=0;k<80;k++) a += T1[b][k]*fc2w[i*80+k];
    T2[b][i] = leakyf(a);
  }
  __syncthreads();
  if (t < 40){
    int b = t/10, i = t%10;
    float a = fc3b[i];
    for (int k=0;k<80;k++) a += T2[b][k]*fc3w[i*80+k];
    out[b*10+i] = a;
  }
}

extern "C" void kernel_launch(void* const* d_in, const int* in_sizes, int n_in,
                              void* d_out, int out_size, void* d_ws, size_t ws_size,
                              hipStream_t stream) {
  const float* nodes = (const float*)d_in[0];
  const int*   edges = (const int*)d_in[1];
  const float* pt    = (const float*)d_in[2];
  const float* w_ih  = (const float*)d_in[3];
  const float* w_hh  = (const float*)d_in[4];
  const float* b_ih  = (const float*)d_in[5];
  const float* b_hh  = (const float*)d_in[6];
  const float* ew1   = (const float*)d_in[7];
  const float* eb1   = (const float*)d_in[8];
  const float* ew2   = (const float*)d_in[9];
  const float* eb2   = (const float*)d_in[10];
  const float* fc1w  = (const float*)d_in[11];
  const float* fc1b  = (const float*)d_in[12];
  const float* fc2w  = (const float*)d_in[13];
  const float* fc2b  = (const float*)d_in[14];
  const float* fc3w  = (const float*)d_in[15];
  const float* fc3b  = (const float*)d_in[16];

  const size_t HN = (size_t)BATCH*NNODES*DIM;   // 10,240,000 floats
  float* ws   = (float*)d_ws;
  float* hbuf = ws;
  float* inc  = hbuf + HN;
  float* wt1  = inc  + HN;
  float* wt2  = wt1  + 2*DIM*DIM;
  float* wtih = wt2  + 2*DIM*DIM;
  float* wthh = wtih + (size_t)DIM*768;
  float* sbuf = wthh + (size_t)DIM*768;
  float* gi   = sbuf + BATCH*DIM;

  // runtime chunk selection (all options divide 40000 and are %32==0)
  size_t fixedf = 2*HN + 4*(size_t)DIM*DIM + 2*(size_t)DIM*768 + BATCH*DIM;
  size_t availf = (ws_size/4 > fixedf) ? (ws_size/4 - fixedf) : 0;
  const int opts[5] = {8000,4000,1600,800,320};
  int chunk = 320;
  for (int i=0;i<5;i++){ if ((size_t)opts[i]*1536 <= availf){ chunk = opts[i]; break; } }
  float* gh = gi + (size_t)chunk*768;
  int nch = (BATCH*NNODES) / chunk;

  // pre-transpose weights to [k][f]
  transpose_kernel<<<256,256,0,stream>>>(ew1,            wt1,            256, 256);
  transpose_kernel<<<256,256,0,stream>>>(ew1 + DIM*DIM,  wt1 + DIM*DIM,  256, 256);
  transpose_kernel<<<256,256,0,stream>>>(ew2,            wt2,            256, 256);
  transpose_kernel<<<256,256,0,stream>>>(ew2 + DIM*DIM,  wt2 + DIM*DIM,  256, 256);
  transpose_kernel<<<768,256,0,stream>>>(w_ih, wtih, 768, 256);
  transpose_kernel<<<768,256,0,stream>>>(w_hh, wthh, 768, 256);

  hipMemcpyAsync(hbuf, nodes, HN*sizeof(float), hipMemcpyDeviceToDevice, stream);
  hipMemsetAsync(sbuf, 0, BATCH*DIM*sizeof(float), stream);

  for (int pass=0; pass<6; pass++){
    hipMemsetAsync(inc, 0, HN*sizeof(float), stream);
    edge_kernel<<<dim3((BATCH*NEDGES)/32, 2), 256, 0, stream>>>(hbuf, edges, wt1, wt2, eb1, eb2, inc);
    for (int c=0;c<nch;c++){
      size_t r0c = (size_t)c*chunk;
      gemm256_kernel<<<dim3(chunk/32,3),256,0,stream>>>(inc  + r0c*DIM, wtih, b_ih, gi, 768);
      gemm256_kernel<<<dim3(chunk/32,3),256,0,stream>>>(hbuf + r0c*DIM, wthh, b_hh, gh, 768);
      gate_kernel<<<chunk,256,0,stream>>>(gi, gh, hbuf + r0c*DIM);
    }
  }
  reduce_kernel<<<200,256,0,stream>>>(hbuf, sbuf);
  head_kernel<<<1,320,0,stream>>>(sbuf, pt, fc1w,fc1b,fc2w,fc2b,fc3w,fc3b,(float*)d_out);
}

// Round 2
// 10286.156 us; speedup vs baseline: 4.1247x; 4.1247x over previous
//
#include <hip/hip_runtime.h>
#include <math.h>

#define NNODES 10000
#define NEDGES 160000
#define DIM    256
#define BATCH  4

typedef __attribute__((ext_vector_type(8))) __bf16 bf16x8;
typedef __attribute__((ext_vector_type(4))) float  floatx4;

__device__ __forceinline__ float leakyf(float x){ return x > 0.f ? x : 0.01f*x; }
__device__ __forceinline__ float sigmoidf_(float x){ return 1.f/(1.f+expf(-x)); }
__device__ __forceinline__ unsigned short f2bf_u(float x){
  unsigned int u = __float_as_uint(x);
  u += 0x7fffu + ((u >> 16) & 1u);
  return (unsigned short)(u >> 16);
}

// out[k*F + f] = in[f*K + k]
__global__ void transpose_kernel(const float* __restrict__ in, float* __restrict__ out, int F, int K){
  int idx = blockIdx.x*256 + threadIdx.x;
  if (idx < F*K){ int k = idx / F, f = idx - k*F; out[idx] = in[(size_t)f*K + k]; }
}

// fp32 -> bf16 (RNE), vectorized x4. n must be divisible by 4.
__global__ void f2bf_kernel(const float* __restrict__ in, unsigned short* __restrict__ out, int n4){
  int i = blockIdx.x*256 + threadIdx.x;
  if (i < n4){
    float4 v = ((const float4*)in)[i];
    ushort4 o;
    o.x = f2bf_u(v.x); o.y = f2bf_u(v.y); o.z = f2bf_u(v.z); o.w = f2bf_u(v.w);
    ((ushort4*)out)[i] = o;
  }
}

// Fused gather -> MFMA 2-layer MLP (bf16 in, fp32 acc) -> atomic scatter-add.
// Block: 256 threads (4 waves). Tile: 64 edges x 256 features.
// Wave w owns cols [w*64, w*64+64) as 4 N-tiles of 16; all 64 edges as 4 M-tiles.
// Weights wb1/wb2 are bf16 in ORIGINAL [f][k] layout: B-fragment lane (n=lane&15)
// reads W[n0+n][k0+q*8 .. +7] = 16 contiguous bytes (L2-resident).
__global__ __launch_bounds__(256) void edge_mfma_kernel(
    const unsigned short* __restrict__ hb, const int* __restrict__ edges,
    const unsigned short* __restrict__ wb1, const unsigned short* __restrict__ wb2,
    const float* __restrict__ eb1, const float* __restrict__ eb2,
    float* __restrict__ incoming)
{
  __shared__ unsigned short As[64*264];   // [edge][k], pad 264 (row 528B: 2-way-free banks)
  __shared__ int dsts[64];
  __shared__ int srcs[64];

  const int si = blockIdx.y;
  const int bx = blockIdx.x;
  const int b  = bx / 2500;               // 2500 blocks per batch (160000/64)
  const int e0 = (bx - b*2500)*64;
  const int t  = threadIdx.x;
  const int w  = t >> 6, lane = t & 63;
  const int q  = lane >> 4, col = lane & 15;

  if (t < 64){
    const int* ep = edges + ((size_t)((b*2 + si)*(size_t)NEDGES + (e0 + t)))*2;
    dsts[t] = ep[0];
    srcs[t] = ep[1];
  }
  __syncthreads();

  // gather 64 rows of h (bf16) into LDS, 16B per thread x 8
  #pragma unroll
  for (int i=0;i<8;i++){
    int idx = t + i*256;
    int row = idx >> 5, c8 = (idx & 31)*8;
    *(bf16x8*)&As[row*264 + c8] =
        *(const bf16x8*)&hb[((size_t)b*NNODES + srcs[row])*256 + c8];
  }
  __syncthreads();

  floatx4 acc[4][4];
  #pragma unroll
  for (int mi=0;mi<4;mi++)
    #pragma unroll
    for (int ni=0;ni<4;ni++) acc[mi][ni] = (floatx4){0.f,0.f,0.f,0.f};

  // ---- layer 1 ----
  {
    const unsigned short* wt = wb1 + (size_t)si*65536;
    for (int k0=0;k0<DIM;k0+=32){
      bf16x8 a[4], bf[4];
      #pragma unroll
      for (int mi=0;mi<4;mi++)
        a[mi] = *(const bf16x8*)&As[(mi*16+col)*264 + k0 + q*8];
      #pragma unroll
      for (int ni=0;ni<4;ni++)
        bf[ni] = *(const bf16x8*)&wt[(size_t)(w*64 + ni*16 + col)*256 + k0 + q*8];
      #pragma unroll
      for (int mi=0;mi<4;mi++)
        #pragma unroll
        for (int ni=0;ni<4;ni++)
          acc[mi][ni] = __builtin_amdgcn_mfma_f32_16x16x32_bf16(a[mi], bf[ni], acc[mi][ni], 0,0,0);
    }
  }

  // bias1 + leaky -> back into As (bf16). C layout: row=q*4+r, col=lane&15.
  {
    float b1v[4];
    #pragma unroll
    for (int ni=0;ni<4;ni++) b1v[ni] = eb1[si*256 + w*64 + ni*16 + col];
    __syncthreads();   // everyone done reading As
    #pragma unroll
    for (int mi=0;mi<4;mi++)
      #pragma unroll
      for (int ni=0;ni<4;ni++)
        #pragma unroll
        for (int r=0;r<4;r++){
          float v = leakyf(acc[mi][ni][r] + b1v[ni]);
          As[(mi*16 + q*4 + r)*264 + w*64 + ni*16 + col] = f2bf_u(v);
        }
    __syncthreads();
  }

  #pragma unroll
  for (int mi=0;mi<4;mi++)
    #pragma unroll
    for (int ni=0;ni<4;ni++) acc[mi][ni] = (floatx4){0.f,0.f,0.f,0.f};

  // ---- layer 2 ----
  {
    const unsigned short* wt = wb2 + (size_t)si*65536;
    for (int k0=0;k0<DIM;k0+=32){
      bf16x8 a[4], bf[4];
      #pragma unroll
      for (int mi=0;mi<4;mi++)
        a[mi] = *(const bf16x8*)&As[(mi*16+col)*264 + k0 + q*8];
      #pragma unroll
      for (int ni=0;ni<4;ni++)
        bf[ni] = *(const bf16x8*)&wt[(size_t)(w*64 + ni*16 + col)*256 + k0 + q*8];
      #pragma unroll
      for (int mi=0;mi<4;mi++)
        #pragma unroll
        for (int ni=0;ni<4;ni++)
          acc[mi][ni] = __builtin_amdgcn_mfma_f32_16x16x32_bf16(a[mi], bf[ni], acc[mi][ni], 0,0,0);
    }
  }

  // bias2 + atomic scatter-add
  {
    float b2v[4];
    #pragma unroll
    for (int ni=0;ni<4;ni++) b2v[ni] = eb2[si*256 + w*64 + ni*16 + col];
    #pragma unroll
    for (int mi=0;mi<4;mi++)
      #pragma unroll
      for (int r=0;r<4;r++){
        int m = mi*16 + q*4 + r;
        float* o = incoming + ((size_t)b*NNODES + dsts[m])*256 + w*64 + col;
        #pragma unroll
        for (int ni=0;ni<4;ni++)
          atomicAdd(o + ni*16, acc[mi][ni][r] + b2v[ni]);
      }
  }
}

// C[r][colOff+f] = A[r][:] @ Wt[:][colOff+f] + bias.  A: rows x 256, Wt: 256 x Ntot.
__global__ __launch_bounds__(256) void gemm256_kernel(
    const float* __restrict__ A, const float* __restrict__ Wt,
    const float* __restrict__ bias, float* __restrict__ C, int Ntot)
{
  __shared__ float Asm[32*17];
  __shared__ float Ws[16*256];
  const int colOff = blockIdx.y * 256;
  const int r0 = blockIdx.x * 32;
  const int t = threadIdx.x;
  const int tx = t & 15, ty = t >> 4;
  const int le = t >> 3, kload = (t & 7)*2;
  const float* arow = A + ((size_t)(r0 + le))*DIM + kload;

  float4 acc0[4], acc1[4];
  #pragma unroll
  for (int i=0;i<4;i++){ acc0[i]=make_float4(0.f,0.f,0.f,0.f); acc1[i]=make_float4(0.f,0.f,0.f,0.f); }

  for (int k0=0;k0<DIM;k0+=16){
    __syncthreads();
    Asm[le*17+kload]   = arow[k0];
    Asm[le*17+kload+1] = arow[k0+1];
    #pragma unroll
    for (int i=0;i<4;i++){
      int qq = t + i*256; int kk = qq >> 6; int f = (qq & 63)*4;
      *(float4*)&Ws[kk*256+f] = *(const float4*)&Wt[(size_t)(k0+kk)*Ntot + colOff + f];
    }
    __syncthreads();
    #pragma unroll
    for (int kk=0;kk<16;kk++){
      float x0 = Asm[(2*ty)*17+kk], x1 = Asm[(2*ty+1)*17+kk];
      #pragma unroll
      for (int i=0;i<4;i++){
        float4 wv = *(float4*)&Ws[kk*256 + tx*4 + 64*i];
        acc0[i].x += x0*wv.x; acc0[i].y += x0*wv.y; acc0[i].z += x0*wv.z; acc0[i].w += x0*wv.w;
        acc1[i].x += x1*wv.x; acc1[i].y += x1*wv.y; acc1[i].z += x1*wv.z; acc1[i].w += x1*wv.w;
      }
    }
  }
  #pragma unroll
  for (int i=0;i<4;i++){
    int f = tx*4 + 64*i;
    float4 bb = *(const float4*)&bias[colOff+f];
    float4 v0, v1;
    v0.x = acc0[i].x+bb.x; v0.y = acc0[i].y+bb.y; v0.z = acc0[i].z+bb.z; v0.w = acc0[i].w+bb.w;
    v1.x = acc1[i].x+bb.x; v1.y = acc1[i].y+bb.y; v1.z = acc1[i].z+bb.z; v1.w = acc1[i].w+bb.w;
    *(float4*)&C[((size_t)(r0+2*ty))*Ntot + colOff + f]   = v0;
    *(float4*)&C[((size_t)(r0+2*ty+1))*Ntot + colOff + f] = v1;
  }
}

__global__ void gate_kernel(const float* __restrict__ gi, const float* __restrict__ gh,
                            float* __restrict__ hrow)
{
  int idx = blockIdx.x*256 + threadIdx.x;
  int r = idx >> 8, d = idx & 255;
  size_t base = (size_t)r*768;
  float ir = gi[base + d];
  float iz = gi[base + 256 + d];
  float inn= gi[base + 512 + d];
  float hr = gh[base + d];
  float hz = gh[base + 256 + d];
  float hn = gh[base + 512 + d];
  float hv = hrow[idx];
  float rg = sigmoidf_(ir+hr);
  float zg = sigmoidf_(iz+hz);
  float ng = tanhf(inn + rg*hn);
  hrow[idx] = (1.f-zg)*ng + zg*hv;
}

__global__ void reduce_kernel(const float* __restrict__ h, float* __restrict__ sbuf){
  int b  = blockIdx.x / 50;
  int s0 = (blockIdx.x % 50) * 200;
  int d  = threadIdx.x;
  const float* p = h + ((size_t)b*NNODES + s0)*DIM + d;
  float acc = 0.f;
  for (int i=0;i<200;i++) acc += p[(size_t)i*DIM];
  atomicAdd(&sbuf[b*DIM + d], acc);
}

__global__ __launch_bounds__(320) void head_kernel(
    const float* __restrict__ sbuf, const float* __restrict__ pt,
    const float* __restrict__ fc1w, const float* __restrict__ fc1b,
    const float* __restrict__ fc2w, const float* __restrict__ fc2b,
    const float* __restrict__ fc3w, const float* __restrict__ fc3b,
    float* __restrict__ out)
{
  __shared__ float L[4][257];
  __shared__ float T1[4][80];
  __shared__ float T2[4][80];
  __shared__ float fmx[4];
  int t = threadIdx.x;
  if (t < 256){
    for (int b=0;b<4;b++){
      float v = sbuf[b*DIM + t];
      float ll = logf(v);
      if (ll != ll) ll = 0.f;
      ll = fmaxf(ll, 0.f);
      L[b][t] = ll;
    }
  }
  __syncthreads();
  int w = t >> 6, lane = t & 63;
  if (w < 4){
    float m = -INFINITY;
    for (int i=lane;i<256;i+=64){ float v = L[w][i]; if (v != INFINITY) m = fmaxf(m, v); }
    #pragma unroll
    for (int o=32;o>=1;o>>=1) m = fmaxf(m, __shfl_xor(m, o, 64));
    if (lane==0) fmx[w] = m;
  }
  __syncthreads();
  if (t < 256){
    for (int b=0;b<4;b++) if (L[b][t] == INFINITY) L[b][t] = fmx[b];
  }
  if (t < 4) L[t][256] = pt[t];
  __syncthreads();
  if (t < 320){
    int b = t/80, i = t%80;
    float a = fc1b[i];
    for (int k=0;k<257;k++) a += L[b][k]*fc1w[i*257+k];
    T1[b][i] = leakyf(a);
  }
  __syncthreads();
  if (t < 320){
    int b = t/80, i = t%80;
    float a = fc2b[i];
    for (int k=0;k<80;k++) a += T1[b][k]*fc2w[i*80+k];
    T2[b][i] = leakyf(a);
  }
  __syncthreads();
  if (t < 40){
    int b = t/10, i = t%10;
    float a = fc3b[i];
    for (int k=0;k<80;k++) a += T2[b][k]*fc3w[i*80+k];
    out[b*10+i] = a;
  }
}

extern "C" void kernel_launch(void* const* d_in, const int* in_sizes, int n_in,
                              void* d_out, int out_size, void* d_ws, size_t ws_size,
                              hipStream_t stream) {
  const float* nodes = (const float*)d_in[0];
  const int*   edges = (const int*)d_in[1];
  const float* pt    = (const float*)d_in[2];
  const float* w_ih  = (const float*)d_in[3];
  const float* w_hh  = (const float*)d_in[4];
  const float* b_ih  = (const float*)d_in[5];
  const float* b_hh  = (const float*)d_in[6];
  const float* ew1   = (const float*)d_in[7];
  const float* eb1   = (const float*)d_in[8];
  const float* ew2   = (const float*)d_in[9];
  const float* eb2   = (const float*)d_in[10];
  const float* fc1w  = (const float*)d_in[11];
  const float* fc1b  = (const float*)d_in[12];
  const float* fc2w  = (const float*)d_in[13];
  const float* fc2b  = (const float*)d_in[14];
  const float* fc3w  = (const float*)d_in[15];
  const float* fc3b  = (const float*)d_in[16];

  const size_t HN = (size_t)BATCH*NNODES*DIM;   // 10,240,000 floats
  float* ws   = (float*)d_ws;
  float* hbuf = ws;                     // HN
  float* inc  = hbuf + HN;              // HN
  float* wtih = inc  + HN;              // 768*256
  float* wthh = wtih + (size_t)DIM*768; // 768*256
  float* sbuf = wthh + (size_t)DIM*768; // 1024
  unsigned short* hb  = (unsigned short*)(sbuf + BATCH*DIM);  // HN bf16
  unsigned short* wb1 = hb  + HN;       // 2*256*256 bf16
  unsigned short* wb2 = wb1 + 2*DIM*DIM;
  float* gi   = (float*)(wb2 + 2*DIM*DIM);

  size_t fixedf = 2*HN + 2*(size_t)DIM*768 + BATCH*DIM + (HN + 4*(size_t)DIM*DIM)/2;
  size_t availf = (ws_size/4 > fixedf) ? (ws_size/4 - fixedf) : 0;
  const int opts[5] = {8000,4000,1600,800,320};
  int chunk = 320;
  for (int i=0;i<5;i++){ if ((size_t)opts[i]*1536 <= availf){ chunk = opts[i]; break; } }
  float* gh = gi + (size_t)chunk*768;
  int nch = (BATCH*NNODES) / chunk;

  // GRU weights: fp32 transpose to [k][f]
  transpose_kernel<<<768,256,0,stream>>>(w_ih, wtih, 768, 256);
  transpose_kernel<<<768,256,0,stream>>>(w_hh, wthh, 768, 256);
  // edge weights: bf16 in original [f][k] layout
  f2bf_kernel<<<128,256,0,stream>>>(ew1, wb1, 2*DIM*DIM/4);
  f2bf_kernel<<<128,256,0,stream>>>(ew2, wb2, 2*DIM*DIM/4);

  hipMemcpyAsync(hbuf, nodes, HN*sizeof(float), hipMemcpyDeviceToDevice, stream);
  hipMemsetAsync(sbuf, 0, BATCH*DIM*sizeof(float), stream);

  for (int pass=0; pass<6; pass++){
    f2bf_kernel<<<(int)(HN/4/256),256,0,stream>>>(hbuf, hb, (int)(HN/4));
    hipMemsetAsync(inc, 0, HN*sizeof(float), stream);
    edge_mfma_kernel<<<dim3((BATCH*NEDGES)/64, 2), 256, 0, stream>>>(hb, edges, wb1, wb2, eb1, eb2, inc);
    for (int c=0;c<nch;c++){
      size_t r0c = (size_t)c*chunk;
      gemm256_kernel<<<dim3(chunk/32,3),256,0,stream>>>(inc  + r0c*DIM, wtih, b_ih, gi, 768);
      gemm256_kernel<<<dim3(chunk/32,3),256,0,stream>>>(hbuf + r0c*DIM, wthh, b_hh, gh, 768);
      gate_kernel<<<chunk,256,0,stream>>>(gi, gh, hbuf + r0c*DIM);
    }
  }
  reduce_kernel<<<200,256,0,stream>>>(hbuf, sbuf);
  head_kernel<<<1,320,0,stream>>>(sbuf, pt, fc1w,fc1b,fc2w,fc2b,fc3w,fc3b,(float*)d_out);
}

// Round 3
// 8611.639 us; speedup vs baseline: 4.9268x; 1.1944x over previous
//
#include <hip/hip_runtime.h>
#include <math.h>

#define NNODES 10000
#define NEDGES 160000
#define DIM    256
#define BATCH  4
#define NG     8          // BATCH * S streams

typedef __attribute__((ext_vector_type(8))) __bf16 bf16x8;
typedef __attribute__((ext_vector_type(4))) float  floatx4;

__device__ __forceinline__ float leakyf(float x){ return x > 0.f ? x : 0.01f*x; }
__device__ __forceinline__ float sigmoidf_(float x){ return 1.f/(1.f+expf(-x)); }
__device__ __forceinline__ unsigned short f2bf_u(float x){
  unsigned int u = __float_as_uint(x);
  u += 0x7fffu + ((u >> 16) & 1u);
  return (unsigned short)(u >> 16);
}
__device__ __forceinline__ float bfdec(unsigned short u){
  return __uint_as_float(((unsigned int)u) << 16);
}

// fp32 -> bf16 (RNE), vectorized x4
__global__ void f2bf_kernel(const float* __restrict__ in, unsigned short* __restrict__ out, int n4){
  int i = blockIdx.x*256 + threadIdx.x;
  if (i < n4){
    float4 v = ((const float4*)in)[i];
    ushort4 o;
    o.x = f2bf_u(v.x); o.y = f2bf_u(v.y); o.z = f2bf_u(v.z); o.w = f2bf_u(v.w);
    ((ushort4*)out)[i] = o;
  }
}

// fp32 -> (hi, lo) bf16 pair: hi = rne(x), lo = rne(x - hi)
__global__ void f2bf_split_kernel(const float* __restrict__ in,
                                  unsigned short* __restrict__ hi,
                                  unsigned short* __restrict__ lo, int n4){
  int i = blockIdx.x*256 + threadIdx.x;
  if (i < n4){
    float4 v = ((const float4*)in)[i];
    ushort4 h, l;
    h.x = f2bf_u(v.x); l.x = f2bf_u(v.x - bfdec(h.x));
    h.y = f2bf_u(v.y); l.y = f2bf_u(v.y - bfdec(h.y));
    h.z = f2bf_u(v.z); l.z = f2bf_u(v.z - bfdec(h.z));
    h.w = f2bf_u(v.w); l.w = f2bf_u(v.w - bfdec(h.w));
    ((ushort4*)hi)[i] = h;
    ((ushort4*)lo)[i] = l;
  }
}

// ---------------- edge sort (counting sort by dst, per stream g) ----------------
__global__ void hist_kernel(const int* __restrict__ edges, int* __restrict__ cnt){
  int idx = blockIdx.x*256 + threadIdx.x;
  if (idx < NG*NEDGES){
    int g = idx / NEDGES, e = idx - g*NEDGES;
    int d = edges[((size_t)g*NEDGES + e)*2];
    atomicAdd(&cnt[g*NNODES + d], 1);
  }
}

// one block per g: exclusive prefix over 10000 bins
__global__ __launch_bounds__(256) void scan_kernel(const int* __restrict__ cnt, int* __restrict__ off){
  __shared__ int sc[256];
  int g = blockIdx.x, t = threadIdx.x;
  int base = 0;
  for (int c=0;c<40;c++){
    int i = c*256 + t;
    int v = (i < NNODES) ? cnt[g*NNODES + i] : 0;
    __syncthreads();
    sc[t] = v;
    __syncthreads();
    for (int o=1;o<256;o<<=1){
      int u = (t>=o) ? sc[t-o] : 0;
      __syncthreads();
      sc[t] += u;
      __syncthreads();
    }
    if (i < NNODES) off[g*(NNODES+1) + i] = base + sc[t] - v;
    base += sc[255];
  }
  if (t == 0) off[g*(NNODES+1) + NNODES] = base;
}

__global__ void scatter_kernel(const int* __restrict__ edges, const int* __restrict__ off,
                               int* __restrict__ cur, int* __restrict__ sdst, int* __restrict__ ssrc){
  int idx = blockIdx.x*256 + threadIdx.x;
  if (idx < NG*NEDGES){
    int g = idx / NEDGES, e = idx - g*NEDGES;
    const int* ep = &edges[((size_t)g*NEDGES + e)*2];
    int d = ep[0], s = ep[1];
    int pos = off[g*(NNODES+1) + d] + atomicAdd(&cur[g*NNODES + d], 1);
    sdst[g*NEDGES + pos] = d;
    ssrc[g*NEDGES + pos] = s;
  }
}

// ---------------- fused edge MLP (sorted, run-compressed scatter) ----------------
__global__ __launch_bounds__(256) void edge_mfma_kernel(
    const unsigned short* __restrict__ hb, const int* __restrict__ sdst, const int* __restrict__ ssrc,
    const unsigned short* __restrict__ wb1, const unsigned short* __restrict__ wb2,
    const float* __restrict__ eb1, const float* __restrict__ eb2,
    float* __restrict__ incoming)
{
  __shared__ unsigned short As[64*264];
  __shared__ int dsts[64];
  __shared__ int srcs[64];

  const int g  = blockIdx.y;           // 0..7
  const int b  = g >> 1, si = g & 1;
  const int e0 = blockIdx.x * 64;
  const int t  = threadIdx.x;
  const int w  = t >> 6, lane = t & 63;
  const int q  = lane >> 4, col = lane & 15;

  if (t < 64){
    dsts[t] = sdst[(size_t)g*NEDGES + e0 + t];
    srcs[t] = ssrc[(size_t)g*NEDGES + e0 + t];
  }
  __syncthreads();

  #pragma unroll
  for (int i=0;i<8;i++){
    int idx = t + i*256;
    int row = idx >> 5, c8 = (idx & 31)*8;
    *(bf16x8*)&As[row*264 + c8] =
        *(const bf16x8*)&hb[((size_t)b*NNODES + srcs[row])*256 + c8];
  }
  __syncthreads();

  floatx4 acc[4][4];
  #pragma unroll
  for (int mi=0;mi<4;mi++)
    #pragma unroll
    for (int ni=0;ni<4;ni++) acc[mi][ni] = (floatx4){0.f,0.f,0.f,0.f};

  // ---- layer 1 ----
  {
    const unsigned short* wt = wb1 + (size_t)si*65536;
    for (int k0=0;k0<DIM;k0+=32){
      bf16x8 a[4], bf[4];
      #pragma unroll
      for (int mi=0;mi<4;mi++)
        a[mi] = *(const bf16x8*)&As[(mi*16+col)*264 + k0 + q*8];
      #pragma unroll
      for (int ni=0;ni<4;ni++)
        bf[ni] = *(const bf16x8*)&wt[(size_t)(w*64 + ni*16 + col)*256 + k0 + q*8];
      #pragma unroll
      for (int mi=0;mi<4;mi++)
        #pragma unroll
        for (int ni=0;ni<4;ni++)
          acc[mi][ni] = __builtin_amdgcn_mfma_f32_16x16x32_bf16(a[mi], bf[ni], acc[mi][ni], 0,0,0);
    }
  }

  // bias1 + leaky -> back into As (bf16)
  {
    float b1v[4];
    #pragma unroll
    for (int ni=0;ni<4;ni++) b1v[ni] = eb1[si*256 + w*64 + ni*16 + col];
    __syncthreads();
    #pragma unroll
    for (int mi=0;mi<4;mi++)
      #pragma unroll
      for (int ni=0;ni<4;ni++)
        #pragma unroll
        for (int r=0;r<4;r++){
          float v = leakyf(acc[mi][ni][r] + b1v[ni]);
          As[(mi*16 + q*4 + r)*264 + w*64 + ni*16 + col] = f2bf_u(v);
        }
    __syncthreads();
  }

  #pragma unroll
  for (int mi=0;mi<4;mi++)
    #pragma unroll
    for (int ni=0;ni<4;ni++) acc[mi][ni] = (floatx4){0.f,0.f,0.f,0.f};

  // ---- layer 2 ----
  {
    const unsigned short* wt = wb2 + (size_t)si*65536;
    for (int k0=0;k0<DIM;k0+=32){
      bf16x8 a[4], bf[4];
      #pragma unroll
      for (int mi=0;mi<4;mi++)
        a[mi] = *(const bf16x8*)&As[(mi*16+col)*264 + k0 + q*8];
      #pragma unroll
      for (int ni=0;ni<4;ni++)
        bf[ni] = *(const bf16x8*)&wt[(size_t)(w*64 + ni*16 + col)*256 + k0 + q*8];
      #pragma unroll
      for (int mi=0;mi<4;mi++)
        #pragma unroll
        for (int ni=0;ni<4;ni++)
          acc[mi][ni] = __builtin_amdgcn_mfma_f32_16x16x32_bf16(a[mi], bf[ni], acc[mi][ni], 0,0,0);
    }
  }

  // bias2 + segmented scatter-add (sorted dsts -> run compression)
  {
    float b2v[4];
    #pragma unroll
    for (int ni=0;ni<4;ni++) b2v[ni] = eb2[si*256 + w*64 + ni*16 + col];
    const size_t obase = (size_t)b*NNODES*256;

    #pragma unroll
    for (int mi=0;mi<4;mi++){
      const int m0 = mi*16;
      if (dsts[m0] == dsts[m0+15]){
        // whole 16-row tile uniform (wave-uniform branch)
        float* o = incoming + obase + (size_t)dsts[m0]*256 + w*64 + col;
        #pragma unroll
        for (int ni=0;ni<4;ni++){
          float s = acc[mi][ni][0]+acc[mi][ni][1]+acc[mi][ni][2]+acc[mi][ni][3] + 4.f*b2v[ni];
          s += __shfl_xor(s, 16, 64);
          s += __shfl_xor(s, 32, 64);
          if (q == ni) atomicAdd(o + ni*16, s);
        }
      } else {
        const int d0=dsts[m0+q*4+0], d1=dsts[m0+q*4+1], d2=dsts[m0+q*4+2], d3=dsts[m0+q*4+3];
        #pragma unroll
        for (int ni=0;ni<4;ni++){
          const int cpos = w*64 + ni*16 + col;
          float v = acc[mi][ni][0] + b2v[ni];
          if (d1==d0) v += acc[mi][ni][1] + b2v[ni];
          else { atomicAdd(incoming + obase + (size_t)d0*256 + cpos, v); v = acc[mi][ni][1] + b2v[ni]; }
          if (d2==d1) v += acc[mi][ni][2] + b2v[ni];
          else { atomicAdd(incoming + obase + (size_t)d1*256 + cpos, v); v = acc[mi][ni][2] + b2v[ni]; }
          if (d3==d2) v += acc[mi][ni][3] + b2v[ni];
          else { atomicAdd(incoming + obase + (size_t)d2*256 + cpos, v); v = acc[mi][ni][3] + b2v[ni]; }
          atomicAdd(incoming + obase + (size_t)d3*256 + cpos, v);
        }
      }
    }
  }
}

// ---------------- GRU GEMM: C = A @ W^T + bias, split-bf16 (3 MFMA) ----------------
// A: rows x 256 as (Ahi, Alo).  W: 768 x 256 [n][k] as (Whi, Wlo).  C: rows x 768 fp32.
// grid: (rows/64, 3). block 256 = 4 waves; wave w owns cols colOff + [w*64, w*64+64).
__global__ __launch_bounds__(256) void gru_gemm_kernel(
    const unsigned short* __restrict__ Ahi, const unsigned short* __restrict__ Alo,
    const unsigned short* __restrict__ Whi, const unsigned short* __restrict__ Wlo,
    const float* __restrict__ bias, float* __restrict__ C)
{
  const int t = threadIdx.x;
  const int w = t >> 6, lane = t & 63;
  const int q = lane >> 4, col = lane & 15;
  const int r0 = blockIdx.x * 64;
  const int colOff = blockIdx.y * 256;

  floatx4 acc[4][4];
  #pragma unroll
  for (int mi=0;mi<4;mi++)
    #pragma unroll
    for (int ni=0;ni<4;ni++) acc[mi][ni] = (floatx4){0.f,0.f,0.f,0.f};

  for (int k0=0;k0<DIM;k0+=32){
    bf16x8 ahi[4], alo[4], bhi[4], blo[4];
    #pragma unroll
    for (int mi=0;mi<4;mi++){
      size_t base = ((size_t)(r0 + mi*16 + col))*256 + k0 + q*8;
      ahi[mi] = *(const bf16x8*)&Ahi[base];
      alo[mi] = *(const bf16x8*)&Alo[base];
    }
    #pragma unroll
    for (int ni=0;ni<4;ni++){
      size_t wb = ((size_t)(colOff + w*64 + ni*16 + col))*256 + k0 + q*8;
      bhi[ni] = *(const bf16x8*)&Whi[wb];
      blo[ni] = *(const bf16x8*)&Wlo[wb];
    }
    #pragma unroll
    for (int mi=0;mi<4;mi++)
      #pragma unroll
      for (int ni=0;ni<4;ni++){
        acc[mi][ni] = __builtin_amdgcn_mfma_f32_16x16x32_bf16(ahi[mi], bhi[ni], acc[mi][ni], 0,0,0);
        acc[mi][ni] = __builtin_amdgcn_mfma_f32_16x16x32_bf16(ahi[mi], blo[ni], acc[mi][ni], 0,0,0);
        acc[mi][ni] = __builtin_amdgcn_mfma_f32_16x16x32_bf16(alo[mi], bhi[ni], acc[mi][ni], 0,0,0);
      }
  }

  float bb[4];
  #pragma unroll
  for (int ni=0;ni<4;ni++) bb[ni] = bias[colOff + w*64 + ni*16 + col];
  #pragma unroll
  for (int mi=0;mi<4;mi++)
    #pragma unroll
    for (int rr=0;rr<4;rr++){
      size_t row = (size_t)(r0 + mi*16 + q*4 + rr);
      #pragma unroll
      for (int ni=0;ni<4;ni++)
        C[row*768 + colOff + w*64 + ni*16 + col] = acc[mi][ni][rr] + bb[ni];
    }
}

// gate: h' = (1-z)*n + z*h ; h stored as bf16 (hi,lo) pair
__global__ void gate_kernel(const float* __restrict__ gi, const float* __restrict__ gh,
                            unsigned short* __restrict__ hhi, unsigned short* __restrict__ hlo)
{
  int idx = blockIdx.x*256 + threadIdx.x;
  int r = idx >> 8, d = idx & 255;
  size_t base = (size_t)r*768;
  float ir = gi[base + d];
  float iz = gi[base + 256 + d];
  float inn= gi[base + 512 + d];
  float hr = gh[base + d];
  float hz = gh[base + 256 + d];
  float hn = gh[base + 512 + d];
  float hv = bfdec(hhi[idx]) + bfdec(hlo[idx]);
  float rg = sigmoidf_(ir+hr);
  float zg = sigmoidf_(iz+hz);
  float ng = tanhf(inn + rg*hn);
  float hnew = (1.f-zg)*ng + zg*hv;
  unsigned short hi = f2bf_u(hnew);
  hhi[idx] = hi;
  hlo[idx] = f2bf_u(hnew - bfdec(hi));
}

__global__ void reduce_kernel(const unsigned short* __restrict__ hhi,
                              const unsigned short* __restrict__ hlo,
                              float* __restrict__ sbuf){
  int b  = blockIdx.x / 50;
  int s0 = (blockIdx.x % 50) * 200;
  int d  = threadIdx.x;
  size_t off = ((size_t)b*NNODES + s0)*DIM + d;
  float acc = 0.f;
  for (int i=0;i<200;i++){
    acc += bfdec(hhi[off]) + bfdec(hlo[off]);
    off += DIM;
  }
  atomicAdd(&sbuf[b*DIM + d], acc);
}

__global__ __launch_bounds__(320) void head_kernel(
    const float* __restrict__ sbuf, const float* __restrict__ pt,
    const float* __restrict__ fc1w, const float* __restrict__ fc1b,
    const float* __restrict__ fc2w, const float* __restrict__ fc2b,
    const float* __restrict__ fc3w, const float* __restrict__ fc3b,
    float* __restrict__ out)
{
  __shared__ float L[4][257];
  __shared__ float T1[4][80];
  __shared__ float T2[4][80];
  __shared__ float fmx[4];
  int t = threadIdx.x;
  if (t < 256){
    for (int b=0;b<4;b++){
      float v = sbuf[b*DIM + t];
      float ll = logf(v);
      if (ll != ll) ll = 0.f;
      ll = fmaxf(ll, 0.f);
      L[b][t] = ll;
    }
  }
  __syncthreads();
  int w = t >> 6, lane = t & 63;
  if (w < 4){
    float m = -INFINITY;
    for (int i=lane;i<256;i+=64){ float v = L[w][i]; if (v != INFINITY) m = fmaxf(m, v); }
    #pragma unroll
    for (int o=32;o>=1;o>>=1) m = fmaxf(m, __shfl_xor(m, o, 64));
    if (lane==0) fmx[w] = m;
  }
  __syncthreads();
  if (t < 256){
    for (int b=0;b<4;b++) if (L[b][t] == INFINITY) L[b][t] = fmx[b];
  }
  if (t < 4) L[t][256] = pt[t];
  __syncthreads();
  if (t < 320){
    int b = t/80, i = t%80;
    float a = fc1b[i];
    for (int k=0;k<257;k++) a += L[b][k]*fc1w[i*257+k];
    T1[b][i] = leakyf(a);
  }
  __syncthreads();
  if (t < 320){
    int b = t/80, i = t%80;
    float a = fc2b[i];
    for (int k=0;k<80;k++) a += T1[b][k]*fc2w[i*80+k];
    T2[b][i] = leakyf(a);
  }
  __syncthreads();
  if (t < 40){
    int b = t/10, i = t%10;
    float a = fc3b[i];
    for (int k=0;k<80;k++) a += T2[b][k]*fc3w[i*80+k];
    out[b*10+i] = a;
  }
}

extern "C" void kernel_launch(void* const* d_in, const int* in_sizes, int n_in,
                              void* d_out, int out_size, void* d_ws, size_t ws_size,
                              hipStream_t stream) {
  const float* nodes = (const float*)d_in[0];
  const int*   edges = (const int*)d_in[1];
  const float* pt    = (const float*)d_in[2];
  const float* w_ih  = (const float*)d_in[3];
  const float* w_hh  = (const float*)d_in[4];
  const float* b_ih  = (const float*)d_in[5];
  const float* b_hh  = (const float*)d_in[6];
  const float* ew1   = (const float*)d_in[7];
  const float* eb1   = (const float*)d_in[8];
  const float* ew2   = (const float*)d_in[9];
  const float* eb2   = (const float*)d_in[10];
  const float* fc1w  = (const float*)d_in[11];
  const float* fc1b  = (const float*)d_in[12];
  const float* fc2w  = (const float*)d_in[13];
  const float* fc2b  = (const float*)d_in[14];
  const float* fc3w  = (const float*)d_in[15];
  const float* fc3b  = (const float*)d_in[16];

  const size_t HN = (size_t)BATCH*NNODES*DIM;     // 10,240,000
  char* p = (char*)d_ws;
  float* inc  = (float*)p;                        p += HN*4;
  float* sbuf = (float*)p;                        p += BATCH*DIM*4;
  unsigned short* h_hi = (unsigned short*)p;      p += HN*2;
  unsigned short* h_lo = (unsigned short*)p;      p += HN*2;
  unsigned short* i_hi = (unsigned short*)p;      p += HN*2;
  unsigned short* i_lo = (unsigned short*)p;      p += HN*2;
  unsigned short* wb1  = (unsigned short*)p;      p += 2*65536*2;
  unsigned short* wb2  = (unsigned short*)p;      p += 2*65536*2;
  unsigned short* wih_hi = (unsigned short*)p;    p += 768*256*2;
  unsigned short* wih_lo = (unsigned short*)p;    p += 768*256*2;
  unsigned short* whh_hi = (unsigned short*)p;    p += 768*256*2;
  unsigned short* whh_lo = (unsigned short*)p;    p += 768*256*2;
  int* off  = (int*)p;                            p += NG*(NNODES+1)*4;
  int* cur  = (int*)p;                            p += NG*NNODES*4;
  int* sdst = (int*)p;                            p += (size_t)NG*NEDGES*4;
  int* ssrc = (int*)p;                            p += (size_t)NG*NEDGES*4;
  float* gi = (float*)p;

  // chunk selection: multiples of 64 dividing 40000
  size_t usedB = (size_t)(p - (char*)d_ws);
  size_t availf = (ws_size > usedB) ? (ws_size - usedB)/4 : 0;
  const int opts[5] = {40000, 8000, 1600, 320, 64};
  int chunk = 64;
  for (int i=0;i<5;i++){ if ((size_t)opts[i]*1536 <= availf){ chunk = opts[i]; break; } }
  float* gh = gi + (size_t)chunk*768;
  int nch = (BATCH*NNODES) / chunk;

  // weights -> bf16 (edge: single; GRU: hi/lo split). [n][k] layouts kept as-is.
  f2bf_kernel<<<128,256,0,stream>>>(ew1, wb1, 2*DIM*DIM/4);
  f2bf_kernel<<<128,256,0,stream>>>(ew2, wb2, 2*DIM*DIM/4);
  f2bf_split_kernel<<<192,256,0,stream>>>(w_ih, wih_hi, wih_lo, 768*256/4);
  f2bf_split_kernel<<<192,256,0,stream>>>(w_hh, whh_hi, whh_lo, 768*256/4);

  // h0 = nodes as (hi,lo) bf16 pair
  f2bf_split_kernel<<<(int)(HN/4/256),256,0,stream>>>(nodes, h_hi, h_lo, (int)(HN/4));

  // counting sort of edges by dst, per stream g
  hipMemsetAsync(cur, 0, NG*NNODES*sizeof(int), stream);
  hist_kernel<<<(NG*NEDGES)/256,256,0,stream>>>(edges, cur);
  scan_kernel<<<NG,256,0,stream>>>(cur, off);
  hipMemsetAsync(cur, 0, NG*NNODES*sizeof(int), stream);
  scatter_kernel<<<(NG*NEDGES)/256,256,0,stream>>>(edges, off, cur, sdst, ssrc);

  hipMemsetAsync(sbuf, 0, BATCH*DIM*sizeof(float), stream);

  for (int pass=0; pass<6; pass++){
    hipMemsetAsync(inc, 0, HN*sizeof(float), stream);
    edge_mfma_kernel<<<dim3(NEDGES/64, NG), 256, 0, stream>>>(h_hi, sdst, ssrc, wb1, wb2, eb1, eb2, inc);
    f2bf_split_kernel<<<(int)(HN/4/256),256,0,stream>>>(inc, i_hi, i_lo, (int)(HN/4));
    for (int c=0;c<nch;c++){
      size_t r0c = (size_t)c*chunk;
      gru_gemm_kernel<<<dim3(chunk/64,3),256,0,stream>>>(i_hi + r0c*DIM, i_lo + r0c*DIM,
                                                         wih_hi, wih_lo, b_ih, gi);
      gru_gemm_kernel<<<dim3(chunk/64,3),256,0,stream>>>(h_hi + r0c*DIM, h_lo + r0c*DIM,
                                                         whh_hi, whh_lo, b_hh, gh);
      gate_kernel<<<chunk,256,0,stream>>>(gi, gh, h_hi + r0c*DIM, h_lo + r0c*DIM);
    }
  }
  reduce_kernel<<<200,256,0,stream>>>(h_hi, h_lo, sbuf);
  head_kernel<<<1,320,0,stream>>>(sbuf, pt, fc1w,fc1b,fc2w,fc2b,fc3w,fc3b,(float*)d_out);
}

// Round 4
// 4028.922 us; speedup vs baseline: 10.5308x; 2.1375x over previous
//
#include <hip/hip_runtime.h>
#include <math.h>

#define NNODES 10000
#define NEDGES 160000
#define DIM    256
#define BATCH  4
#define NG     8          // BATCH * S streams

typedef __attribute__((ext_vector_type(8))) __bf16 bf16x8;
typedef __attribute__((ext_vector_type(4))) float  floatx4;

__device__ __forceinline__ float leakyf(float x){ return x > 0.f ? x : 0.01f*x; }
__device__ __forceinline__ float sigmoidf_(float x){ return 1.f/(1.f+expf(-x)); }
__device__ __forceinline__ unsigned short f2bf_u(float x){
  unsigned int u = __float_as_uint(x);
  u += 0x7fffu + ((u >> 16) & 1u);
  return (unsigned short)(u >> 16);
}
__device__ __forceinline__ float bfdec(unsigned short u){
  return __uint_as_float(((unsigned int)u) << 16);
}

// fp32 -> bf16 (RNE), vectorized x4
__global__ void f2bf_kernel(const float* __restrict__ in, unsigned short* __restrict__ out, int n4){
  int i = blockIdx.x*256 + threadIdx.x;
  if (i < n4){
    float4 v = ((const float4*)in)[i];
    ushort4 o;
    o.x = f2bf_u(v.x); o.y = f2bf_u(v.y); o.z = f2bf_u(v.z); o.w = f2bf_u(v.w);
    ((ushort4*)out)[i] = o;
  }
}

// fp32 -> (hi, lo) bf16 pair
__global__ void f2bf_split_kernel(const float* __restrict__ in,
                                  unsigned short* __restrict__ hi,
                                  unsigned short* __restrict__ lo, int n4){
  int i = blockIdx.x*256 + threadIdx.x;
  if (i < n4){
    float4 v = ((const float4*)in)[i];
    ushort4 h, l;
    h.x = f2bf_u(v.x); l.x = f2bf_u(v.x - bfdec(h.x));
    h.y = f2bf_u(v.y); l.y = f2bf_u(v.y - bfdec(h.y));
    h.z = f2bf_u(v.z); l.z = f2bf_u(v.z - bfdec(h.z));
    h.w = f2bf_u(v.w); l.w = f2bf_u(v.w - bfdec(h.w));
    ((ushort4*)hi)[i] = h;
    ((ushort4*)lo)[i] = l;
  }
}

// W2cat[n][si*256+k] = ew2[si][n][k], split to hi/lo. grid 512 x 256
__global__ void w2cat_kernel(const float* __restrict__ ew2,
                             unsigned short* __restrict__ hi, unsigned short* __restrict__ lo){
  int idx = blockIdx.x*256 + threadIdx.x;           // 256*512 = 131072
  int n = idx >> 9, kk = idx & 511;
  int si = kk >> 8, k = kk & 255;
  float v = ew2[si*65536 + n*256 + k];
  unsigned short h = f2bf_u(v);
  hi[idx] = h; lo[idx] = f2bf_u(v - bfdec(h));
}

// ---------------- edge sort (counting sort by dst, per stream g) ----------------
__global__ void hist_kernel(const int* __restrict__ edges, int* __restrict__ cnt){
  int idx = blockIdx.x*256 + threadIdx.x;
  if (idx < NG*NEDGES){
    int g = idx / NEDGES, e = idx - g*NEDGES;
    int d = edges[((size_t)g*NEDGES + e)*2];
    atomicAdd(&cnt[g*NNODES + d], 1);
  }
}

__global__ __launch_bounds__(256) void scan_kernel(const int* __restrict__ cnt, int* __restrict__ off){
  __shared__ int sc[256];
  int g = blockIdx.x, t = threadIdx.x;
  int base = 0;
  for (int c=0;c<40;c++){
    int i = c*256 + t;
    int v = (i < NNODES) ? cnt[g*NNODES + i] : 0;
    __syncthreads();
    sc[t] = v;
    __syncthreads();
    for (int o=1;o<256;o<<=1){
      int u = (t>=o) ? sc[t-o] : 0;
      __syncthreads();
      sc[t] += u;
      __syncthreads();
    }
    if (i < NNODES) off[g*(NNODES+1) + i] = base + sc[t] - v;
    base += sc[255];
  }
  if (t == 0) off[g*(NNODES+1) + NNODES] = base;
}

__global__ void scatter_kernel(const int* __restrict__ edges, const int* __restrict__ off,
                               int* __restrict__ cur, int* __restrict__ ssrc){
  int idx = blockIdx.x*256 + threadIdx.x;
  if (idx < NG*NEDGES){
    int g = idx / NEDGES, e = idx - g*NEDGES;
    const int* ep = &edges[((size_t)g*NEDGES + e)*2];
    int d = ep[0], s = ep[1];
    int pos = off[g*(NNODES+1) + d] + atomicAdd(&cur[g*NNODES + d], 1);
    ssrc[g*NEDGES + pos] = s;
  }
}

// ---------------- Z = leaky(h @ W1^T + b1), bf16 out ----------------
// grid (625, 2), block 256 (4 waves). Rows flat 0..40000 (b*10000+n).
__global__ __launch_bounds__(256) void z_gemm_kernel(
    const unsigned short* __restrict__ h_hi, const unsigned short* __restrict__ wb1,
    const float* __restrict__ eb1, unsigned short* __restrict__ Z)
{
  const int si = blockIdx.y;
  const int r0 = blockIdx.x * 64;
  const int t = threadIdx.x;
  const int w = t >> 6, lane = t & 63;
  const int q = lane >> 4, col = lane & 15;

  floatx4 acc[4][4];
  #pragma unroll
  for (int mi=0;mi<4;mi++)
    #pragma unroll
    for (int ni=0;ni<4;ni++) acc[mi][ni] = (floatx4){0.f,0.f,0.f,0.f};

  const unsigned short* wt = wb1 + (size_t)si*65536;
  for (int k0=0;k0<DIM;k0+=32){
    bf16x8 a[4], bf[4];
    #pragma unroll
    for (int mi=0;mi<4;mi++)
      a[mi] = *(const bf16x8*)&h_hi[((size_t)(r0 + mi*16 + col))*256 + k0 + q*8];
    #pragma unroll
    for (int ni=0;ni<4;ni++)
      bf[ni] = *(const bf16x8*)&wt[(size_t)(w*64 + ni*16 + col)*256 + k0 + q*8];
    #pragma unroll
    for (int mi=0;mi<4;mi++)
      #pragma unroll
      for (int ni=0;ni<4;ni++)
        acc[mi][ni] = __builtin_amdgcn_mfma_f32_16x16x32_bf16(a[mi], bf[ni], acc[mi][ni], 0,0,0);
  }

  float b1v[4];
  #pragma unroll
  for (int ni=0;ni<4;ni++) b1v[ni] = eb1[si*256 + w*64 + ni*16 + col];
  #pragma unroll
  for (int mi=0;mi<4;mi++)
    #pragma unroll
    for (int rr=0;rr<4;rr++){
      size_t row = (size_t)(r0 + mi*16 + q*4 + rr);
      #pragma unroll
      for (int ni=0;ni<4;ni++){
        float v = leakyf(acc[mi][ni][rr] + b1v[ni]);
        Z[((size_t)si*40000 + row)*256 + w*64 + ni*16 + col] = f2bf_u(v);
      }
    }
}

// ---------------- CSR aggregate: S[b,d,si,:] = sum_{e: dst=d} Z[si, b, src] ----------------
// grid (2500, 8), block 256 = 4 waves; wave w handles node d = blockIdx.x*4+w.
__global__ __launch_bounds__(256) void aggregate_kernel(
    const unsigned short* __restrict__ Z, const int* __restrict__ ssrc,
    const int* __restrict__ off, unsigned short* __restrict__ S_hi, unsigned short* __restrict__ S_lo)
{
  const int g = blockIdx.y;
  const int b = g >> 1, si = g & 1;
  const int w = threadIdx.x >> 6, lane = threadIdx.x & 63;
  const int d = blockIdx.x*4 + w;
  const int j0 = off[g*(NNODES+1) + d];
  const int j1 = off[g*(NNODES+1) + d + 1];
  const unsigned short* zb = Z + ((size_t)si*40000 + b*10000)*256 + lane*4;
  const int* sp = ssrc + (size_t)g*NEDGES;

  float a0=0.f, a1=0.f, a2=0.f, a3=0.f;
  int j = j0;
  for (; j+4 <= j1; j+=4){
    int s0=sp[j], s1=sp[j+1], s2=sp[j+2], s3=sp[j+3];
    ushort4 u0 = *(const ushort4*)&zb[(size_t)s0*256];
    ushort4 u1 = *(const ushort4*)&zb[(size_t)s1*256];
    ushort4 u2 = *(const ushort4*)&zb[(size_t)s2*256];
    ushort4 u3 = *(const ushort4*)&zb[(size_t)s3*256];
    a0 += bfdec(u0.x)+bfdec(u1.x)+bfdec(u2.x)+bfdec(u3.x);
    a1 += bfdec(u0.y)+bfdec(u1.y)+bfdec(u2.y)+bfdec(u3.y);
    a2 += bfdec(u0.z)+bfdec(u1.z)+bfdec(u2.z)+bfdec(u3.z);
    a3 += bfdec(u0.w)+bfdec(u1.w)+bfdec(u2.w)+bfdec(u3.w);
  }
  for (; j < j1; j++){
    ushort4 u = *(const ushort4*)&zb[(size_t)sp[j]*256];
    a0 += bfdec(u.x); a1 += bfdec(u.y); a2 += bfdec(u.z); a3 += bfdec(u.w);
  }
  size_t so = ((size_t)(b*10000 + d)*2 + si)*256 + lane*4;
  ushort4 h, l;
  h.x = f2bf_u(a0); l.x = f2bf_u(a0 - bfdec(h.x));
  h.y = f2bf_u(a1); l.y = f2bf_u(a1 - bfdec(h.y));
  h.z = f2bf_u(a2); l.z = f2bf_u(a2 - bfdec(h.z));
  h.w = f2bf_u(a3); l.w = f2bf_u(a3 - bfdec(h.w));
  *(ushort4*)&S_hi[so] = h;
  *(ushort4*)&S_lo[so] = l;
}

// ---------------- incoming = S @ W2cat^T + deg0*b2[0] + deg1*b2[1], split-bf16 out ----------
// S viewed flat as [40000][512] (hi/lo). W2cat [256][512] (hi/lo). 3-term MFMA.
// grid (625), block 256. Writes i_hi/i_lo (GRU input) directly.
__global__ __launch_bounds__(256) void w2_gemm_kernel(
    const unsigned short* __restrict__ S_hi, const unsigned short* __restrict__ S_lo,
    const unsigned short* __restrict__ Wc_hi, const unsigned short* __restrict__ Wc_lo,
    const float* __restrict__ eb2, const int* __restrict__ off,
    unsigned short* __restrict__ i_hi, unsigned short* __restrict__ i_lo)
{
  const int t = threadIdx.x;
  const int w = t >> 6, lane = t & 63;
  const int q = lane >> 4, col = lane & 15;
  const int r0 = blockIdx.x * 64;

  floatx4 acc[4][4];
  #pragma unroll
  for (int mi=0;mi<4;mi++)
    #pragma unroll
    for (int ni=0;ni<4;ni++) acc[mi][ni] = (floatx4){0.f,0.f,0.f,0.f};

  for (int k0=0;k0<512;k0+=32){
    bf16x8 ahi[4], alo[4], bhi[4], blo[4];
    #pragma unroll
    for (int mi=0;mi<4;mi++){
      size_t base = ((size_t)(r0 + mi*16 + col))*512 + k0 + q*8;
      ahi[mi] = *(const bf16x8*)&S_hi[base];
      alo[mi] = *(const bf16x8*)&S_lo[base];
    }
    #pragma unroll
    for (int ni=0;ni<4;ni++){
      size_t wb = ((size_t)(w*64 + ni*16 + col))*512 + k0 + q*8;
      bhi[ni] = *(const bf16x8*)&Wc_hi[wb];
      blo[ni] = *(const bf16x8*)&Wc_lo[wb];
    }
    #pragma unroll
    for (int mi=0;mi<4;mi++)
      #pragma unroll
      for (int ni=0;ni<4;ni++){
        acc[mi][ni] = __builtin_amdgcn_mfma_f32_16x16x32_bf16(ahi[mi], bhi[ni], acc[mi][ni], 0,0,0);
        acc[mi][ni] = __builtin_amdgcn_mfma_f32_16x16x32_bf16(ahi[mi], blo[ni], acc[mi][ni], 0,0,0);
        acc[mi][ni] = __builtin_amdgcn_mfma_f32_16x16x32_bf16(alo[mi], bhi[ni], acc[mi][ni], 0,0,0);
      }
  }

  float b20[4], b21[4];
  #pragma unroll
  for (int ni=0;ni<4;ni++){
    b20[ni] = eb2[w*64 + ni*16 + col];
    b21[ni] = eb2[256 + w*64 + ni*16 + col];
  }
  #pragma unroll
  for (int mi=0;mi<4;mi++)
    #pragma unroll
    for (int rr=0;rr<4;rr++){
      int r = r0 + mi*16 + q*4 + rr;
      int b = r / 10000, d = r - b*10000;
      int o0 = (b*2)*(NNODES+1) + d;
      int o1 = (b*2+1)*(NNODES+1) + d;
      float dg0 = (float)(off[o0+1] - off[o0]);
      float dg1 = (float)(off[o1+1] - off[o1]);
      #pragma unroll
      for (int ni=0;ni<4;ni++){
        float v = acc[mi][ni][rr] + dg0*b20[ni] + dg1*b21[ni];
        unsigned short hv = f2bf_u(v);
        size_t oo = (size_t)r*256 + w*64 + ni*16 + col;
        i_hi[oo] = hv;
        i_lo[oo] = f2bf_u(v - bfdec(hv));
      }
    }
}

// ---------------- GRU GEMM: C = A @ W^T + bias, split-bf16 (3 MFMA), K=256 ----------------
__global__ __launch_bounds__(256) void gru_gemm_kernel(
    const unsigned short* __restrict__ Ahi, const unsigned short* __restrict__ Alo,
    const unsigned short* __restrict__ Whi, const unsigned short* __restrict__ Wlo,
    const float* __restrict__ bias, float* __restrict__ C)
{
  const int t = threadIdx.x;
  const int w = t >> 6, lane = t & 63;
  const int q = lane >> 4, col = lane & 15;
  const int r0 = blockIdx.x * 64;
  const int colOff = blockIdx.y * 256;

  floatx4 acc[4][4];
  #pragma unroll
  for (int mi=0;mi<4;mi++)
    #pragma unroll
    for (int ni=0;ni<4;ni++) acc[mi][ni] = (floatx4){0.f,0.f,0.f,0.f};

  for (int k0=0;k0<DIM;k0+=32){
    bf16x8 ahi[4], alo[4], bhi[4], blo[4];
    #pragma unroll
    for (int mi=0;mi<4;mi++){
      size_t base = ((size_t)(r0 + mi*16 + col))*256 + k0 + q*8;
      ahi[mi] = *(const bf16x8*)&Ahi[base];
      alo[mi] = *(const bf16x8*)&Alo[base];
    }
    #pragma unroll
    for (int ni=0;ni<4;ni++){
      size_t wb = ((size_t)(colOff + w*64 + ni*16 + col))*256 + k0 + q*8;
      bhi[ni] = *(const bf16x8*)&Whi[wb];
      blo[ni] = *(const bf16x8*)&Wlo[wb];
    }
    #pragma unroll
    for (int mi=0;mi<4;mi++)
      #pragma unroll
      for (int ni=0;ni<4;ni++){
        acc[mi][ni] = __builtin_amdgcn_mfma_f32_16x16x32_bf16(ahi[mi], bhi[ni], acc[mi][ni], 0,0,0);
        acc[mi][ni] = __builtin_amdgcn_mfma_f32_16x16x32_bf16(ahi[mi], blo[ni], acc[mi][ni], 0,0,0);
        acc[mi][ni] = __builtin_amdgcn_mfma_f32_16x16x32_bf16(alo[mi], bhi[ni], acc[mi][ni], 0,0,0);
      }
  }

  float bb[4];
  #pragma unroll
  for (int ni=0;ni<4;ni++) bb[ni] = bias[colOff + w*64 + ni*16 + col];
  #pragma unroll
  for (int mi=0;mi<4;mi++)
    #pragma unroll
    for (int rr=0;rr<4;rr++){
      size_t row = (size_t)(r0 + mi*16 + q*4 + rr);
      #pragma unroll
      for (int ni=0;ni<4;ni++)
        C[row*768 + colOff + w*64 + ni*16 + col] = acc[mi][ni][rr] + bb[ni];
    }
}

// gate: h' = (1-z)*n + z*h ; h stored as bf16 (hi,lo) pair
__global__ void gate_kernel(const float* __restrict__ gi, const float* __restrict__ gh,
                            unsigned short* __restrict__ hhi, unsigned short* __restrict__ hlo)
{
  int idx = blockIdx.x*256 + threadIdx.x;
  int r = idx >> 8, d = idx & 255;
  size_t base = (size_t)r*768;
  float ir = gi[base + d];
  float iz = gi[base + 256 + d];
  float inn= gi[base + 512 + d];
  float hr = gh[base + d];
  float hz = gh[base + 256 + d];
  float hn = gh[base + 512 + d];
  float hv = bfdec(hhi[idx]) + bfdec(hlo[idx]);
  float rg = sigmoidf_(ir+hr);
  float zg = sigmoidf_(iz+hz);
  float ng = tanhf(inn + rg*hn);
  float hnew = (1.f-zg)*ng + zg*hv;
  unsigned short hi = f2bf_u(hnew);
  hhi[idx] = hi;
  hlo[idx] = f2bf_u(hnew - bfdec(hi));
}

__global__ void reduce_kernel(const unsigned short* __restrict__ hhi,
                              const unsigned short* __restrict__ hlo,
                              float* __restrict__ sbuf){
  int b  = blockIdx.x / 50;
  int s0 = (blockIdx.x % 50) * 200;
  int d  = threadIdx.x;
  size_t off = ((size_t)b*NNODES + s0)*DIM + d;
  float acc = 0.f;
  for (int i=0;i<200;i++){
    acc += bfdec(hhi[off]) + bfdec(hlo[off]);
    off += DIM;
  }
  atomicAdd(&sbuf[b*DIM + d], acc);
}

__global__ __launch_bounds__(320) void head_kernel(
    const float* __restrict__ sbuf, const float* __restrict__ pt,
    const float* __restrict__ fc1w, const float* __restrict__ fc1b,
    const float* __restrict__ fc2w, const float* __restrict__ fc2b,
    const float* __restrict__ fc3w, const float* __restrict__ fc3b,
    float* __restrict__ out)
{
  __shared__ float L[4][257];
  __shared__ float T1[4][80];
  __shared__ float T2[4][80];
  __shared__ float fmx[4];
  int t = threadIdx.x;
  if (t < 256){
    for (int b=0;b<4;b++){
      float v = sbuf[b*DIM + t];
      float ll = logf(v);
      if (ll != ll) ll = 0.f;
      ll = fmaxf(ll, 0.f);
      L[b][t] = ll;
    }
  }
  __syncthreads();
  int w = t >> 6, lane = t & 63;
  if (w < 4){
    float m = -INFINITY;
    for (int i=lane;i<256;i+=64){ float v = L[w][i]; if (v != INFINITY) m = fmaxf(m, v); }
    #pragma unroll
    for (int o=32;o>=1;o>>=1) m = fmaxf(m, __shfl_xor(m, o, 64));
    if (lane==0) fmx[w] = m;
  }
  __syncthreads();
  if (t < 256){
    for (int b=0;b<4;b++) if (L[b][t] == INFINITY) L[b][t] = fmx[b];
  }
  if (t < 4) L[t][256] = pt[t];
  __syncthreads();
  if (t < 320){
    int b = t/80, i = t%80;
    float a = fc1b[i];
    for (int k=0;k<257;k++) a += L[b][k]*fc1w[i*257+k];
    T1[b][i] = leakyf(a);
  }
  __syncthreads();
  if (t < 320){
    int b = t/80, i = t%80;
    float a = fc2b[i];
    for (int k=0;k<80;k++) a += T1[b][k]*fc2w[i*80+k];
    T2[b][i] = leakyf(a);
  }
  __syncthreads();
  if (t < 40){
    int b = t/10, i = t%10;
    float a = fc3b[i];
    for (int k=0;k<80;k++) a += T2[b][k]*fc3w[i*80+k];
    out[b*10+i] = a;
  }
}

extern "C" void kernel_launch(void* const* d_in, const int* in_sizes, int n_in,
                              void* d_out, int out_size, void* d_ws, size_t ws_size,
                              hipStream_t stream) {
  const float* nodes = (const float*)d_in[0];
  const int*   edges = (const int*)d_in[1];
  const float* pt    = (const float*)d_in[2];
  const float* w_ih  = (const float*)d_in[3];
  const float* w_hh  = (const float*)d_in[4];
  const float* b_ih  = (const float*)d_in[5];
  const float* b_hh  = (const float*)d_in[6];
  const float* ew1   = (const float*)d_in[7];
  const float* eb1   = (const float*)d_in[8];
  const float* ew2   = (const float*)d_in[9];
  const float* eb2   = (const float*)d_in[10];
  const float* fc1w  = (const float*)d_in[11];
  const float* fc1b  = (const float*)d_in[12];
  const float* fc2w  = (const float*)d_in[13];
  const float* fc2b  = (const float*)d_in[14];
  const float* fc3w  = (const float*)d_in[15];
  const float* fc3b  = (const float*)d_in[16];

  const size_t HN = (size_t)BATCH*NNODES*DIM;     // 10,240,000
  char* p = (char*)d_ws;
  float* sbuf = (float*)p;                        p += BATCH*DIM*4;
  unsigned short* h_hi = (unsigned short*)p;      p += HN*2;
  unsigned short* h_lo = (unsigned short*)p;      p += HN*2;
  unsigned short* i_hi = (unsigned short*)p;      p += HN*2;
  unsigned short* i_lo = (unsigned short*)p;      p += HN*2;
  unsigned short* Zb   = (unsigned short*)p;      p += 2*HN*2;     // [si][b*10000+n][256]
  unsigned short* S_hi = (unsigned short*)p;      p += 2*HN*2;     // flat [40000][512]
  unsigned short* S_lo = (unsigned short*)p;      p += 2*HN*2;
  unsigned short* wb1  = (unsigned short*)p;      p += 2*65536*2;
  unsigned short* w2c_hi = (unsigned short*)p;    p += 256*512*2;
  unsigned short* w2c_lo = (unsigned short*)p;    p += 256*512*2;
  unsigned short* wih_hi = (unsigned short*)p;    p += 768*256*2;
  unsigned short* wih_lo = (unsigned short*)p;    p += 768*256*2;
  unsigned short* whh_hi = (unsigned short*)p;    p += 768*256*2;
  unsigned short* whh_lo = (unsigned short*)p;    p += 768*256*2;
  int* off  = (int*)p;                            p += NG*(NNODES+1)*4;
  int* cur  = (int*)p;                            p += NG*NNODES*4;
  int* ssrc = (int*)p;                            p += (size_t)NG*NEDGES*4;
  float* gi = (float*)p;

  size_t usedB = (size_t)(p - (char*)d_ws);
  size_t availf = (ws_size > usedB) ? (ws_size - usedB)/4 : 0;
  const int opts[5] = {40000, 8000, 1600, 320, 64};
  int chunk = 64;
  for (int i=0;i<5;i++){ if ((size_t)opts[i]*1536 <= availf){ chunk = opts[i]; break; } }
  float* gh = gi + (size_t)chunk*768;
  int nch = (BATCH*NNODES) / chunk;

  // weights
  f2bf_kernel<<<128,256,0,stream>>>(ew1, wb1, 2*DIM*DIM/4);
  w2cat_kernel<<<512,256,0,stream>>>(ew2, w2c_hi, w2c_lo);
  f2bf_split_kernel<<<192,256,0,stream>>>(w_ih, wih_hi, wih_lo, 768*256/4);
  f2bf_split_kernel<<<192,256,0,stream>>>(w_hh, whh_hi, whh_lo, 768*256/4);

  // h0
  f2bf_split_kernel<<<(int)(HN/4/256),256,0,stream>>>(nodes, h_hi, h_lo, (int)(HN/4));

  // counting sort (CSR) of edges by dst, per stream g
  hipMemsetAsync(cur, 0, NG*NNODES*sizeof(int), stream);
  hist_kernel<<<(NG*NEDGES)/256,256,0,stream>>>(edges, cur);
  scan_kernel<<<NG,256,0,stream>>>(cur, off);
  hipMemsetAsync(cur, 0, NG*NNODES*sizeof(int), stream);
  scatter_kernel<<<(NG*NEDGES)/256,256,0,stream>>>(edges, off, cur, ssrc);

  hipMemsetAsync(sbuf, 0, BATCH*DIM*sizeof(float), stream);

  for (int pass=0; pass<6; pass++){
    z_gemm_kernel<<<dim3(625,2),256,0,stream>>>(h_hi, wb1, eb1, Zb);
    aggregate_kernel<<<dim3(2500,NG),256,0,stream>>>(Zb, ssrc, off, S_hi, S_lo);
    w2_gemm_kernel<<<625,256,0,stream>>>(S_hi, S_lo, w2c_hi, w2c_lo, eb2, off, i_hi, i_lo);
    for (int c=0;c<nch;c++){
      size_t r0c = (size_t)c*chunk;
      gru_gemm_kernel<<<dim3(chunk/64,3),256,0,stream>>>(i_hi + r0c*DIM, i_lo + r0c*DIM,
                                                         wih_hi, wih_lo, b_ih, gi);
      gru_gemm_kernel<<<dim3(chunk/64,3),256,0,stream>>>(h_hi + r0c*DIM, h_lo + r0c*DIM,
                                                         whh_hi, whh_lo, b_hh, gh);
      gate_kernel<<<chunk,256,0,stream>>>(gi, gh, h_hi + r0c*DIM, h_lo + r0c*DIM);
    }
  }
  reduce_kernel<<<200,256,0,stream>>>(h_hi, h_lo, sbuf);
  head_kernel<<<1,320,0,stream>>>(sbuf, pt, fc1w,fc1b,fc2w,fc2b,fc3w,fc3b,(float*)d_out);
}

// Round 5
// 3621.413 us; speedup vs baseline: 11.7158x; 1.1125x over previous
//
#include <hip/hip_runtime.h>
#include <math.h>

#define NNODES 10000
#define NEDGES 160000
#define DIM    256
#define BATCH  4
#define NG     8          // BATCH * S streams

typedef __attribute__((ext_vector_type(8))) __bf16 bf16x8;
typedef __attribute__((ext_vector_type(4))) float  floatx4;

__device__ __forceinline__ float leakyf(float x){ return x > 0.f ? x : 0.01f*x; }
__device__ __forceinline__ float sigmoidf_(float x){ return 1.f/(1.f+expf(-x)); }
__device__ __forceinline__ unsigned short f2bf_u(float x){
  unsigned int u = __float_as_uint(x);
  u += 0x7fffu + ((u >> 16) & 1u);
  return (unsigned short)(u >> 16);
}
__device__ __forceinline__ float bfdec(unsigned short u){
  return __uint_as_float(((unsigned int)u) << 16);
}

// fp32 -> bf16 (RNE), vectorized x4
__global__ void f2bf_kernel(const float* __restrict__ in, unsigned short* __restrict__ out, int n4){
  int i = blockIdx.x*256 + threadIdx.x;
  if (i < n4){
    float4 v = ((const float4*)in)[i];
    ushort4 o;
    o.x = f2bf_u(v.x); o.y = f2bf_u(v.y); o.z = f2bf_u(v.z); o.w = f2bf_u(v.w);
    ((ushort4*)out)[i] = o;
  }
}

// fp32 -> (hi, lo) bf16 pair
__global__ void f2bf_split_kernel(const float* __restrict__ in,
                                  unsigned short* __restrict__ hi,
                                  unsigned short* __restrict__ lo, int n4){
  int i = blockIdx.x*256 + threadIdx.x;
  if (i < n4){
    float4 v = ((const float4*)in)[i];
    ushort4 h, l;
    h.x = f2bf_u(v.x); l.x = f2bf_u(v.x - bfdec(h.x));
    h.y = f2bf_u(v.y); l.y = f2bf_u(v.y - bfdec(h.y));
    h.z = f2bf_u(v.z); l.z = f2bf_u(v.z - bfdec(h.z));
    h.w = f2bf_u(v.w); l.w = f2bf_u(v.w - bfdec(h.w));
    ((ushort4*)hi)[i] = h;
    ((ushort4*)lo)[i] = l;
  }
}

// W2cat[n][si*256+k] = ew2[si][n][k], split hi/lo
__global__ void w2cat_kernel(const float* __restrict__ ew2,
                             unsigned short* __restrict__ hi, unsigned short* __restrict__ lo){
  int idx = blockIdx.x*256 + threadIdx.x;           // 131072
  int n = idx >> 9, kk = idx & 511;
  int si = kk >> 8, k = kk & 255;
  float v = ew2[si*65536 + n*256 + k];
  unsigned short h = f2bf_u(v);
  hi[idx] = h; lo[idx] = f2bf_u(v - bfdec(h));
}

// ---------------- edge sort (counting sort by dst, per stream g) ----------------
__global__ void hist_kernel(const int* __restrict__ edges, int* __restrict__ cnt){
  int idx = blockIdx.x*256 + threadIdx.x;
  if (idx < NG*NEDGES){
    int g = idx / NEDGES, e = idx - g*NEDGES;
    int d = edges[((size_t)g*NEDGES + e)*2];
    atomicAdd(&cnt[g*NNODES + d], 1);
  }
}

__global__ __launch_bounds__(256) void scan_kernel(const int* __restrict__ cnt, int* __restrict__ off){
  __shared__ int sc[256];
  int g = blockIdx.x, t = threadIdx.x;
  int base = 0;
  for (int c=0;c<40;c++){
    int i = c*256 + t;
    int v = (i < NNODES) ? cnt[g*NNODES + i] : 0;
    __syncthreads();
    sc[t] = v;
    __syncthreads();
    for (int o=1;o<256;o<<=1){
      int u = (t>=o) ? sc[t-o] : 0;
      __syncthreads();
      sc[t] += u;
      __syncthreads();
    }
    if (i < NNODES) off[g*(NNODES+1) + i] = base + sc[t] - v;
    base += sc[255];
  }
  if (t == 0) off[g*(NNODES+1) + NNODES] = base;
}

__global__ void scatter_kernel(const int* __restrict__ edges, const int* __restrict__ off,
                               int* __restrict__ cur, int* __restrict__ ssrc){
  int idx = blockIdx.x*256 + threadIdx.x;
  if (idx < NG*NEDGES){
    int g = idx / NEDGES, e = idx - g*NEDGES;
    const int* ep = &edges[((size_t)g*NEDGES + e)*2];
    int d = ep[0], s = ep[1];
    int pos = off[g*(NNODES+1) + d] + atomicAdd(&cur[g*NNODES + d], 1);
    ssrc[g*NEDGES + pos] = s;
  }
}

// ---------------- Z = leaky(h @ W1^T + b1), bf16 out. 32-row tiles ----------------
__global__ __launch_bounds__(256) void z_gemm_kernel(
    const unsigned short* __restrict__ h_hi, const unsigned short* __restrict__ wb1,
    const float* __restrict__ eb1, unsigned short* __restrict__ Z)
{
  const int si = blockIdx.y;
  const int r0 = blockIdx.x * 32;
  const int t = threadIdx.x;
  const int w = t >> 6, lane = t & 63;
  const int q = lane >> 4, col = lane & 15;

  floatx4 acc[2][4];
  #pragma unroll
  for (int mi=0;mi<2;mi++)
    #pragma unroll
    for (int ni=0;ni<4;ni++) acc[mi][ni] = (floatx4){0.f,0.f,0.f,0.f};

  const unsigned short* wt = wb1 + (size_t)si*65536;
  for (int k0=0;k0<DIM;k0+=32){
    bf16x8 a[2], bf[4];
    #pragma unroll
    for (int mi=0;mi<2;mi++)
      a[mi] = *(const bf16x8*)&h_hi[((size_t)(r0 + mi*16 + col))*256 + k0 + q*8];
    #pragma unroll
    for (int ni=0;ni<4;ni++)
      bf[ni] = *(const bf16x8*)&wt[(size_t)(w*64 + ni*16 + col)*256 + k0 + q*8];
    #pragma unroll
    for (int mi=0;mi<2;mi++)
      #pragma unroll
      for (int ni=0;ni<4;ni++)
        acc[mi][ni] = __builtin_amdgcn_mfma_f32_16x16x32_bf16(a[mi], bf[ni], acc[mi][ni], 0,0,0);
  }

  float b1v[4];
  #pragma unroll
  for (int ni=0;ni<4;ni++) b1v[ni] = eb1[si*256 + w*64 + ni*16 + col];
  #pragma unroll
  for (int mi=0;mi<2;mi++)
    #pragma unroll
    for (int rr=0;rr<4;rr++){
      size_t row = (size_t)(r0 + mi*16 + q*4 + rr);
      #pragma unroll
      for (int ni=0;ni<4;ni++){
        float v = leakyf(acc[mi][ni][rr] + b1v[ni]);
        Z[((size_t)si*40000 + row)*256 + w*64 + ni*16 + col] = f2bf_u(v);
      }
    }
}

// ---------------- CSR aggregate: S[b,d][si*256+:] = sum Z[si,b,src], bf16 out ------------
__global__ __launch_bounds__(256) void aggregate_kernel(
    const unsigned short* __restrict__ Z, const int* __restrict__ ssrc,
    const int* __restrict__ off, unsigned short* __restrict__ Sb)
{
  const int g = blockIdx.y;
  const int b = g >> 1, si = g & 1;
  const int w = threadIdx.x >> 6, lane = threadIdx.x & 63;
  const int d = blockIdx.x*4 + w;
  const int j0 = off[g*(NNODES+1) + d];
  const int j1 = off[g*(NNODES+1) + d + 1];
  const unsigned short* zb = Z + ((size_t)si*40000 + b*10000)*256 + lane*4;
  const int* sp = ssrc + (size_t)g*NEDGES;

  float a0=0.f, a1=0.f, a2=0.f, a3=0.f;
  int j = j0;
  for (; j+4 <= j1; j+=4){
    int s0=sp[j], s1=sp[j+1], s2=sp[j+2], s3=sp[j+3];
    ushort4 u0 = *(const ushort4*)&zb[(size_t)s0*256];
    ushort4 u1 = *(const ushort4*)&zb[(size_t)s1*256];
    ushort4 u2 = *(const ushort4*)&zb[(size_t)s2*256];
    ushort4 u3 = *(const ushort4*)&zb[(size_t)s3*256];
    a0 += bfdec(u0.x)+bfdec(u1.x)+bfdec(u2.x)+bfdec(u3.x);
    a1 += bfdec(u0.y)+bfdec(u1.y)+bfdec(u2.y)+bfdec(u3.y);
    a2 += bfdec(u0.z)+bfdec(u1.z)+bfdec(u2.z)+bfdec(u3.z);
    a3 += bfdec(u0.w)+bfdec(u1.w)+bfdec(u2.w)+bfdec(u3.w);
  }
  for (; j < j1; j++){
    ushort4 u = *(const ushort4*)&zb[(size_t)sp[j]*256];
    a0 += bfdec(u.x); a1 += bfdec(u.y); a2 += bfdec(u.z); a3 += bfdec(u.w);
  }
  size_t so = ((size_t)(b*10000 + d)*2 + si)*256 + lane*4;
  ushort4 h;
  h.x = f2bf_u(a0); h.y = f2bf_u(a1); h.z = f2bf_u(a2); h.w = f2bf_u(a3);
  *(ushort4*)&Sb[so] = h;
}

// ------------- incoming = S @ W2cat^T + deg·b2, 2-term, bf16 out. 32-row tiles ------------
__global__ __launch_bounds__(256) void w2_gemm_kernel(
    const unsigned short* __restrict__ Sb,
    const unsigned short* __restrict__ Wc_hi, const unsigned short* __restrict__ Wc_lo,
    const float* __restrict__ eb2, const int* __restrict__ off,
    unsigned short* __restrict__ ib)
{
  const int t = threadIdx.x;
  const int w = t >> 6, lane = t & 63;
  const int q = lane >> 4, col = lane & 15;
  const int r0 = blockIdx.x * 32;

  floatx4 acc[2][4];
  #pragma unroll
  for (int mi=0;mi<2;mi++)
    #pragma unroll
    for (int ni=0;ni<4;ni++) acc[mi][ni] = (floatx4){0.f,0.f,0.f,0.f};

  for (int k0=0;k0<512;k0+=32){
    bf16x8 a[2], bhi[4], blo[4];
    #pragma unroll
    for (int mi=0;mi<2;mi++)
      a[mi] = *(const bf16x8*)&Sb[((size_t)(r0 + mi*16 + col))*512 + k0 + q*8];
    #pragma unroll
    for (int ni=0;ni<4;ni++){
      size_t wb = ((size_t)(w*64 + ni*16 + col))*512 + k0 + q*8;
      bhi[ni] = *(const bf16x8*)&Wc_hi[wb];
      blo[ni] = *(const bf16x8*)&Wc_lo[wb];
    }
    #pragma unroll
    for (int mi=0;mi<2;mi++)
      #pragma unroll
      for (int ni=0;ni<4;ni++){
        acc[mi][ni] = __builtin_amdgcn_mfma_f32_16x16x32_bf16(a[mi], bhi[ni], acc[mi][ni], 0,0,0);
        acc[mi][ni] = __builtin_amdgcn_mfma_f32_16x16x32_bf16(a[mi], blo[ni], acc[mi][ni], 0,0,0);
      }
  }

  float b20[4], b21[4];
  #pragma unroll
  for (int ni=0;ni<4;ni++){
    b20[ni] = eb2[w*64 + ni*16 + col];
    b21[ni] = eb2[256 + w*64 + ni*16 + col];
  }
  #pragma unroll
  for (int mi=0;mi<2;mi++)
    #pragma unroll
    for (int rr=0;rr<4;rr++){
      int r = r0 + mi*16 + q*4 + rr;
      int b = r / 10000, d = r - b*10000;
      int o0 = (b*2)*(NNODES+1) + d;
      int o1 = (b*2+1)*(NNODES+1) + d;
      float dg0 = (float)(off[o0+1] - off[o0]);
      float dg1 = (float)(off[o1+1] - off[o1]);
      #pragma unroll
      for (int ni=0;ni<4;ni++){
        float v = acc[mi][ni][rr] + dg0*b20[ni] + dg1*b21[ni];
        ib[(size_t)r*256 + w*64 + ni*16 + col] = f2bf_u(v);
      }
    }
}

// ---------- GRU GEMMs fused: z-dim picks (gi = ib@Wih^T) or (gh = h@Whh^T); bf16 out ------
// 2-term (A single bf16, W hi/lo). 32-row tiles. grid (rows/32, 3, 2).
__global__ __launch_bounds__(256) void gru_gemm_kernel(
    const unsigned short* __restrict__ ib, const unsigned short* __restrict__ h_hi,
    const unsigned short* __restrict__ wih_hi, const unsigned short* __restrict__ wih_lo,
    const unsigned short* __restrict__ whh_hi, const unsigned short* __restrict__ whh_lo,
    const float* __restrict__ b_ih, const float* __restrict__ b_hh,
    unsigned short* __restrict__ gi_b, unsigned short* __restrict__ gh_b)
{
  const int which = blockIdx.z;
  const unsigned short* A   = which ? h_hi   : ib;
  const unsigned short* Whi = which ? whh_hi : wih_hi;
  const unsigned short* Wlo = which ? whh_lo : wih_lo;
  const float* bias         = which ? b_hh   : b_ih;
  unsigned short* C         = which ? gh_b   : gi_b;

  const int t = threadIdx.x;
  const int w = t >> 6, lane = t & 63;
  const int q = lane >> 4, col = lane & 15;
  const int r0 = blockIdx.x * 32;
  const int colOff = blockIdx.y * 256;

  floatx4 acc[2][4];
  #pragma unroll
  for (int mi=0;mi<2;mi++)
    #pragma unroll
    for (int ni=0;ni<4;ni++) acc[mi][ni] = (floatx4){0.f,0.f,0.f,0.f};

  for (int k0=0;k0<DIM;k0+=32){
    bf16x8 a[2], bhi[4], blo[4];
    #pragma unroll
    for (int mi=0;mi<2;mi++)
      a[mi] = *(const bf16x8*)&A[((size_t)(r0 + mi*16 + col))*256 + k0 + q*8];
    #pragma unroll
    for (int ni=0;ni<4;ni++){
      size_t wb = ((size_t)(colOff + w*64 + ni*16 + col))*256 + k0 + q*8;
      bhi[ni] = *(const bf16x8*)&Whi[wb];
      blo[ni] = *(const bf16x8*)&Wlo[wb];
    }
    #pragma unroll
    for (int mi=0;mi<2;mi++)
      #pragma unroll
      for (int ni=0;ni<4;ni++){
        acc[mi][ni] = __builtin_amdgcn_mfma_f32_16x16x32_bf16(a[mi], bhi[ni], acc[mi][ni], 0,0,0);
        acc[mi][ni] = __builtin_amdgcn_mfma_f32_16x16x32_bf16(a[mi], blo[ni], acc[mi][ni], 0,0,0);
      }
  }

  float bb[4];
  #pragma unroll
  for (int ni=0;ni<4;ni++) bb[ni] = bias[colOff + w*64 + ni*16 + col];
  #pragma unroll
  for (int mi=0;mi<2;mi++)
    #pragma unroll
    for (int rr=0;rr<4;rr++){
      size_t row = (size_t)(r0 + mi*16 + q*4 + rr);
      #pragma unroll
      for (int ni=0;ni<4;ni++)
        C[row*768 + colOff + w*64 + ni*16 + col] = f2bf_u(acc[mi][ni][rr] + bb[ni]);
    }
}

// gate: h' = (1-z)*n + z*h ; gi/gh bf16, h stored as bf16 (hi,lo)
__global__ void gate_kernel(const unsigned short* __restrict__ gi, const unsigned short* __restrict__ gh,
                            unsigned short* __restrict__ hhi, unsigned short* __restrict__ hlo)
{
  int idx = blockIdx.x*256 + threadIdx.x;
  int r = idx >> 8, d = idx & 255;
  size_t base = (size_t)r*768;
  float ir = bfdec(gi[base + d]);
  float iz = bfdec(gi[base + 256 + d]);
  float inn= bfdec(gi[base + 512 + d]);
  float hr = bfdec(gh[base + d]);
  float hz = bfdec(gh[base + 256 + d]);
  float hn = bfdec(gh[base + 512 + d]);
  float hv = bfdec(hhi[idx]) + bfdec(hlo[idx]);
  float rg = sigmoidf_(ir+hr);
  float zg = sigmoidf_(iz+hz);
  float ng = tanhf(inn + rg*hn);
  float hnew = (1.f-zg)*ng + zg*hv;
  unsigned short hi = f2bf_u(hnew);
  hhi[idx] = hi;
  hlo[idx] = f2bf_u(hnew - bfdec(hi));
}

__global__ void reduce_kernel(const unsigned short* __restrict__ hhi,
                              const unsigned short* __restrict__ hlo,
                              float* __restrict__ sbuf){
  int b  = blockIdx.x / 50;
  int s0 = (blockIdx.x % 50) * 200;
  int d  = threadIdx.x;
  size_t off = ((size_t)b*NNODES + s0)*DIM + d;
  float acc = 0.f;
  for (int i=0;i<200;i++){
    acc += bfdec(hhi[off]) + bfdec(hlo[off]);
    off += DIM;
  }
  atomicAdd(&sbuf[b*DIM + d], acc);
}

__global__ __launch_bounds__(320) void head_kernel(
    const float* __restrict__ sbuf, const float* __restrict__ pt,
    const float* __restrict__ fc1w, const float* __restrict__ fc1b,
    const float* __restrict__ fc2w, const float* __restrict__ fc2b,
    const float* __restrict__ fc3w, const float* __restrict__ fc3b,
    float* __restrict__ out)
{
  __shared__ float L[4][257];
  __shared__ float T1[4][80];
  __shared__ float T2[4][80];
  __shared__ float fmx[4];
  int t = threadIdx.x;
  if (t < 256){
    for (int b=0;b<4;b++){
      float v = sbuf[b*DIM + t];
      float ll = logf(v);
      if (ll != ll) ll = 0.f;
      ll = fmaxf(ll, 0.f);
      L[b][t] = ll;
    }
  }
  __syncthreads();
  int w = t >> 6, lane = t & 63;
  if (w < 4){
    float m = -INFINITY;
    for (int i=lane;i<256;i+=64){ float v = L[w][i]; if (v != INFINITY) m = fmaxf(m, v); }
    #pragma unroll
    for (int o=32;o>=1;o>>=1) m = fmaxf(m, __shfl_xor(m, o, 64));
    if (lane==0) fmx[w] = m;
  }
  __syncthreads();
  if (t < 256){
    for (int b=0;b<4;b++) if (L[b][t] == INFINITY) L[b][t] = fmx[b];
  }
  if (t < 4) L[t][256] = pt[t];
  __syncthreads();
  if (t < 320){
    int b = t/80, i = t%80;
    float a = fc1b[i];
    for (int k=0;k<257;k++) a += L[b][k]*fc1w[i*257+k];
    T1[b][i] = leakyf(a);
  }
  __syncthreads();
  if (t < 320){
    int b = t/80, i = t%80;
    float a = fc2b[i];
    for (int k=0;k<80;k++) a += T1[b][k]*fc2w[i*80+k];
    T2[b][i] = leakyf(a);
  }
  __syncthreads();
  if (t < 40){
    int b = t/10, i = t%10;
    float a = fc3b[i];
    for (int k=0;k<80;k++) a += T2[b][k]*fc3w[i*80+k];
    out[b*10+i] = a;
  }
}

extern "C" void kernel_launch(void* const* d_in, const int* in_sizes, int n_in,
                              void* d_out, int out_size, void* d_ws, size_t ws_size,
                              hipStream_t stream) {
  const float* nodes = (const float*)d_in[0];
  const int*   edges = (const int*)d_in[1];
  const float* pt    = (const float*)d_in[2];
  const float* w_ih  = (const float*)d_in[3];
  const float* w_hh  = (const float*)d_in[4];
  const float* b_ih  = (const float*)d_in[5];
  const float* b_hh  = (const float*)d_in[6];
  const float* ew1   = (const float*)d_in[7];
  const float* eb1   = (const float*)d_in[8];
  const float* ew2   = (const float*)d_in[9];
  const float* eb2   = (const float*)d_in[10];
  const float* fc1w  = (const float*)d_in[11];
  const float* fc1b  = (const float*)d_in[12];
  const float* fc2w  = (const float*)d_in[13];
  const float* fc2b  = (const float*)d_in[14];
  const float* fc3w  = (const float*)d_in[15];
  const float* fc3b  = (const float*)d_in[16];

  const size_t HN = (size_t)BATCH*NNODES*DIM;     // 10,240,000
  char* p = (char*)d_ws;
  float* sbuf = (float*)p;                        p += BATCH*DIM*4;
  unsigned short* h_hi = (unsigned short*)p;      p += HN*2;
  unsigned short* h_lo = (unsigned short*)p;      p += HN*2;
  unsigned short* ib   = (unsigned short*)p;      p += HN*2;      // incoming, bf16
  unsigned short* Zb   = (unsigned short*)p;      p += 2*HN*2;    // [si][b*10000+n][256]
  unsigned short* Sb   = (unsigned short*)p;      p += 2*HN*2;    // flat [40000][512]
  unsigned short* wb1  = (unsigned short*)p;      p += 2*65536*2;
  unsigned short* w2c_hi = (unsigned short*)p;    p += 256*512*2;
  unsigned short* w2c_lo = (unsigned short*)p;    p += 256*512*2;
  unsigned short* wih_hi = (unsigned short*)p;    p += 768*256*2;
  unsigned short* wih_lo = (unsigned short*)p;    p += 768*256*2;
  unsigned short* whh_hi = (unsigned short*)p;    p += 768*256*2;
  unsigned short* whh_lo = (unsigned short*)p;    p += 768*256*2;
  int* off  = (int*)p;                            p += NG*(NNODES+1)*4;
  int* cur  = (int*)p;                            p += NG*NNODES*4;
  int* ssrc = (int*)p;                            p += (size_t)NG*NEDGES*4;
  unsigned short* gi_b = (unsigned short*)p;

  size_t usedB = (size_t)(p - (char*)d_ws);
  size_t availf = (ws_size > usedB) ? (ws_size - usedB)/4 : 0;
  const int opts[5] = {40000, 8000, 1600, 320, 64};
  int chunk = 64;
  for (int i=0;i<5;i++){ if ((size_t)opts[i]*768 <= availf){ chunk = opts[i]; break; } }
  unsigned short* gh_b = gi_b + (size_t)chunk*768;
  int nch = (BATCH*NNODES) / chunk;

  // weights
  f2bf_kernel<<<128,256,0,stream>>>(ew1, wb1, 2*DIM*DIM/4);
  w2cat_kernel<<<512,256,0,stream>>>(ew2, w2c_hi, w2c_lo);
  f2bf_split_kernel<<<192,256,0,stream>>>(w_ih, wih_hi, wih_lo, 768*256/4);
  f2bf_split_kernel<<<192,256,0,stream>>>(w_hh, whh_hi, whh_lo, 768*256/4);

  // h0
  f2bf_split_kernel<<<(int)(HN/4/256),256,0,stream>>>(nodes, h_hi, h_lo, (int)(HN/4));

  // counting sort (CSR) of edges by dst, per stream g
  hipMemsetAsync(cur, 0, NG*NNODES*sizeof(int), stream);
  hist_kernel<<<(NG*NEDGES)/256,256,0,stream>>>(edges, cur);
  scan_kernel<<<NG,256,0,stream>>>(cur, off);
  hipMemsetAsync(cur, 0, NG*NNODES*sizeof(int), stream);
  scatter_kernel<<<(NG*NEDGES)/256,256,0,stream>>>(edges, off, cur, ssrc);

  hipMemsetAsync(sbuf, 0, BATCH*DIM*sizeof(float), stream);

  for (int pass=0; pass<6; pass++){
    z_gemm_kernel<<<dim3(1250,2),256,0,stream>>>(h_hi, wb1, eb1, Zb);
    aggregate_kernel<<<dim3(2500,NG),256,0,stream>>>(Zb, ssrc, off, Sb);
    w2_gemm_kernel<<<1250,256,0,stream>>>(Sb, w2c_hi, w2c_lo, eb2, off, ib);
    for (int c=0;c<nch;c++){
      size_t r0c = (size_t)c*chunk;
      gru_gemm_kernel<<<dim3(chunk/32,3,2),256,0,stream>>>(ib + r0c*DIM, h_hi + r0c*DIM,
                                                           wih_hi, wih_lo, whh_hi, whh_lo,
                                                           b_ih, b_hh, gi_b, gh_b);
      gate_kernel<<<chunk,256,0,stream>>>(gi_b, gh_b, h_hi + r0c*DIM, h_lo + r0c*DIM);
    }
  }
  reduce_kernel<<<200,256,0,stream>>>(h_hi, h_lo, sbuf);
  head_kernel<<<1,320,0,stream>>>(sbuf, pt, fc1w,fc1b,fc2w,fc2b,fc3w,fc3b,(float*)d_out);
}

// Round 6
// 2174.167 us; speedup vs baseline: 19.5145x; 1.6657x over previous
//
#include <hip/hip_runtime.h>
#include <math.h>

#define NNODES 10000
#define NEDGES 160000
#define DIM    256
#define BATCH  4
#define NG     8           // BATCH * S streams
#define MROWS  40064       // 40000 padded to 313*128

typedef __attribute__((ext_vector_type(8))) __bf16 bf16x8;
typedef __attribute__((ext_vector_type(4))) float  floatx4;

__device__ __forceinline__ float leakyf(float x){ return x > 0.f ? x : 0.01f*x; }
__device__ __forceinline__ float sigmoidf_(float x){ return 1.f/(1.f+expf(-x)); }
__device__ __forceinline__ unsigned short f2bf_u(float x){
  unsigned int u = __float_as_uint(x);
  u += 0x7fffu + ((u >> 16) & 1u);
  return (unsigned short)(u >> 16);
}
__device__ __forceinline__ float bfdec(unsigned short u){
  return __uint_as_float(((unsigned int)u) << 16);
}

__device__ __forceinline__ void glds16(unsigned short* lds, const unsigned short* g){
  __builtin_amdgcn_global_load_lds(
      (const __attribute__((address_space(1))) void*)g,
      (__attribute__((address_space(3))) void*)lds, 16, 0, 0);
}

// fp32 -> (hi, lo) bf16 pair
__global__ void f2bf_split_kernel(const float* __restrict__ in,
                                  unsigned short* __restrict__ hi,
                                  unsigned short* __restrict__ lo, int n4){
  int i = blockIdx.x*256 + threadIdx.x;
  if (i < n4){
    float4 v = ((const float4*)in)[i];
    ushort4 h, l;
    h.x = f2bf_u(v.x); l.x = f2bf_u(v.x - bfdec(h.x));
    h.y = f2bf_u(v.y); l.y = f2bf_u(v.y - bfdec(h.y));
    h.z = f2bf_u(v.z); l.z = f2bf_u(v.z - bfdec(h.z));
    h.w = f2bf_u(v.w); l.w = f2bf_u(v.w - bfdec(h.w));
    ((ushort4*)hi)[i] = h;
    ((ushort4*)lo)[i] = l;
  }
}

// ---- weight prep ----
// w1cat[n][k], n in [0,512): rows = [W1[0]; W1[1]]  (1-term bf16)
__global__ void w1cat_kernel(const float* __restrict__ ew1, unsigned short* __restrict__ o){
  int idx = blockIdx.x*256 + threadIdx.x;      // 512*256
  int n = idx >> 8, k = idx & 255;
  o[idx] = f2bf_u(ew1[(n>>8)*65536 + (n&255)*256 + k]);
}
// w2k[n][kp], kp in [0,1024): K' = [hi(si0,si1) | lo(si0,si1)] over S cols
__global__ void w2k_kernel(const float* __restrict__ ew2, unsigned short* __restrict__ o){
  int idx = blockIdx.x*256 + threadIdx.x;      // 256*1024
  int n = idx >> 10, kp = idx & 1023;
  int j = kp & 511, term = kp >> 9;
  int si = j >> 8, k = j & 255;
  float v = ew2[si*65536 + n*256 + k];
  unsigned short h = f2bf_u(v);
  o[idx] = term ? f2bf_u(v - bfdec(h)) : h;
}
// wk2[c][kp], kp in [0,512): K' = [hi | lo] over 256 cols
__global__ void wk2_kernel(const float* __restrict__ w, unsigned short* __restrict__ o){
  int idx = blockIdx.x*256 + threadIdx.x;      // 768*512
  int c = idx >> 9, kp = idx & 511;
  int k = kp & 255, term = kp >> 8;
  float v = w[c*256 + k];
  unsigned short h = f2bf_u(v);
  o[idx] = term ? f2bf_u(v - bfdec(h)) : h;
}

// ---------------- edge sort (counting sort by dst, per stream g) ----------------
__global__ void hist_kernel(const int* __restrict__ edges, int* __restrict__ cnt){
  int idx = blockIdx.x*256 + threadIdx.x;
  if (idx < NG*NEDGES){
    int g = idx / NEDGES, e = idx - g*NEDGES;
    int d = edges[((size_t)g*NEDGES + e)*2];
    atomicAdd(&cnt[g*NNODES + d], 1);
  }
}

__global__ __launch_bounds__(256) void scan_kernel(const int* __restrict__ cnt, int* __restrict__ off){
  __shared__ int sc[256];
  int g = blockIdx.x, t = threadIdx.x;
  int base = 0;
  for (int c=0;c<40;c++){
    int i = c*256 + t;
    int v = (i < NNODES) ? cnt[g*NNODES + i] : 0;
    __syncthreads();
    sc[t] = v;
    __syncthreads();
    for (int o=1;o<256;o<<=1){
      int u = (t>=o) ? sc[t-o] : 0;
      __syncthreads();
      sc[t] += u;
      __syncthreads();
    }
    if (i < NNODES) off[g*(NNODES+1) + i] = base + sc[t] - v;
    base += sc[255];
  }
  if (t == 0) off[g*(NNODES+1) + NNODES] = base;
}

__global__ void scatter_kernel(const int* __restrict__ edges, const int* __restrict__ off,
                               int* __restrict__ cur, int* __restrict__ ssrc){
  int idx = blockIdx.x*256 + threadIdx.x;
  if (idx < NG*NEDGES){
    int g = idx / NEDGES, e = idx - g*NEDGES;
    const int* ep = &edges[((size_t)g*NEDGES + e)*2];
    int d = ep[0], s = ep[1];
    int pos = off[g*(NNODES+1) + d] + atomicAdd(&cur[g*NNODES + d], 1);
    ssrc[g*NEDGES + pos] = s;
  }
}

// ================= 128x128 LDS-staged MFMA core (m97-style) =================
// A: [rows][KA] bf16 (row base pre-offset), k wraps by KA for 2-term.
// W: [cols][KP] bf16 (col base pre-offset).
// LDS: A-tile [128][64] + B-tile [128][64], XOR-swizzled slots:
//   slot j of row r holds global k-elems (j ^ (r&7))*8 .. +8
template<int KP, int KA>
__device__ __forceinline__ void mm128_core(
    const unsigned short* __restrict__ Ab, const unsigned short* __restrict__ Wb,
    unsigned short* lds, floatx4 (&acc)[4][4])
{
  const int t = threadIdx.x;
  const int w = t >> 6, lane = t & 63;
  const int q = lane >> 4, col = lane & 15;
  const int wr = (w & 1)*64, wc = (w >> 1)*64;
  unsigned short* Al = lds;
  unsigned short* Bl = lds + 128*64;

  const int sr = t >> 3;                 // staging row within 32-row group
  const int sj = t & 7;                  // staging 16B slot
  const int sk = ((sj ^ (sr & 7)) * 8);  // global k offset within chunk

  for (int kb = 0; kb < KP; kb += 64){
    #pragma unroll
    for (int i=0;i<4;i++){
      int r = i*32 + sr;
      glds16(&Al[i*2048 + w*512], &Ab[(size_t)r*KA + ((kb + sk) & (KA-1))]);
    }
    #pragma unroll
    for (int i=0;i<4;i++){
      int r = i*32 + sr;
      glds16(&Bl[i*2048 + w*512], &Wb[(size_t)r*KP + kb + sk]);
    }
    __syncthreads();
    #pragma unroll
    for (int ks2=0; ks2<2; ks2++){
      bf16x8 a[4], bf[4];
      #pragma unroll
      for (int mi=0;mi<4;mi++){
        int r = wr + mi*16 + col;
        int j = (ks2*4 + q) ^ (r & 7);
        a[mi] = *(const bf16x8*)&Al[r*64 + j*8];
      }
      #pragma unroll
      for (int ni=0;ni<4;ni++){
        int r = wc + ni*16 + col;
        int j = (ks2*4 + q) ^ (r & 7);
        bf[ni] = *(const bf16x8*)&Bl[r*64 + j*8];
      }
      #pragma unroll
      for (int mi=0;mi<4;mi++)
        #pragma unroll
        for (int ni=0;ni<4;ni++)
          acc[mi][ni] = __builtin_amdgcn_mfma_f32_16x16x32_bf16(a[mi], bf[ni], acc[mi][ni], 0,0,0);
    }
    __syncthreads();
  }
}

// ---- Z = leaky(h @ W1cat^T + b1): grid (313, 4). N=512 -> si = n>>8 ----
__global__ __launch_bounds__(256) void z128_kernel(
    const unsigned short* __restrict__ h_hi, const unsigned short* __restrict__ w1cat,
    const float* __restrict__ eb1, unsigned short* __restrict__ Z)
{
  __shared__ unsigned short lds[16384];
  const int row0 = blockIdx.x*128, col0 = blockIdx.y*128;
  const int t = threadIdx.x, w = t >> 6, lane = t & 63;
  const int q = lane >> 4, col = lane & 15;
  const int wr = (w & 1)*64, wc = (w >> 1)*64;

  floatx4 acc[4][4];
  #pragma unroll
  for (int mi=0;mi<4;mi++)
    #pragma unroll
    for (int ni=0;ni<4;ni++) acc[mi][ni] = (floatx4){0.f,0.f,0.f,0.f};

  mm128_core<256,256>(h_hi + (size_t)row0*256, w1cat + (size_t)col0*256, lds, acc);

  #pragma unroll
  for (int ni=0;ni<4;ni++){
    int n = col0 + wc + ni*16 + col;
    int si = n >> 8, cz = n & 255;
    float bb = eb1[si*256 + cz];
    unsigned short* zp = Z + (size_t)si*MROWS*256 + cz;
    #pragma unroll
    for (int mi=0;mi<4;mi++)
      #pragma unroll
      for (int rr=0;rr<4;rr++){
        int row = row0 + wr + mi*16 + q*4 + rr;
        zp[(size_t)row*256] = f2bf_u(leakyf(acc[mi][ni][rr] + bb));
      }
  }
}

// ---- CSR aggregate: S[b*10000+d][si*256+:] = sum Z[si][b*10000+src][:] ----
__global__ __launch_bounds__(256) void aggregate_kernel(
    const unsigned short* __restrict__ Z, const int* __restrict__ ssrc,
    const int* __restrict__ off, unsigned short* __restrict__ Sb)
{
  const int g = blockIdx.y;
  const int b = g >> 1, si = g & 1;
  const int w = threadIdx.x >> 6, lane = threadIdx.x & 63;
  const int d = blockIdx.x*4 + w;
  const int j0 = off[g*(NNODES+1) + d];
  const int j1 = off[g*(NNODES+1) + d + 1];
  const unsigned short* zb = Z + ((size_t)si*MROWS + b*10000)*256 + lane*4;
  const int* sp = ssrc + (size_t)g*NEDGES;

  float a0=0.f, a1=0.f, a2=0.f, a3=0.f;
  int j = j0;
  for (; j+4 <= j1; j+=4){
    int s0=sp[j], s1=sp[j+1], s2=sp[j+2], s3=sp[j+3];
    ushort4 u0 = *(const ushort4*)&zb[(size_t)s0*256];
    ushort4 u1 = *(const ushort4*)&zb[(size_t)s1*256];
    ushort4 u2 = *(const ushort4*)&zb[(size_t)s2*256];
    ushort4 u3 = *(const ushort4*)&zb[(size_t)s3*256];
    a0 += bfdec(u0.x)+bfdec(u1.x)+bfdec(u2.x)+bfdec(u3.x);
    a1 += bfdec(u0.y)+bfdec(u1.y)+bfdec(u2.y)+bfdec(u3.y);
    a2 += bfdec(u0.z)+bfdec(u1.z)+bfdec(u2.z)+bfdec(u3.z);
    a3 += bfdec(u0.w)+bfdec(u1.w)+bfdec(u2.w)+bfdec(u3.w);
  }
  for (; j < j1; j++){
    ushort4 u = *(const ushort4*)&zb[(size_t)sp[j]*256];
    a0 += bfdec(u.x); a1 += bfdec(u.y); a2 += bfdec(u.z); a3 += bfdec(u.w);
  }
  size_t so = (size_t)(b*10000 + d)*512 + si*256 + lane*4;
  ushort4 h;
  h.x = f2bf_u(a0); h.y = f2bf_u(a1); h.z = f2bf_u(a2); h.w = f2bf_u(a3);
  *(ushort4*)&Sb[so] = h;
}

// ---- ib = S @ W2k^T (2-term via K'=1024) + deg.b2: grid (313, 2) ----
__global__ __launch_bounds__(256) void w2128_kernel(
    const unsigned short* __restrict__ Sb, const unsigned short* __restrict__ w2k,
    const float* __restrict__ eb2, const int* __restrict__ off,
    unsigned short* __restrict__ ib)
{
  __shared__ unsigned short lds[16384];
  const int row0 = blockIdx.x*128, col0 = blockIdx.y*128;
  const int t = threadIdx.x, w = t >> 6, lane = t & 63;
  const int q = lane >> 4, col = lane & 15;
  const int wr = (w & 1)*64, wc = (w >> 1)*64;

  floatx4 acc[4][4];
  #pragma unroll
  for (int mi=0;mi<4;mi++)
    #pragma unroll
    for (int ni=0;ni<4;ni++) acc[mi][ni] = (floatx4){0.f,0.f,0.f,0.f};

  mm128_core<1024,512>(Sb + (size_t)row0*512, w2k + (size_t)col0*1024, lds, acc);

  float b20[4], b21[4];
  #pragma unroll
  for (int ni=0;ni<4;ni++){
    int n = col0 + wc + ni*16 + col;
    b20[ni] = eb2[n];
    b21[ni] = eb2[256 + n];
  }
  #pragma unroll
  for (int mi=0;mi<4;mi++)
    #pragma unroll
    for (int rr=0;rr<4;rr++){
      int row = row0 + wr + mi*16 + q*4 + rr;
      int b = row / 10000, d = row - b*10000;
      float dg0 = 0.f, dg1 = 0.f;
      if (row < 40000){
        int o0 = (b*2)*(NNODES+1) + d;
        int o1 = (b*2+1)*(NNODES+1) + d;
        dg0 = (float)(off[o0+1] - off[o0]);
        dg1 = (float)(off[o1+1] - off[o1]);
      }
      #pragma unroll
      for (int ni=0;ni<4;ni++){
        int n = col0 + wc + ni*16 + col;
        ib[(size_t)row*256 + n] = f2bf_u(acc[mi][ni][rr] + dg0*b20[ni] + dg1*b21[ni]);
      }
    }
}

// ---- GRU GEMMs: gi = ib@Wih^T, gh = h@Whh^T (2-term via K'=512): grid (mb, 6, 2) ----
__global__ __launch_bounds__(256) void gru128_kernel(
    const unsigned short* __restrict__ ib, const unsigned short* __restrict__ h_hi,
    const unsigned short* __restrict__ wihk, const unsigned short* __restrict__ whhk,
    const float* __restrict__ b_ih, const float* __restrict__ b_hh,
    unsigned short* __restrict__ gi_b, unsigned short* __restrict__ gh_b)
{
  __shared__ unsigned short lds[16384];
  const int which = blockIdx.z;
  const unsigned short* A = which ? h_hi : ib;
  const unsigned short* W = which ? whhk : wihk;
  const float* bias        = which ? b_hh : b_ih;
  unsigned short* C        = which ? gh_b : gi_b;

  const int row0 = blockIdx.x*128, col0 = blockIdx.y*128;
  const int t = threadIdx.x, w = t >> 6, lane = t & 63;
  const int q = lane >> 4, col = lane & 15;
  const int wr = (w & 1)*64, wc = (w >> 1)*64;

  floatx4 acc[4][4];
  #pragma unroll
  for (int mi=0;mi<4;mi++)
    #pragma unroll
    for (int ni=0;ni<4;ni++) acc[mi][ni] = (floatx4){0.f,0.f,0.f,0.f};

  mm128_core<512,256>(A + (size_t)row0*256, W + (size_t)col0*512, lds, acc);

  float bb[4];
  #pragma unroll
  for (int ni=0;ni<4;ni++) bb[ni] = bias[col0 + wc + ni*16 + col];
  #pragma unroll
  for (int mi=0;mi<4;mi++)
    #pragma unroll
    for (int rr=0;rr<4;rr++){
      size_t row = (size_t)(row0 + wr + mi*16 + q*4 + rr);
      #pragma unroll
      for (int ni=0;ni<4;ni++)
        C[row*768 + col0 + wc + ni*16 + col] = f2bf_u(acc[mi][ni][rr] + bb[ni]);
    }
}

// gate: h' = (1-z)*n + z*h ; gi/gh bf16, h stored as bf16 (hi,lo)
__global__ void gate_kernel(const unsigned short* __restrict__ gi, const unsigned short* __restrict__ gh,
                            unsigned short* __restrict__ hhi, unsigned short* __restrict__ hlo)
{
  int idx = blockIdx.x*256 + threadIdx.x;
  int r = idx >> 8, d = idx & 255;
  size_t base = (size_t)r*768;
  float ir = bfdec(gi[base + d]);
  float iz = bfdec(gi[base + 256 + d]);
  float inn= bfdec(gi[base + 512 + d]);
  float hr = bfdec(gh[base + d]);
  float hz = bfdec(gh[base + 256 + d]);
  float hn = bfdec(gh[base + 512 + d]);
  float hv = bfdec(hhi[idx]) + bfdec(hlo[idx]);
  float rg = sigmoidf_(ir+hr);
  float zg = sigmoidf_(iz+hz);
  float ng = tanhf(inn + rg*hn);
  float hnew = (1.f-zg)*ng + zg*hv;
  unsigned short hi = f2bf_u(hnew);
  hhi[idx] = hi;
  hlo[idx] = f2bf_u(hnew - bfdec(hi));
}

__global__ void reduce_kernel(const unsigned short* __restrict__ hhi,
                              const unsigned short* __restrict__ hlo,
                              float* __restrict__ sbuf){
  int b  = blockIdx.x / 50;
  int s0 = (blockIdx.x % 50) * 200;
  int d  = threadIdx.x;
  size_t off = ((size_t)b*NNODES + s0)*DIM + d;
  float acc = 0.f;
  for (int i=0;i<200;i++){
    acc += bfdec(hhi[off]) + bfdec(hlo[off]);
    off += DIM;
  }
  atomicAdd(&sbuf[b*DIM + d], acc);
}

__global__ __launch_bounds__(320) void head_kernel(
    const float* __restrict__ sbuf, const float* __restrict__ pt,
    const float* __restrict__ fc1w, const float* __restrict__ fc1b,
    const float* __restrict__ fc2w, const float* __restrict__ fc2b,
    const float* __restrict__ fc3w, const float* __restrict__ fc3b,
    float* __restrict__ out)
{
  __shared__ float L[4][257];
  __shared__ float T1[4][80];
  __shared__ float T2[4][80];
  __shared__ float fmx[4];
  int t = threadIdx.x;
  if (t < 256){
    for (int b=0;b<4;b++){
      float v = sbuf[b*DIM + t];
      float ll = logf(v);
      if (ll != ll) ll = 0.f;
      ll = fmaxf(ll, 0.f);
      L[b][t] = ll;
    }
  }
  __syncthreads();
  int w = t >> 6, lane = t & 63;
  if (w < 4){
    float m = -INFINITY;
    for (int i=lane;i<256;i+=64){ float v = L[w][i]; if (v != INFINITY) m = fmaxf(m, v); }
    #pragma unroll
    for (int o=32;o>=1;o>>=1) m = fmaxf(m, __shfl_xor(m, o, 64));
    if (lane==0) fmx[w] = m;
  }
  __syncthreads();
  if (t < 256){
    for (int b=0;b<4;b++) if (L[b][t] == INFINITY) L[b][t] = fmx[b];
  }
  if (t < 4) L[t][256] = pt[t];
  __syncthreads();
  if (t < 320){
    int b = t/80, i = t%80;
    float a = fc1b[i];
    for (int k=0;k<257;k++) a += L[b][k]*fc1w[i*257+k];
    T1[b][i] = leakyf(a);
  }
  __syncthreads();
  if (t < 320){
    int b = t/80, i = t%80;
    float a = fc2b[i];
    for (int k=0;k<80;k++) a += T1[b][k]*fc2w[i*80+k];
    T2[b][i] = leakyf(a);
  }
  __syncthreads();
  if (t < 40){
    int b = t/10, i = t%10;
    float a = fc3b[i];
    for (int k=0;k<80;k++) a += T2[b][k]*fc3w[i*80+k];
    out[b*10+i] = a;
  }
}

extern "C" void kernel_launch(void* const* d_in, const int* in_sizes, int n_in,
                              void* d_out, int out_size, void* d_ws, size_t ws_size,
                              hipStream_t stream) {
  const float* nodes = (const float*)d_in[0];
  const int*   edges = (const int*)d_in[1];
  const float* pt    = (const float*)d_in[2];
  const float* w_ih  = (const float*)d_in[3];
  const float* w_hh  = (const float*)d_in[4];
  const float* b_ih  = (const float*)d_in[5];
  const float* b_hh  = (const float*)d_in[6];
  const float* ew1   = (const float*)d_in[7];
  const float* eb1   = (const float*)d_in[8];
  const float* ew2   = (const float*)d_in[9];
  const float* eb2   = (const float*)d_in[10];
  const float* fc1w  = (const float*)d_in[11];
  const float* fc1b  = (const float*)d_in[12];
  const float* fc2w  = (const float*)d_in[13];
  const float* fc2b  = (const float*)d_in[14];
  const float* fc3w  = (const float*)d_in[15];
  const float* fc3b  = (const float*)d_in[16];

  const size_t HN  = (size_t)BATCH*NNODES*DIM;    // 10,240,000 (real rows)
  const size_t HNP = (size_t)MROWS*DIM;           // padded rows x 256
  char* p = (char*)d_ws;
  float* sbuf = (float*)p;                        p += BATCH*DIM*4;
  unsigned short* h_hi = (unsigned short*)p;      p += HNP*2;
  unsigned short* h_lo = (unsigned short*)p;      p += HNP*2;
  unsigned short* ib   = (unsigned short*)p;      p += HNP*2;
  unsigned short* Zb   = (unsigned short*)p;      p += 2*HNP*2;     // [si][MROWS][256]
  unsigned short* Sb   = (unsigned short*)p;      p += (size_t)MROWS*512*2;
  unsigned short* w1cat= (unsigned short*)p;      p += 512*256*2;
  unsigned short* w2k  = (unsigned short*)p;      p += 256*1024*2;
  unsigned short* wihk = (unsigned short*)p;      p += 768*512*2;
  unsigned short* whhk = (unsigned short*)p;      p += 768*512*2;
  int* off  = (int*)p;                            p += NG*(NNODES+1)*4;
  int* cur  = (int*)p;                            p += NG*NNODES*4;
  int* ssrc = (int*)p;                            p += (size_t)NG*NEDGES*4;
  unsigned short* gi_b = (unsigned short*)p;

  size_t usedB = (size_t)(p - (char*)d_ws);
  size_t freeB = (ws_size > usedB) ? ws_size - usedB : 0;
  int chunk_rows = 1280;                          // multiples of 128
  if (freeB >= (size_t)MROWS*768*2*2)      chunk_rows = MROWS;
  else if (freeB >= (size_t)5120*768*2*2)  chunk_rows = 5120;
  unsigned short* gh_b = gi_b + (size_t)chunk_rows*768;

  // weights
  w1cat_kernel<<<512,256,0,stream>>>(ew1, w1cat);
  w2k_kernel<<<1024,256,0,stream>>>(ew2, w2k);
  wk2_kernel<<<1536,256,0,stream>>>(w_ih, wihk);
  wk2_kernel<<<1536,256,0,stream>>>(w_hh, whhk);

  // h0 (real rows only; pad rows hold harmless garbage)
  f2bf_split_kernel<<<(int)(HN/4/256),256,0,stream>>>(nodes, h_hi, h_lo, (int)(HN/4));

  // counting sort (CSR) of edges by dst, per stream g
  hipMemsetAsync(cur, 0, NG*NNODES*sizeof(int), stream);
  hist_kernel<<<(NG*NEDGES)/256,256,0,stream>>>(edges, cur);
  scan_kernel<<<NG,256,0,stream>>>(cur, off);
  hipMemsetAsync(cur, 0, NG*NNODES*sizeof(int), stream);
  scatter_kernel<<<(NG*NEDGES)/256,256,0,stream>>>(edges, off, cur, ssrc);

  hipMemsetAsync(sbuf, 0, BATCH*DIM*sizeof(float), stream);

  for (int pass=0; pass<6; pass++){
    z128_kernel<<<dim3(MROWS/128,4),256,0,stream>>>(h_hi, w1cat, eb1, Zb);
    aggregate_kernel<<<dim3(2500,NG),256,0,stream>>>(Zb, ssrc, off, Sb);
    w2128_kernel<<<dim3(MROWS/128,2),256,0,stream>>>(Sb, w2k, eb2, off, ib);
    for (int r0=0; r0<MROWS; r0+=chunk_rows){
      int rows = (MROWS - r0 < chunk_rows) ? (MROWS - r0) : chunk_rows;
      gru128_kernel<<<dim3(rows/128,6,2),256,0,stream>>>(ib + (size_t)r0*256, h_hi + (size_t)r0*256,
                                                         wihk, whhk, b_ih, b_hh, gi_b, gh_b);
      gate_kernel<<<rows,256,0,stream>>>(gi_b, gh_b, h_hi + (size_t)r0*256, h_lo + (size_t)r0*256);
    }
  }
  reduce_kernel<<<200,256,0,stream>>>(h_hi, h_lo, sbuf);
  head_kernel<<<1,320,0,stream>>>(sbuf, pt, fc1w,fc1b,fc2w,fc2b,fc3w,fc3b,(float*)d_out);
}

// Round 8
// 2139.686 us; speedup vs baseline: 19.8289x; 1.0161x over previous
//
#include <hip/hip_runtime.h>
#include <math.h>

#define NNODES 10000
#define NEDGES 160000
#define DIM    256
#define BATCH  4
#define NG     8           // BATCH * S streams
#define MROWS  40064       // 40000 padded to 313*128

typedef __attribute__((ext_vector_type(8))) __bf16 bf16x8;
typedef __attribute__((ext_vector_type(4))) float  floatx4;

__device__ __forceinline__ float leakyf(float x){ return x > 0.f ? x : 0.01f*x; }
__device__ __forceinline__ float sigmoidf_(float x){ return 1.f/(1.f+expf(-x)); }
__device__ __forceinline__ unsigned short f2bf_u(float x){
  unsigned int u = __float_as_uint(x);
  u += 0x7fffu + ((u >> 16) & 1u);
  return (unsigned short)(u >> 16);
}
__device__ __forceinline__ float bfdec(unsigned short u){
  return __uint_as_float(((unsigned int)u) << 16);
}

__device__ __forceinline__ void glds16(unsigned short* lds, const unsigned short* g){
  __builtin_amdgcn_global_load_lds(
      (const __attribute__((address_space(1))) void*)g,
      (__attribute__((address_space(3))) void*)lds, 16, 0, 0);
}

// fp32 -> (hi, lo) bf16 pair
__global__ void f2bf_split_kernel(const float* __restrict__ in,
                                  unsigned short* __restrict__ hi,
                                  unsigned short* __restrict__ lo, int n4){
  int i = blockIdx.x*256 + threadIdx.x;
  if (i < n4){
    float4 v = ((const float4*)in)[i];
    ushort4 h, l;
    h.x = f2bf_u(v.x); l.x = f2bf_u(v.x - bfdec(h.x));
    h.y = f2bf_u(v.y); l.y = f2bf_u(v.y - bfdec(h.y));
    h.z = f2bf_u(v.z); l.z = f2bf_u(v.z - bfdec(h.z));
    h.w = f2bf_u(v.w); l.w = f2bf_u(v.w - bfdec(h.w));
    ((ushort4*)hi)[i] = h;
    ((ushort4*)lo)[i] = l;
  }
}

// ---- weight prep ----
__global__ void w1cat_kernel(const float* __restrict__ ew1, unsigned short* __restrict__ o){
  int idx = blockIdx.x*256 + threadIdx.x;      // 512*256
  int n = idx >> 8, k = idx & 255;
  o[idx] = f2bf_u(ew1[(n>>8)*65536 + (n&255)*256 + k]);
}
__global__ void w2k_kernel(const float* __restrict__ ew2, unsigned short* __restrict__ o){
  int idx = blockIdx.x*256 + threadIdx.x;      // 256*1024
  int n = idx >> 10, kp = idx & 1023;
  int j = kp & 511, term = kp >> 9;
  int si = j >> 8, k = j & 255;
  float v = ew2[si*65536 + n*256 + k];
  unsigned short h = f2bf_u(v);
  o[idx] = term ? f2bf_u(v - bfdec(h)) : h;
}
__global__ void wk2_kernel(const float* __restrict__ w, unsigned short* __restrict__ o){
  int idx = blockIdx.x*256 + threadIdx.x;      // 768*512
  int c = idx >> 9, kp = idx & 511;
  int k = kp & 255, term = kp >> 8;
  float v = w[c*256 + k];
  unsigned short h = f2bf_u(v);
  o[idx] = term ? f2bf_u(v - bfdec(h)) : h;
}

// ---------------- edge sort (counting sort by dst, per stream g) ----------------
__global__ void hist_kernel(const int* __restrict__ edges, int* __restrict__ cnt){
  int idx = blockIdx.x*256 + threadIdx.x;
  if (idx < NG*NEDGES){
    int g = idx / NEDGES, e = idx - g*NEDGES;
    int d = edges[((size_t)g*NEDGES + e)*2];
    atomicAdd(&cnt[g*NNODES + d], 1);
  }
}

__global__ __launch_bounds__(256) void scan_kernel(const int* __restrict__ cnt, int* __restrict__ off){
  __shared__ int sc[256];
  int g = blockIdx.x, t = threadIdx.x;
  int base = 0;
  for (int c=0;c<40;c++){
    int i = c*256 + t;
    int v = (i < NNODES) ? cnt[g*NNODES + i] : 0;
    __syncthreads();
    sc[t] = v;
    __syncthreads();
    for (int o=1;o<256;o<<=1){
      int u = (t>=o) ? sc[t-o] : 0;
      __syncthreads();
      sc[t] += u;
      __syncthreads();
    }
    if (i < NNODES) off[g*(NNODES+1) + i] = base + sc[t] - v;
    base += sc[255];
  }
  if (t == 0) off[g*(NNODES+1) + NNODES] = base;
}

__global__ void scatter_kernel(const int* __restrict__ edges, const int* __restrict__ off,
                               int* __restrict__ cur, int* __restrict__ ssrc){
  int idx = blockIdx.x*256 + threadIdx.x;
  if (idx < NG*NEDGES){
    int g = idx / NEDGES, e = idx - g*NEDGES;
    const int* ep = &edges[((size_t)g*NEDGES + e)*2];
    int d = ep[0], s = ep[1];
    int pos = off[g*(NNODES+1) + d] + atomicAdd(&cur[g*NNODES + d], 1);
    ssrc[g*NEDGES + pos] = s;
  }
}

// ================= 128x128 LDS-staged MFMA core =================
template<int KP, int KA>
__device__ __forceinline__ void mm128_core(
    const unsigned short* __restrict__ Ab, const unsigned short* __restrict__ Wb,
    unsigned short* lds, floatx4 (&acc)[4][4])
{
  const int t = threadIdx.x;
  const int w = t >> 6, lane = t & 63;
  const int q = lane >> 4, col = lane & 15;
  const int wr = (w & 1)*64, wc = (w >> 1)*64;
  unsigned short* Al = lds;
  unsigned short* Bl = lds + 128*64;

  const int sr = t >> 3;
  const int sj = t & 7;
  const int sk = ((sj ^ (sr & 7)) * 8);

  for (int kb = 0; kb < KP; kb += 64){
    #pragma unroll
    for (int i=0;i<4;i++){
      int r = i*32 + sr;
      glds16(&Al[i*2048 + w*512], &Ab[(size_t)r*KA + ((kb + sk) & (KA-1))]);
    }
    #pragma unroll
    for (int i=0;i<4;i++){
      int r = i*32 + sr;
      glds16(&Bl[i*2048 + w*512], &Wb[(size_t)r*KP + kb + sk]);
    }
    __syncthreads();
    #pragma unroll
    for (int ks2=0; ks2<2; ks2++){
      bf16x8 a[4], bf[4];
      #pragma unroll
      for (int mi=0;mi<4;mi++){
        int r = wr + mi*16 + col;
        int j = (ks2*4 + q) ^ (r & 7);
        a[mi] = *(const bf16x8*)&Al[r*64 + j*8];
      }
      #pragma unroll
      for (int ni=0;ni<4;ni++){
        int r = wc + ni*16 + col;
        int j = (ks2*4 + q) ^ (r & 7);
        bf[ni] = *(const bf16x8*)&Bl[r*64 + j*8];
      }
      #pragma unroll
      for (int mi=0;mi<4;mi++)
        #pragma unroll
        for (int ni=0;ni<4;ni++)
          acc[mi][ni] = __builtin_amdgcn_mfma_f32_16x16x32_bf16(a[mi], bf[ni], acc[mi][ni], 0,0,0);
    }
    __syncthreads();
  }
}

// ---- Z = leaky(h @ W1cat^T + b1): grid (313, 4) ----
__global__ __launch_bounds__(256) void z128_kernel(
    const unsigned short* __restrict__ h_hi, const unsigned short* __restrict__ w1cat,
    const float* __restrict__ eb1, unsigned short* __restrict__ Z)
{
  __shared__ unsigned short lds[16384];
  const int row0 = blockIdx.x*128, col0 = blockIdx.y*128;
  const int t = threadIdx.x, w = t >> 6, lane = t & 63;
  const int q = lane >> 4, col = lane & 15;
  const int wr = (w & 1)*64, wc = (w >> 1)*64;

  floatx4 acc[4][4];
  #pragma unroll
  for (int mi=0;mi<4;mi++)
    #pragma unroll
    for (int ni=0;ni<4;ni++) acc[mi][ni] = (floatx4){0.f,0.f,0.f,0.f};

  mm128_core<256,256>(h_hi + (size_t)row0*256, w1cat + (size_t)col0*256, lds, acc);

  #pragma unroll
  for (int ni=0;ni<4;ni++){
    int n = col0 + wc + ni*16 + col;
    int si = n >> 8, cz = n & 255;
    float bb = eb1[si*256 + cz];
    unsigned short* zp = Z + (size_t)si*MROWS*256 + cz;
    #pragma unroll
    for (int mi=0;mi<4;mi++)
      #pragma unroll
      for (int rr=0;rr<4;rr++){
        int row = row0 + wr + mi*16 + q*4 + rr;
        zp[(size_t)row*256] = f2bf_u(leakyf(acc[mi][ni][rr] + bb));
      }
  }
}

// ---- CSR aggregate, XCD-pinned: g = bid & 7; 4 nodes per wave ----
__global__ __launch_bounds__(256) void aggregate_kernel(
    const unsigned short* __restrict__ Z, const int* __restrict__ ssrc,
    const int* __restrict__ off, unsigned short* __restrict__ Sb)
{
  const int bid = blockIdx.x;          // 5000
  const int g = bid & 7;
  const int dgrp = bid >> 3;           // 0..624
  const int b = g >> 1, si = g & 1;
  const int w = threadIdx.x >> 6, lane = threadIdx.x & 63;
  const unsigned short* zb = Z + ((size_t)si*MROWS + b*10000)*256 + lane*4;
  const int* sp = ssrc + (size_t)g*NEDGES;
  const int* offg = off + g*(NNODES+1);

  #pragma unroll
  for (int i=0;i<4;i++){
    const int d = dgrp*16 + w*4 + i;
    const int j0 = offg[d], j1 = offg[d+1];
    float a0=0.f, a1=0.f, a2=0.f, a3=0.f;
    int j = j0;
    for (; j+4 <= j1; j+=4){
      int s0=sp[j], s1=sp[j+1], s2=sp[j+2], s3=sp[j+3];
      ushort4 u0 = *(const ushort4*)&zb[(size_t)s0*256];
      ushort4 u1 = *(const ushort4*)&zb[(size_t)s1*256];
      ushort4 u2 = *(const ushort4*)&zb[(size_t)s2*256];
      ushort4 u3 = *(const ushort4*)&zb[(size_t)s3*256];
      a0 += bfdec(u0.x)+bfdec(u1.x)+bfdec(u2.x)+bfdec(u3.x);
      a1 += bfdec(u0.y)+bfdec(u1.y)+bfdec(u2.y)+bfdec(u3.y);
      a2 += bfdec(u0.z)+bfdec(u1.z)+bfdec(u2.z)+bfdec(u3.z);
      a3 += bfdec(u0.w)+bfdec(u1.w)+bfdec(u2.w)+bfdec(u3.w);
    }
    for (; j < j1; j++){
      ushort4 u = *(const ushort4*)&zb[(size_t)sp[j]*256];
      a0 += bfdec(u.x); a1 += bfdec(u.y); a2 += bfdec(u.z); a3 += bfdec(u.w);
    }
    size_t so = (size_t)(b*10000 + d)*512 + si*256 + lane*4;
    ushort4 h;
    h.x = f2bf_u(a0); h.y = f2bf_u(a1); h.z = f2bf_u(a2); h.w = f2bf_u(a3);
    *(ushort4*)&Sb[so] = h;
  }
}

// ---- ib = S @ W2k^T (2-term via K'=1024) + deg.b2: grid (313, 2) ----
__global__ __launch_bounds__(256) void w2128_kernel(
    const unsigned short* __restrict__ Sb, const unsigned short* __restrict__ w2k,
    const float* __restrict__ eb2, const int* __restrict__ off,
    unsigned short* __restrict__ ib)
{
  __shared__ unsigned short lds[16384];
  const int row0 = blockIdx.x*128, col0 = blockIdx.y*128;
  const int t = threadIdx.x, w = t >> 6, lane = t & 63;
  const int q = lane >> 4, col = lane & 15;
  const int wr = (w & 1)*64, wc = (w >> 1)*64;

  floatx4 acc[4][4];
  #pragma unroll
  for (int mi=0;mi<4;mi++)
    #pragma unroll
    for (int ni=0;ni<4;ni++) acc[mi][ni] = (floatx4){0.f,0.f,0.f,0.f};

  mm128_core<1024,512>(Sb + (size_t)row0*512, w2k + (size_t)col0*1024, lds, acc);

  float b20[4], b21[4];
  #pragma unroll
  for (int ni=0;ni<4;ni++){
    int n = col0 + wc + ni*16 + col;
    b20[ni] = eb2[n];
    b21[ni] = eb2[256 + n];
  }
  #pragma unroll
  for (int mi=0;mi<4;mi++)
    #pragma unroll
    for (int rr=0;rr<4;rr++){
      int row = row0 + wr + mi*16 + q*4 + rr;
      int b = row / 10000, d = row - b*10000;
      float dg0 = 0.f, dg1 = 0.f;
      if (row < 40000){
        int o0 = (b*2)*(NNODES+1) + d;
        int o1 = (b*2+1)*(NNODES+1) + d;
        dg0 = (float)(off[o0+1] - off[o0]);
        dg1 = (float)(off[o1+1] - off[o1]);
      }
      #pragma unroll
      for (int ni=0;ni<4;ni++){
        int n = col0 + wc + ni*16 + col;
        ib[(size_t)row*256 + n] = f2bf_u(acc[mi][ni][rr] + dg0*b20[ni] + dg1*b21[ni]);
      }
    }
}

// ---- gruA: r,z gates -> fp32 rz_r / rz_z. grid (313,4): col0 in [0,512) ----
__global__ __launch_bounds__(256) void gruA_kernel(
    const unsigned short* __restrict__ ib, const unsigned short* __restrict__ h_hi,
    const unsigned short* __restrict__ wihk, const unsigned short* __restrict__ whhk,
    const float* __restrict__ b_ih, const float* __restrict__ b_hh,
    float* __restrict__ rz_r, float* __restrict__ rz_z)
{
  __shared__ unsigned short lds[16384];
  const int row0 = blockIdx.x*128, col0 = blockIdx.y*128;
  const int t = threadIdx.x, w = t >> 6, lane = t & 63;
  const int q = lane >> 4, col = lane & 15;
  const int wr = (w & 1)*64, wc = (w >> 1)*64;

  floatx4 ai[4][4], ah[4][4];
  #pragma unroll
  for (int mi=0;mi<4;mi++)
    #pragma unroll
    for (int ni=0;ni<4;ni++){ ai[mi][ni] = (floatx4){0.f,0.f,0.f,0.f}; ah[mi][ni] = (floatx4){0.f,0.f,0.f,0.f}; }

  mm128_core<512,256>(ib   + (size_t)row0*256, wihk + (size_t)col0*512, lds, ai);
  mm128_core<512,256>(h_hi + (size_t)row0*256, whhk + (size_t)col0*512, lds, ah);

  float bi[4], bh[4];
  #pragma unroll
  for (int ni=0;ni<4;ni++){
    int n = col0 + wc + ni*16 + col;
    bi[ni] = b_ih[n]; bh[ni] = b_hh[n];
  }
  // cols 0..255 -> r gate, 256..511 -> z gate (block-uniform split)
  float* dst = (col0 < 256) ? rz_r : rz_z;
  const int cbase = (col0 & 255) + wc;
  #pragma unroll
  for (int mi=0;mi<4;mi++)
    #pragma unroll
    for (int rr=0;rr<4;rr++){
      size_t row = (size_t)(row0 + wr + mi*16 + q*4 + rr);
      #pragma unroll
      for (int ni=0;ni<4;ni++){
        float v = sigmoidf_(ai[mi][ni][rr] + bi[ni] + ah[mi][ni][rr] + bh[ni]);
        dst[row*256 + cbase + ni*16 + col] = v;
      }
    }
}

// ---- gruB: n gate + full GRU update (fp32 gates). grid (313,2). Writes h_nxt ----
__global__ __launch_bounds__(256) void gruB_kernel(
    const unsigned short* __restrict__ ib, const unsigned short* __restrict__ h_hi,
    const unsigned short* __restrict__ h_lo,
    const unsigned short* __restrict__ wihk, const unsigned short* __restrict__ whhk,
    const float* __restrict__ b_ih, const float* __restrict__ b_hh,
    const float* __restrict__ rz_r, const float* __restrict__ rz_z,
    unsigned short* __restrict__ nh_hi, unsigned short* __restrict__ nh_lo)
{
  __shared__ unsigned short lds[16384];
  const int row0 = blockIdx.x*128, dcol0 = blockIdx.y*128;   // n-gate W cols = 512 + dcol0
  const int t = threadIdx.x, w = t >> 6, lane = t & 63;
  const int q = lane >> 4, col = lane & 15;
  const int wr = (w & 1)*64, wc = (w >> 1)*64;

  floatx4 ai[4][4], ah[4][4];
  #pragma unroll
  for (int mi=0;mi<4;mi++)
    #pragma unroll
    for (int ni=0;ni<4;ni++){ ai[mi][ni] = (floatx4){0.f,0.f,0.f,0.f}; ah[mi][ni] = (floatx4){0.f,0.f,0.f,0.f}; }

  mm128_core<512,256>(ib   + (size_t)row0*256, wihk + (size_t)(512 + dcol0)*512, lds, ai);
  mm128_core<512,256>(h_hi + (size_t)row0*256, whhk + (size_t)(512 + dcol0)*512, lds, ah);

  float bi[4], bh[4];
  #pragma unroll
  for (int ni=0;ni<4;ni++){
    int n = 512 + dcol0 + wc + ni*16 + col;
    bi[ni] = b_ih[n]; bh[ni] = b_hh[n];
  }
  #pragma unroll
  for (int mi=0;mi<4;mi++)
    #pragma unroll
    for (int rr=0;rr<4;rr++){
      size_t row = (size_t)(row0 + wr + mi*16 + q*4 + rr);
      #pragma unroll
      for (int ni=0;ni<4;ni++){
        int dn = dcol0 + wc + ni*16 + col;
        float rg = rz_r[row*256 + dn];
        float zg = rz_z[row*256 + dn];
        float ng = tanhf(ai[mi][ni][rr] + bi[ni] + rg*(ah[mi][ni][rr] + bh[ni]));
        size_t hidx = row*256 + dn;
        float hv = bfdec(h_hi[hidx]) + bfdec(h_lo[hidx]);
        float hnew = (1.f - zg)*ng + zg*hv;
        unsigned short hh = f2bf_u(hnew);
        nh_hi[hidx] = hh;
        nh_lo[hidx] = f2bf_u(hnew - bfdec(hh));
      }
    }
}

__global__ void reduce_kernel(const unsigned short* __restrict__ hhi,
                              const unsigned short* __restrict__ hlo,
                              float* __restrict__ sbuf){
  int b  = blockIdx.x / 50;
  int s0 = (blockIdx.x % 50) * 200;
  int d  = threadIdx.x;
  size_t off = ((size_t)b*NNODES + s0)*DIM + d;
  float acc = 0.f;
  for (int i=0;i<200;i++){
    acc += bfdec(hhi[off]) + bfdec(hlo[off]);
    off += DIM;
  }
  atomicAdd(&sbuf[b*DIM + d], acc);
}

__global__ __launch_bounds__(320) void head_kernel(
    const float* __restrict__ sbuf, const float* __restrict__ pt,
    const float* __restrict__ fc1w, const float* __restrict__ fc1b,
    const float* __restrict__ fc2w, const float* __restrict__ fc2b,
    const float* __restrict__ fc3w, const float* __restrict__ fc3b,
    float* __restrict__ out)
{
  __shared__ float L[4][257];
  __shared__ float T1[4][80];
  __shared__ float T2[4][80];
  __shared__ float fmx[4];
  int t = threadIdx.x;
  if (t < 256){
    for (int b=0;b<4;b++){
      float v = sbuf[b*DIM + t];
      float ll = logf(v);
      if (ll != ll) ll = 0.f;
      ll = fmaxf(ll, 0.f);
      L[b][t] = ll;
    }
  }
  __syncthreads();
  int w = t >> 6, lane = t & 63;
  if (w < 4){
    float m = -INFINITY;
    for (int i=lane;i<256;i+=64){ float v = L[w][i]; if (v != INFINITY) m = fmaxf(m, v); }
    #pragma unroll
    for (int o=32;o>=1;o>>=1) m = fmaxf(m, __shfl_xor(m, o, 64));
    if (lane==0) fmx[w] = m;
  }
  __syncthreads();
  if (t < 256){
    for (int b=0;b<4;b++) if (L[b][t] == INFINITY) L[b][t] = fmx[b];
  }
  if (t < 4) L[t][256] = pt[t];
  __syncthreads();
  if (t < 320){
    int b = t/80, i = t%80;
    float a = fc1b[i];
    for (int k=0;k<257;k++) a += L[b][k]*fc1w[i*257+k];
    T1[b][i] = leakyf(a);
  }
  __syncthreads();
  if (t < 320){
    int b = t/80, i = t%80;
    float a = fc2b[i];
    for (int k=0;k<80;k++) a += T1[b][k]*fc2w[i*80+k];
    T2[b][i] = leakyf(a);
  }
  __syncthreads();
  if (t < 40){
    int b = t/10, i = t%10;
    float a = fc3b[i];
    for (int k=0;k<80;k++) a += T2[b][k]*fc3w[i*80+k];
    out[b*10+i] = a;
  }
}

extern "C" void kernel_launch(void* const* d_in, const int* in_sizes, int n_in,
                              void* d_out, int out_size, void* d_ws, size_t ws_size,
                              hipStream_t stream) {
  const float* nodes = (const float*)d_in[0];
  const int*   edges = (const int*)d_in[1];
  const float* pt    = (const float*)d_in[2];
  const float* w_ih  = (const float*)d_in[3];
  const float* w_hh  = (const float*)d_in[4];
  const float* b_ih  = (const float*)d_in[5];
  const float* b_hh  = (const float*)d_in[6];
  const float* ew1   = (const float*)d_in[7];
  const float* eb1   = (const float*)d_in[8];
  const float* ew2   = (const float*)d_in[9];
  const float* eb2   = (const float*)d_in[10];
  const float* fc1w  = (const float*)d_in[11];
  const float* fc1b  = (const float*)d_in[12];
  const float* fc2w  = (const float*)d_in[13];
  const float* fc2b  = (const float*)d_in[14];
  const float* fc3w  = (const float*)d_in[15];
  const float* fc3b  = (const float*)d_in[16];

  const size_t HN  = (size_t)BATCH*NNODES*DIM;    // 10,240,000 (real rows)
  const size_t HNP = (size_t)MROWS*DIM;
  char* p = (char*)d_ws;
  float* sbuf = (float*)p;                        p += BATCH*DIM*4;
  unsigned short* h_hi0 = (unsigned short*)p;     p += HNP*2;
  unsigned short* h_lo0 = (unsigned short*)p;     p += HNP*2;
  unsigned short* h_hi1 = (unsigned short*)p;     p += HNP*2;
  unsigned short* h_lo1 = (unsigned short*)p;     p += HNP*2;
  unsigned short* ib   = (unsigned short*)p;      p += HNP*2;
  unsigned short* Zb   = (unsigned short*)p;      p += 2*HNP*2;     // dead after aggregate -> rz_r
  unsigned short* Sb   = (unsigned short*)p;      p += (size_t)MROWS*512*2;  // dead after w2128 -> rz_z
  unsigned short* w1cat= (unsigned short*)p;      p += 512*256*2;
  unsigned short* w2k  = (unsigned short*)p;      p += 256*1024*2;
  unsigned short* wihk = (unsigned short*)p;      p += 768*512*2;
  unsigned short* whhk = (unsigned short*)p;      p += 768*512*2;
  int* off  = (int*)p;                            p += NG*(NNODES+1)*4;
  int* cur  = (int*)p;                            p += NG*NNODES*4;
  int* ssrc = (int*)p;                            p += (size_t)NG*NEDGES*4;

  float* rz_r = (float*)Zb;   // MROWS*256 fp32 == 2*HNP*2 bytes exactly
  float* rz_z = (float*)Sb;   // MROWS*256 fp32 == MROWS*512*2 bytes exactly

  // weights
  w1cat_kernel<<<512,256,0,stream>>>(ew1, w1cat);
  w2k_kernel<<<1024,256,0,stream>>>(ew2, w2k);
  wk2_kernel<<<1536,256,0,stream>>>(w_ih, wihk);
  wk2_kernel<<<1536,256,0,stream>>>(w_hh, whhk);

  // h0
  f2bf_split_kernel<<<(int)(HN/4/256),256,0,stream>>>(nodes, h_hi0, h_lo0, (int)(HN/4));

  // counting sort (CSR) of edges by dst, per stream g
  hipMemsetAsync(cur, 0, NG*NNODES*sizeof(int), stream);
  hist_kernel<<<(NG*NEDGES)/256,256,0,stream>>>(edges, cur);
  scan_kernel<<<NG,256,0,stream>>>(cur, off);
  hipMemsetAsync(cur, 0, NG*NNODES*sizeof(int), stream);
  scatter_kernel<<<(NG*NEDGES)/256,256,0,stream>>>(edges, off, cur, ssrc);

  hipMemsetAsync(sbuf, 0, BATCH*DIM*sizeof(float), stream);

  unsigned short* hhi[2] = {h_hi0, h_hi1};
  unsigned short* hlo[2] = {h_lo0, h_lo1};

  for (int pass=0; pass<6; pass++){
    unsigned short* hc_hi = hhi[pass & 1];
    unsigned short* hc_lo = hlo[pass & 1];
    unsigned short* hn_hi = hhi[(pass+1) & 1];
    unsigned short* hn_lo = hlo[(pass+1) & 1];
    z128_kernel<<<dim3(MROWS/128,4),256,0,stream>>>(hc_hi, w1cat, eb1, Zb);
    aggregate_kernel<<<5000,256,0,stream>>>(Zb, ssrc, off, Sb);
    w2128_kernel<<<dim3(MROWS/128,2),256,0,stream>>>(Sb, w2k, eb2, off, ib);
    gruA_kernel<<<dim3(MROWS/128,4),256,0,stream>>>(ib, hc_hi, wihk, whhk, b_ih, b_hh, rz_r, rz_z);
    gruB_kernel<<<dim3(MROWS/128,2),256,0,stream>>>(ib, hc_hi, hc_lo, wihk, whhk, b_ih, b_hh,
                                                    rz_r, rz_z, hn_hi, hn_lo);
  }
  reduce_kernel<<<200,256,0,stream>>>(hhi[0], hlo[0], sbuf);
  head_kernel<<<1,320,0,stream>>>(sbuf, pt, fc1w,fc1b,fc2w,fc2b,fc3w,fc3b,(float*)d_out);
}

// Round 9
// 2058.379 us; speedup vs baseline: 20.6122x; 1.0395x over previous
//
#include <hip/hip_runtime.h>
#include <math.h>

#define NNODES 10000
#define NEDGES 160000
#define DIM    256
#define BATCH  4
#define NG     8           // BATCH * S streams
#define MROWS  40064       // 40000 padded to 313*128

typedef __attribute__((ext_vector_type(8))) __bf16 bf16x8;
typedef __attribute__((ext_vector_type(4))) float  floatx4;

__device__ __forceinline__ float leakyf(float x){ return x > 0.f ? x : 0.01f*x; }
__device__ __forceinline__ float sigmoidf_(float x){ return 1.f/(1.f+expf(-x)); }
__device__ __forceinline__ unsigned short f2bf_u(float x){
  unsigned int u = __float_as_uint(x);
  u += 0x7fffu + ((u >> 16) & 1u);
  return (unsigned short)(u >> 16);
}
__device__ __forceinline__ float bfdec(unsigned short u){
  return __uint_as_float(((unsigned int)u) << 16);
}
#define GATE_SCL 65535.f
#define GATE_INV 1.5259021896696422e-5f

__device__ __forceinline__ void glds16(unsigned short* lds, const unsigned short* g){
  __builtin_amdgcn_global_load_lds(
      (const __attribute__((address_space(1))) void*)g,
      (__attribute__((address_space(3))) void*)lds, 16, 0, 0);
}

// fp32 -> (hi, lo) bf16 pair
__global__ void f2bf_split_kernel(const float* __restrict__ in,
                                  unsigned short* __restrict__ hi,
                                  unsigned short* __restrict__ lo, int n4){
  int i = blockIdx.x*256 + threadIdx.x;
  if (i < n4){
    float4 v = ((const float4*)in)[i];
    ushort4 h, l;
    h.x = f2bf_u(v.x); l.x = f2bf_u(v.x - bfdec(h.x));
    h.y = f2bf_u(v.y); l.y = f2bf_u(v.y - bfdec(h.y));
    h.z = f2bf_u(v.z); l.z = f2bf_u(v.z - bfdec(h.z));
    h.w = f2bf_u(v.w); l.w = f2bf_u(v.w - bfdec(h.w));
    ((ushort4*)hi)[i] = h;
    ((ushort4*)lo)[i] = l;
  }
}

// copy h_hi into ihcat h-half (init for pass 0)
__global__ void ihinit_kernel(const unsigned short* __restrict__ h_hi,
                              unsigned short* __restrict__ ihcat){
  int idx = blockIdx.x*256 + threadIdx.x;   // 40000*256
  int row = idx >> 8, d = idx & 255;
  ihcat[(size_t)row*512 + 256 + d] = h_hi[idx];
}

// ---- weight prep ----
__global__ void w1cat_kernel(const float* __restrict__ ew1, unsigned short* __restrict__ o){
  int idx = blockIdx.x*256 + threadIdx.x;      // 512*256
  int n = idx >> 8, k = idx & 255;
  o[idx] = f2bf_u(ew1[(n>>8)*65536 + (n&255)*256 + k]);
}
__global__ void w2k_kernel(const float* __restrict__ ew2, unsigned short* __restrict__ o){
  int idx = blockIdx.x*256 + threadIdx.x;      // 256*1024
  int n = idx >> 10, kp = idx & 1023;
  int j = kp & 511, term = kp >> 9;
  int si = j >> 8, k = j & 255;
  float v = ew2[si*65536 + n*256 + k];
  unsigned short h = f2bf_u(v);
  o[idx] = term ? f2bf_u(v - bfdec(h)) : h;
}
// wk2[c][kp], kp in [0,512): K' = [hi | lo]
__global__ void wk2_kernel(const float* __restrict__ w, unsigned short* __restrict__ o){
  int idx = blockIdx.x*256 + threadIdx.x;      // 768*512
  int c = idx >> 9, kp = idx & 511;
  int k = kp & 255, term = kp >> 8;
  float v = w[c*256 + k];
  unsigned short h = f2bf_u(v);
  o[idx] = term ? f2bf_u(v - bfdec(h)) : h;
}
// wcomb[c][kp], c in [0,512) (r,z rows), kp in [0,1024):
// segments [Wih_hi | Whh_hi | Wih_lo | Whh_lo]
__global__ void wcomb_kernel(const float* __restrict__ wih, const float* __restrict__ whh,
                             unsigned short* __restrict__ o){
  int idx = blockIdx.x*256 + threadIdx.x;      // 512*1024
  int c = idx >> 10, kp = idx & 1023;
  int seg = kp >> 8, k = kp & 255;
  const float* w = (seg & 1) ? whh : wih;
  float v = w[c*256 + k];
  unsigned short h = f2bf_u(v);
  o[idx] = (seg >> 1) ? f2bf_u(v - bfdec(h)) : h;
}

// ---------------- edge sort (counting sort by dst, per stream g) ----------------
__global__ void hist_kernel(const int* __restrict__ edges, int* __restrict__ cnt){
  int idx = blockIdx.x*256 + threadIdx.x;
  if (idx < NG*NEDGES){
    int g = idx / NEDGES, e = idx - g*NEDGES;
    int d = edges[((size_t)g*NEDGES + e)*2];
    atomicAdd(&cnt[g*NNODES + d], 1);
  }
}

__global__ __launch_bounds__(256) void scan_kernel(const int* __restrict__ cnt, int* __restrict__ off){
  __shared__ int sc[256];
  int g = blockIdx.x, t = threadIdx.x;
  int base = 0;
  for (int c=0;c<40;c++){
    int i = c*256 + t;
    int v = (i < NNODES) ? cnt[g*NNODES + i] : 0;
    __syncthreads();
    sc[t] = v;
    __syncthreads();
    for (int o=1;o<256;o<<=1){
      int u = (t>=o) ? sc[t-o] : 0;
      __syncthreads();
      sc[t] += u;
      __syncthreads();
    }
    if (i < NNODES) off[g*(NNODES+1) + i] = base + sc[t] - v;
    base += sc[255];
  }
  if (t == 0) off[g*(NNODES+1) + NNODES] = base;
}

__global__ void scatter_kernel(const int* __restrict__ edges, const int* __restrict__ off,
                               int* __restrict__ cur, int* __restrict__ ssrc){
  int idx = blockIdx.x*256 + threadIdx.x;
  if (idx < NG*NEDGES){
    int g = idx / NEDGES, e = idx - g*NEDGES;
    const int* ep = &edges[((size_t)g*NEDGES + e)*2];
    int d = ep[0], s = ep[1];
    int pos = off[g*(NNODES+1) + d] + atomicAdd(&cur[g*NNODES + d], 1);
    ssrc[g*NEDGES + pos] = s;
  }
}

// ================= 128x128 LDS-staged MFMA core =================
// A row r, element kp -> Ab[r*RS + (kp & KM)]  (RS = row stride, KM = wrap mask)
template<int KP, int RS, int KM>
__device__ __forceinline__ void mm128_core(
    const unsigned short* __restrict__ Ab, const unsigned short* __restrict__ Wb,
    unsigned short* lds, floatx4 (&acc)[4][4])
{
  const int t = threadIdx.x;
  const int w = t >> 6, lane = t & 63;
  const int q = lane >> 4, col = lane & 15;
  const int wr = (w & 1)*64, wc = (w >> 1)*64;
  unsigned short* Al = lds;
  unsigned short* Bl = lds + 128*64;

  const int sr = t >> 3;
  const int sj = t & 7;
  const int sk = ((sj ^ (sr & 7)) * 8);

  for (int kb = 0; kb < KP; kb += 64){
    #pragma unroll
    for (int i=0;i<4;i++){
      int r = i*32 + sr;
      glds16(&Al[i*2048 + w*512], &Ab[(size_t)r*RS + ((kb + sk) & KM)]);
    }
    #pragma unroll
    for (int i=0;i<4;i++){
      int r = i*32 + sr;
      glds16(&Bl[i*2048 + w*512], &Wb[(size_t)r*KP + kb + sk]);
    }
    __syncthreads();
    #pragma unroll
    for (int ks2=0; ks2<2; ks2++){
      bf16x8 a[4], bf[4];
      #pragma unroll
      for (int mi=0;mi<4;mi++){
        int r = wr + mi*16 + col;
        int j = (ks2*4 + q) ^ (r & 7);
        a[mi] = *(const bf16x8*)&Al[r*64 + j*8];
      }
      #pragma unroll
      for (int ni=0;ni<4;ni++){
        int r = wc + ni*16 + col;
        int j = (ks2*4 + q) ^ (r & 7);
        bf[ni] = *(const bf16x8*)&Bl[r*64 + j*8];
      }
      #pragma unroll
      for (int mi=0;mi<4;mi++)
        #pragma unroll
        for (int ni=0;ni<4;ni++)
          acc[mi][ni] = __builtin_amdgcn_mfma_f32_16x16x32_bf16(a[mi], bf[ni], acc[mi][ni], 0,0,0);
    }
    __syncthreads();
  }
}

// ---- Z = leaky(h @ W1cat^T + b1): grid (313, 4) ----
__global__ __launch_bounds__(256) void z128_kernel(
    const unsigned short* __restrict__ h_hi, const unsigned short* __restrict__ w1cat,
    const float* __restrict__ eb1, unsigned short* __restrict__ Z)
{
  __shared__ unsigned short lds[16384];
  const int row0 = blockIdx.x*128, col0 = blockIdx.y*128;
  const int t = threadIdx.x, w = t >> 6, lane = t & 63;
  const int q = lane >> 4, col = lane & 15;
  const int wr = (w & 1)*64, wc = (w >> 1)*64;

  floatx4 acc[4][4];
  #pragma unroll
  for (int mi=0;mi<4;mi++)
    #pragma unroll
    for (int ni=0;ni<4;ni++) acc[mi][ni] = (floatx4){0.f,0.f,0.f,0.f};

  mm128_core<256,256,255>(h_hi + (size_t)row0*256, w1cat + (size_t)col0*256, lds, acc);

  #pragma unroll
  for (int ni=0;ni<4;ni++){
    int n = col0 + wc + ni*16 + col;
    int si = n >> 8, cz = n & 255;
    float bb = eb1[si*256 + cz];
    unsigned short* zp = Z + (size_t)si*MROWS*256 + cz;
    #pragma unroll
    for (int mi=0;mi<4;mi++)
      #pragma unroll
      for (int rr=0;rr<4;rr++){
        int row = row0 + wr + mi*16 + q*4 + rr;
        zp[(size_t)row*256] = f2bf_u(leakyf(acc[mi][ni][rr] + bb));
      }
  }
}

// ---- CSR aggregate, XCD-pinned: g = bid & 7; 4 nodes per wave ----
__global__ __launch_bounds__(256) void aggregate_kernel(
    const unsigned short* __restrict__ Z, const int* __restrict__ ssrc,
    const int* __restrict__ off, unsigned short* __restrict__ Sb)
{
  const int bid = blockIdx.x;          // 5000
  const int g = bid & 7;
  const int dgrp = bid >> 3;           // 0..624
  const int b = g >> 1, si = g & 1;
  const int w = threadIdx.x >> 6, lane = threadIdx.x & 63;
  const unsigned short* zb = Z + ((size_t)si*MROWS + b*10000)*256 + lane*4;
  const int* sp = ssrc + (size_t)g*NEDGES;
  const int* offg = off + g*(NNODES+1);

  #pragma unroll
  for (int i=0;i<4;i++){
    const int d = dgrp*16 + w*4 + i;
    const int j0 = offg[d], j1 = offg[d+1];
    float a0=0.f, a1=0.f, a2=0.f, a3=0.f;
    int j = j0;
    for (; j+4 <= j1; j+=4){
      int s0=sp[j], s1=sp[j+1], s2=sp[j+2], s3=sp[j+3];
      ushort4 u0 = *(const ushort4*)&zb[(size_t)s0*256];
      ushort4 u1 = *(const ushort4*)&zb[(size_t)s1*256];
      ushort4 u2 = *(const ushort4*)&zb[(size_t)s2*256];
      ushort4 u3 = *(const ushort4*)&zb[(size_t)s3*256];
      a0 += bfdec(u0.x)+bfdec(u1.x)+bfdec(u2.x)+bfdec(u3.x);
      a1 += bfdec(u0.y)+bfdec(u1.y)+bfdec(u2.y)+bfdec(u3.y);
      a2 += bfdec(u0.z)+bfdec(u1.z)+bfdec(u2.z)+bfdec(u3.z);
      a3 += bfdec(u0.w)+bfdec(u1.w)+bfdec(u2.w)+bfdec(u3.w);
    }
    for (; j < j1; j++){
      ushort4 u = *(const ushort4*)&zb[(size_t)sp[j]*256];
      a0 += bfdec(u.x); a1 += bfdec(u.y); a2 += bfdec(u.z); a3 += bfdec(u.w);
    }
    size_t so = (size_t)(b*10000 + d)*512 + si*256 + lane*4;
    ushort4 h;
    h.x = f2bf_u(a0); h.y = f2bf_u(a1); h.z = f2bf_u(a2); h.w = f2bf_u(a3);
    *(ushort4*)&Sb[so] = h;
  }
}

// ---- ihcat.ib = S @ W2k^T (2-term K'=1024) + deg.b2: grid (313, 2) ----
__global__ __launch_bounds__(256) void w2128_kernel(
    const unsigned short* __restrict__ Sb, const unsigned short* __restrict__ w2k,
    const float* __restrict__ eb2, const int* __restrict__ off,
    unsigned short* __restrict__ ihcat)
{
  __shared__ unsigned short lds[16384];
  const int row0 = blockIdx.x*128, col0 = blockIdx.y*128;
  const int t = threadIdx.x, w = t >> 6, lane = t & 63;
  const int q = lane >> 4, col = lane & 15;
  const int wr = (w & 1)*64, wc = (w >> 1)*64;

  floatx4 acc[4][4];
  #pragma unroll
  for (int mi=0;mi<4;mi++)
    #pragma unroll
    for (int ni=0;ni<4;ni++) acc[mi][ni] = (floatx4){0.f,0.f,0.f,0.f};

  mm128_core<1024,512,511>(Sb + (size_t)row0*512, w2k + (size_t)col0*1024, lds, acc);

  float b20[4], b21[4];
  #pragma unroll
  for (int ni=0;ni<4;ni++){
    int n = col0 + wc + ni*16 + col;
    b20[ni] = eb2[n];
    b21[ni] = eb2[256 + n];
  }
  #pragma unroll
  for (int mi=0;mi<4;mi++)
    #pragma unroll
    for (int rr=0;rr<4;rr++){
      int row = row0 + wr + mi*16 + q*4 + rr;
      int b = row / 10000, d = row - b*10000;
      float dg0 = 0.f, dg1 = 0.f;
      if (row < 40000){
        int o0 = (b*2)*(NNODES+1) + d;
        int o1 = (b*2+1)*(NNODES+1) + d;
        dg0 = (float)(off[o0+1] - off[o0]);
        dg1 = (float)(off[o1+1] - off[o1]);
      }
      #pragma unroll
      for (int ni=0;ni<4;ni++){
        int n = col0 + wc + ni*16 + col;
        ihcat[(size_t)row*512 + n] = f2bf_u(acc[mi][ni][rr] + dg0*b20[ni] + dg1*b21[ni]);
      }
    }
}

// ---- gruA: single combined GEMM -> u16 gates. grid (313,4): col0 in [0,512) ----
// ihcat[row][512]=[ib|h]; wcomb[c][1024]=[Wih_hi|Whh_hi|Wih_lo|Whh_lo]
__global__ __launch_bounds__(256) void gruA_kernel(
    const unsigned short* __restrict__ ihcat, const unsigned short* __restrict__ wcomb,
    const float* __restrict__ b_ih, const float* __restrict__ b_hh,
    unsigned short* __restrict__ rz_r, unsigned short* __restrict__ rz_z)
{
  __shared__ unsigned short lds[16384];
  const int row0 = blockIdx.x*128, col0 = blockIdx.y*128;
  const int t = threadIdx.x, w = t >> 6, lane = t & 63;
  const int q = lane >> 4, col = lane & 15;
  const int wr = (w & 1)*64, wc = (w >> 1)*64;

  floatx4 acc[4][4];
  #pragma unroll
  for (int mi=0;mi<4;mi++)
    #pragma unroll
    for (int ni=0;ni<4;ni++) acc[mi][ni] = (floatx4){0.f,0.f,0.f,0.f};

  mm128_core<1024,512,511>(ihcat + (size_t)row0*512, wcomb + (size_t)col0*1024, lds, acc);

  float bb[4];
  #pragma unroll
  for (int ni=0;ni<4;ni++){
    int n = col0 + wc + ni*16 + col;
    bb[ni] = b_ih[n] + b_hh[n];
  }
  unsigned short* dst = (col0 < 256) ? rz_r : rz_z;
  const int cbase = (col0 & 255) + wc;
  #pragma unroll
  for (int mi=0;mi<4;mi++)
    #pragma unroll
    for (int rr=0;rr<4;rr++){
      size_t row = (size_t)(row0 + wr + mi*16 + q*4 + rr);
      #pragma unroll
      for (int ni=0;ni<4;ni++){
        float v = sigmoidf_(acc[mi][ni][rr] + bb[ni]);
        dst[row*256 + cbase + ni*16 + col] = (unsigned short)(v*GATE_SCL + 0.5f);
      }
    }
}

// ---- gruB: n gate + GRU update. grid (313,2). Writes h_nxt + ihcat h-half ----
__global__ __launch_bounds__(256) void gruB_kernel(
    const unsigned short* __restrict__ ihcat, const unsigned short* __restrict__ h_hi,
    const unsigned short* __restrict__ h_lo,
    const unsigned short* __restrict__ wihk, const unsigned short* __restrict__ whhk,
    const float* __restrict__ b_ih, const float* __restrict__ b_hh,
    const unsigned short* __restrict__ rz_r, const unsigned short* __restrict__ rz_z,
    unsigned short* __restrict__ nh_hi, unsigned short* __restrict__ nh_lo,
    unsigned short* __restrict__ ihcat_w)
{
  __shared__ unsigned short lds[16384];
  const int row0 = blockIdx.x*128, dcol0 = blockIdx.y*128;   // n-gate W cols = 512 + dcol0
  const int t = threadIdx.x, w = t >> 6, lane = t & 63;
  const int q = lane >> 4, col = lane & 15;
  const int wr = (w & 1)*64, wc = (w >> 1)*64;

  floatx4 ai[4][4], ah[4][4];
  #pragma unroll
  for (int mi=0;mi<4;mi++)
    #pragma unroll
    for (int ni=0;ni<4;ni++){ ai[mi][ni] = (floatx4){0.f,0.f,0.f,0.f}; ah[mi][ni] = (floatx4){0.f,0.f,0.f,0.f}; }

  // ai over ib-half of ihcat (stride 512, wrap 255); ah over h (2-term wrap)
  mm128_core<512,512,255>(ihcat + (size_t)row0*512, wihk + (size_t)(512 + dcol0)*512, lds, ai);
  mm128_core<512,256,255>(h_hi  + (size_t)row0*256, whhk + (size_t)(512 + dcol0)*512, lds, ah);

  float bi[4], bh[4];
  #pragma unroll
  for (int ni=0;ni<4;ni++){
    int n = 512 + dcol0 + wc + ni*16 + col;
    bi[ni] = b_ih[n]; bh[ni] = b_hh[n];
  }
  #pragma unroll
  for (int mi=0;mi<4;mi++)
    #pragma unroll
    for (int rr=0;rr<4;rr++){
      size_t row = (size_t)(row0 + wr + mi*16 + q*4 + rr);
      #pragma unroll
      for (int ni=0;ni<4;ni++){
        int dn = dcol0 + wc + ni*16 + col;
        float rg = (float)rz_r[row*256 + dn] * GATE_INV;
        float zg = (float)rz_z[row*256 + dn] * GATE_INV;
        float ng = tanhf(ai[mi][ni][rr] + bi[ni] + rg*(ah[mi][ni][rr] + bh[ni]));
        size_t hidx = row*256 + dn;
        float hv = bfdec(h_hi[hidx]) + bfdec(h_lo[hidx]);
        float hnew = (1.f - zg)*ng + zg*hv;
        unsigned short hh = f2bf_u(hnew);
        nh_hi[hidx] = hh;
        nh_lo[hidx] = f2bf_u(hnew - bfdec(hh));
        ihcat_w[row*512 + 256 + dn] = hh;
      }
    }
}

__global__ void reduce_kernel(const unsigned short* __restrict__ hhi,
                              const unsigned short* __restrict__ hlo,
                              float* __restrict__ sbuf){
  int b  = blockIdx.x / 50;
  int s0 = (blockIdx.x % 50) * 200;
  int d  = threadIdx.x;
  size_t off = ((size_t)b*NNODES + s0)*DIM + d;
  float acc = 0.f;
  for (int i=0;i<200;i++){
    acc += bfdec(hhi[off]) + bfdec(hlo[off]);
    off += DIM;
  }
  atomicAdd(&sbuf[b*DIM + d], acc);
}

__global__ __launch_bounds__(320) void head_kernel(
    const float* __restrict__ sbuf, const float* __restrict__ pt,
    const float* __restrict__ fc1w, const float* __restrict__ fc1b,
    const float* __restrict__ fc2w, const float* __restrict__ fc2b,
    const float* __restrict__ fc3w, const float* __restrict__ fc3b,
    float* __restrict__ out)
{
  __shared__ float L[4][257];
  __shared__ float T1[4][80];
  __shared__ float T2[4][80];
  __shared__ float fmx[4];
  int t = threadIdx.x;
  if (t < 256){
    for (int b=0;b<4;b++){
      float v = sbuf[b*DIM + t];
      float ll = logf(v);
      if (ll != ll) ll = 0.f;
      ll = fmaxf(ll, 0.f);
      L[b][t] = ll;
    }
  }
  __syncthreads();
  int w = t >> 6, lane = t & 63;
  if (w < 4){
    float m = -INFINITY;
    for (int i=lane;i<256;i+=64){ float v = L[w][i]; if (v != INFINITY) m = fmaxf(m, v); }
    #pragma unroll
    for (int o=32;o>=1;o>>=1) m = fmaxf(m, __shfl_xor(m, o, 64));
    if (lane==0) fmx[w] = m;
  }
  __syncthreads();
  if (t < 256){
    for (int b=0;b<4;b++) if (L[b][t] == INFINITY) L[b][t] = fmx[b];
  }
  if (t < 4) L[t][256] = pt[t];
  __syncthreads();
  if (t < 320){
    int b = t/80, i = t%80;
    float a = fc1b[i];
    for (int k=0;k<257;k++) a += L[b][k]*fc1w[i*257+k];
    T1[b][i] = leakyf(a);
  }
  __syncthreads();
  if (t < 320){
    int b = t/80, i = t%80;
    float a = fc2b[i];
    for (int k=0;k<80;k++) a += T1[b][k]*fc2w[i*80+k];
    T2[b][i] = leakyf(a);
  }
  __syncthreads();
  if (t < 40){
    int b = t/10, i = t%10;
    float a = fc3b[i];
    for (int k=0;k<80;k++) a += T2[b][k]*fc3w[i*80+k];
    out[b*10+i] = a;
  }
}

extern "C" void kernel_launch(void* const* d_in, const int* in_sizes, int n_in,
                              void* d_out, int out_size, void* d_ws, size_t ws_size,
                              hipStream_t stream) {
  const float* nodes = (const float*)d_in[0];
  const int*   edges = (const int*)d_in[1];
  const float* pt    = (const float*)d_in[2];
  const float* w_ih  = (const float*)d_in[3];
  const float* w_hh  = (const float*)d_in[4];
  const float* b_ih  = (const float*)d_in[5];
  const float* b_hh  = (const float*)d_in[6];
  const float* ew1   = (const float*)d_in[7];
  const float* eb1   = (const float*)d_in[8];
  const float* ew2   = (const float*)d_in[9];
  const float* eb2   = (const float*)d_in[10];
  const float* fc1w  = (const float*)d_in[11];
  const float* fc1b  = (const float*)d_in[12];
  const float* fc2w  = (const float*)d_in[13];
  const float* fc2b  = (const float*)d_in[14];
  const float* fc3w  = (const float*)d_in[15];
  const float* fc3b  = (const float*)d_in[16];

  const size_t HN  = (size_t)BATCH*NNODES*DIM;    // 10,240,000 (real rows)
  const size_t HNP = (size_t)MROWS*DIM;
  char* p = (char*)d_ws;
  float* sbuf = (float*)p;                        p += BATCH*DIM*4;
  unsigned short* h_hi0 = (unsigned short*)p;     p += HNP*2;
  unsigned short* h_lo0 = (unsigned short*)p;     p += HNP*2;
  unsigned short* h_hi1 = (unsigned short*)p;     p += HNP*2;
  unsigned short* h_lo1 = (unsigned short*)p;     p += HNP*2;
  unsigned short* ihcat = (unsigned short*)p;     p += (size_t)MROWS*512*2;  // [ib | h]
  unsigned short* Zb   = (unsigned short*)p;      p += 2*HNP*2;              // z/agg scratch
  unsigned short* Sb   = (unsigned short*)p;      p += (size_t)MROWS*512*2;  // dead after w2128 -> rz
  unsigned short* w1cat= (unsigned short*)p;      p += 512*256*2;
  unsigned short* w2k  = (unsigned short*)p;      p += 256*1024*2;
  unsigned short* wihk = (unsigned short*)p;      p += 768*512*2;
  unsigned short* whhk = (unsigned short*)p;      p += 768*512*2;
  unsigned short* wcomb= (unsigned short*)p;      p += 512*1024*2;
  int* off  = (int*)p;                            p += NG*(NNODES+1)*4;
  int* cur  = (int*)p;                            p += NG*NNODES*4;
  int* ssrc = (int*)p;                            p += (size_t)NG*NEDGES*4;

  unsigned short* rz_r = (unsigned short*)Sb;              // MROWS*256 u16
  unsigned short* rz_z = rz_r + (size_t)MROWS*256;         // MROWS*256 u16 (fits Sb exactly)

  // weights
  w1cat_kernel<<<512,256,0,stream>>>(ew1, w1cat);
  w2k_kernel<<<1024,256,0,stream>>>(ew2, w2k);
  wk2_kernel<<<1536,256,0,stream>>>(w_ih, wihk);
  wk2_kernel<<<1536,256,0,stream>>>(w_hh, whhk);
  wcomb_kernel<<<2048,256,0,stream>>>(w_ih, w_hh, wcomb);

  // h0
  f2bf_split_kernel<<<(int)(HN/4/256),256,0,stream>>>(nodes, h_hi0, h_lo0, (int)(HN/4));
  ihinit_kernel<<<(int)(HN/256),256,0,stream>>>(h_hi0, ihcat);

  // counting sort (CSR) of edges by dst, per stream g
  hipMemsetAsync(cur, 0, NG*NNODES*sizeof(int), stream);
  hist_kernel<<<(NG*NEDGES)/256,256,0,stream>>>(edges, cur);
  scan_kernel<<<NG,256,0,stream>>>(cur, off);
  hipMemsetAsync(cur, 0, NG*NNODES*sizeof(int), stream);
  scatter_kernel<<<(NG*NEDGES)/256,256,0,stream>>>(edges, off, cur, ssrc);

  hipMemsetAsync(sbuf, 0, BATCH*DIM*sizeof(float), stream);

  unsigned short* hhi[2] = {h_hi0, h_hi1};
  unsigned short* hlo[2] = {h_lo0, h_lo1};

  for (int pass=0; pass<6; pass++){
    unsigned short* hc_hi = hhi[pass & 1];
    unsigned short* hc_lo = hlo[pass & 1];
    unsigned short* hn_hi = hhi[(pass+1) & 1];
    unsigned short* hn_lo = hlo[(pass+1) & 1];
    z128_kernel<<<dim3(MROWS/128,4),256,0,stream>>>(hc_hi, w1cat, eb1, Zb);
    aggregate_kernel<<<5000,256,0,stream>>>(Zb, ssrc, off, Sb);
    w2128_kernel<<<dim3(MROWS/128,2),256,0,stream>>>(Sb, w2k, eb2, off, ihcat);
    gruA_kernel<<<dim3(MROWS/128,4),256,0,stream>>>(ihcat, wcomb, b_ih, b_hh, rz_r, rz_z);
    gruB_kernel<<<dim3(MROWS/128,2),256,0,stream>>>(ihcat, hc_hi, hc_lo, wihk, whhk, b_ih, b_hh,
                                                    rz_r, rz_z, hn_hi, hn_lo, ihcat);
  }
  reduce_kernel<<<200,256,0,stream>>>(hhi[0], hlo[0], sbuf);
  head_kernel<<<1,320,0,stream>>>(sbuf, pt, fc1w,fc1b,fc2w,fc2b,fc3w,fc3b,(float*)d_out);
}

// Round 10
// 1785.886 us; speedup vs baseline: 23.7572x; 1.1526x over previous
//
#include <hip/hip_runtime.h>
#include <math.h>

#define NNODES 10000
#define NEDGES 160000
#define DIM    256
#define BATCH  4
#define NG     8           // BATCH * S streams
#define MROWS  40064       // 40000 padded to 626*64

typedef __attribute__((ext_vector_type(8))) __bf16 bf16x8;
typedef __attribute__((ext_vector_type(4))) float  floatx4;

__device__ __forceinline__ float leakyf(float x){ return x > 0.f ? x : 0.01f*x; }
__device__ __forceinline__ float fsig(float x){ return 1.f/(1.f + __expf(-x)); }
__device__ __forceinline__ float ftanh(float x){ return 1.f - 2.f/(1.f + __expf(2.f*x)); }
__device__ __forceinline__ unsigned short f2bf_u(float x){
  unsigned int u = __float_as_uint(x);
  u += 0x7fffu + ((u >> 16) & 1u);
  return (unsigned short)(u >> 16);
}
__device__ __forceinline__ float bfdec(unsigned short u){
  return __uint_as_float(((unsigned int)u) << 16);
}
#define GATE_SCL 65535.f
#define GATE_INV 1.5259021896696422e-5f

__device__ __forceinline__ void glds16(unsigned short* lds, const unsigned short* g){
  __builtin_amdgcn_global_load_lds(
      (const __attribute__((address_space(1))) void*)g,
      (__attribute__((address_space(3))) void*)lds, 16, 0, 0);
}

// h0: nodes -> ihcat0 h-half (hi) + h_lo
__global__ void ihinit_kernel(const float* __restrict__ nodes,
                              unsigned short* __restrict__ ihcat,
                              unsigned short* __restrict__ h_lo){
  int idx = blockIdx.x*256 + threadIdx.x;   // 40000*256
  int row = idx >> 8, d = idx & 255;
  float v = nodes[idx];
  unsigned short h = f2bf_u(v);
  ihcat[(size_t)row*512 + 256 + d] = h;
  h_lo[idx] = f2bf_u(v - bfdec(h));
}

// ---- weight prep ----
__global__ void w1cat_kernel(const float* __restrict__ ew1, unsigned short* __restrict__ o){
  int idx = blockIdx.x*256 + threadIdx.x;      // 512*256
  int n = idx >> 8, k = idx & 255;
  o[idx] = f2bf_u(ew1[(n>>8)*65536 + (n&255)*256 + k]);
}
__global__ void w2k_kernel(const float* __restrict__ ew2, unsigned short* __restrict__ o){
  int idx = blockIdx.x*256 + threadIdx.x;      // 256*1024
  int n = idx >> 10, kp = idx & 1023;
  int j = kp & 511, term = kp >> 9;
  int si = j >> 8, k = j & 255;
  float v = ew2[si*65536 + n*256 + k];
  unsigned short h = f2bf_u(v);
  o[idx] = term ? f2bf_u(v - bfdec(h)) : h;
}
// wk2[c][kp], kp in [0,512): K' = [hi | lo]
__global__ void wk2_kernel(const float* __restrict__ w, unsigned short* __restrict__ o){
  int idx = blockIdx.x*256 + threadIdx.x;      // 768*512
  int c = idx >> 9, kp = idx & 511;
  int k = kp & 255, term = kp >> 8;
  float v = w[c*256 + k];
  unsigned short h = f2bf_u(v);
  o[idx] = term ? f2bf_u(v - bfdec(h)) : h;
}
// wcomb[c][kp], c in [0,512) (r,z rows), kp: [Wih_hi|Whh_hi|Wih_lo|Whh_lo]
__global__ void wcomb_kernel(const float* __restrict__ wih, const float* __restrict__ whh,
                             unsigned short* __restrict__ o){
  int idx = blockIdx.x*256 + threadIdx.x;      // 512*1024
  int c = idx >> 10, kp = idx & 1023;
  int seg = kp >> 8, k = kp & 255;
  const float* w = (seg & 1) ? whh : wih;
  float v = w[c*256 + k];
  unsigned short h = f2bf_u(v);
  o[idx] = (seg >> 1) ? f2bf_u(v - bfdec(h)) : h;
}

// ---------------- edge sort (counting sort by dst, per stream g) ----------------
__global__ void hist_kernel(const int* __restrict__ edges, int* __restrict__ cnt){
  int idx = blockIdx.x*256 + threadIdx.x;
  if (idx < NG*NEDGES){
    int g = idx / NEDGES, e = idx - g*NEDGES;
    int d = edges[((size_t)g*NEDGES + e)*2];
    atomicAdd(&cnt[g*NNODES + d], 1);
  }
}

__global__ __launch_bounds__(256) void scan_kernel(const int* __restrict__ cnt, int* __restrict__ off){
  __shared__ int sc[256];
  int g = blockIdx.x, t = threadIdx.x;
  int base = 0;
  for (int c=0;c<40;c++){
    int i = c*256 + t;
    int v = (i < NNODES) ? cnt[g*NNODES + i] : 0;
    __syncthreads();
    sc[t] = v;
    __syncthreads();
    for (int o=1;o<256;o<<=1){
      int u = (t>=o) ? sc[t-o] : 0;
      __syncthreads();
      sc[t] += u;
      __syncthreads();
    }
    if (i < NNODES) off[g*(NNODES+1) + i] = base + sc[t] - v;
    base += sc[255];
  }
  if (t == 0) off[g*(NNODES+1) + NNODES] = base;
}

__global__ void scatter_kernel(const int* __restrict__ edges, const int* __restrict__ off,
                               int* __restrict__ cur, int* __restrict__ ssrc){
  int idx = blockIdx.x*256 + threadIdx.x;
  if (idx < NG*NEDGES){
    int g = idx / NEDGES, e = idx - g*NEDGES;
    const int* ep = &edges[((size_t)g*NEDGES + e)*2];
    int d = ep[0], s = ep[1];
    int pos = off[g*(NNODES+1) + d] + atomicAdd(&cur[g*NNODES + d], 1);
    ssrc[g*NEDGES + pos] = s;
  }
}

// ================= 64x128 LDS-staged MFMA core =================
// A: 64 rows, row r elem kp -> Ab[r*RS + (kp & KM)]; W: 128 rows stride KP.
// acc[4][2]: wave w owns cols [w*32, w*32+32).
template<int KP, int RS, int KM>
__device__ __forceinline__ void mm64_core(
    const unsigned short* __restrict__ Ab, const unsigned short* __restrict__ Wb,
    unsigned short* lds, floatx4 (&acc)[4][2])
{
  const int t = threadIdx.x;
  const int w = t >> 6, lane = t & 63;
  const int q = lane >> 4, col = lane & 15;
  const int wc = w*32;
  unsigned short* Al = lds;           // 64*64
  unsigned short* Bl = lds + 64*64;   // 128*64

  const int sr = t >> 3;
  const int sj = t & 7;
  const int sk = ((sj ^ (sr & 7)) * 8);

  for (int kb = 0; kb < KP; kb += 64){
    #pragma unroll
    for (int i=0;i<2;i++){
      int r = i*32 + sr;
      glds16(&Al[i*2048 + w*512], &Ab[(size_t)r*RS + ((kb + sk) & KM)]);
    }
    #pragma unroll
    for (int i=0;i<4;i++){
      int r = i*32 + sr;
      glds16(&Bl[i*2048 + w*512], &Wb[(size_t)r*KP + kb + sk]);
    }
    __syncthreads();
    #pragma unroll
    for (int ks2=0; ks2<2; ks2++){
      bf16x8 a[4], bf[2];
      #pragma unroll
      for (int mi=0;mi<4;mi++){
        int r = mi*16 + col;
        int j = (ks2*4 + q) ^ (r & 7);
        a[mi] = *(const bf16x8*)&Al[r*64 + j*8];
      }
      #pragma unroll
      for (int ni=0;ni<2;ni++){
        int r = wc + ni*16 + col;
        int j = (ks2*4 + q) ^ (r & 7);
        bf[ni] = *(const bf16x8*)&Bl[r*64 + j*8];
      }
      #pragma unroll
      for (int mi=0;mi<4;mi++)
        #pragma unroll
        for (int ni=0;ni<2;ni++)
          acc[mi][ni] = __builtin_amdgcn_mfma_f32_16x16x32_bf16(a[mi], bf[ni], acc[mi][ni], 0,0,0);
    }
    __syncthreads();
  }
}

#define MMPRO \
  const int t = threadIdx.x, w = t >> 6, lane = t & 63; \
  const int q = lane >> 4, col = lane & 15; \
  const int wc = w*32; \
  floatx4 acc[4][2]; \
  _Pragma("unroll") for (int mi=0;mi<4;mi++) _Pragma("unroll") for (int ni=0;ni<2;ni++) \
    acc[mi][ni] = (floatx4){0.f,0.f,0.f,0.f};

// ---- Z = leaky(h @ W1cat^T + b1): grid (626, 4); h read from ihcat h-half ----
__global__ __launch_bounds__(256) void z64_kernel(
    const unsigned short* __restrict__ ihcat, const unsigned short* __restrict__ w1cat,
    const float* __restrict__ eb1, unsigned short* __restrict__ Z)
{
  __shared__ unsigned short lds[12288];
  const int row0 = blockIdx.x*64, col0 = blockIdx.y*128;
  MMPRO
  mm64_core<256,512,255>(ihcat + (size_t)row0*512 + 256, w1cat + (size_t)col0*256, lds, acc);

  #pragma unroll
  for (int ni=0;ni<2;ni++){
    int n = col0 + wc + ni*16 + col;
    int si = n >> 8, cz = n & 255;
    float bb = eb1[si*256 + cz];
    unsigned short* zp = Z + (size_t)si*MROWS*256 + cz;
    #pragma unroll
    for (int mi=0;mi<4;mi++)
      #pragma unroll
      for (int rr=0;rr<4;rr++){
        int row = row0 + mi*16 + q*4 + rr;
        zp[(size_t)row*256] = f2bf_u(leakyf(acc[mi][ni][rr] + bb));
      }
  }
}

// ---- CSR aggregate, XCD-pinned: g = bid & 7; 4 nodes per wave ----
__global__ __launch_bounds__(256) void aggregate_kernel(
    const unsigned short* __restrict__ Z, const int* __restrict__ ssrc,
    const int* __restrict__ off, unsigned short* __restrict__ Sb)
{
  const int bid = blockIdx.x;          // 5000
  const int g = bid & 7;
  const int dgrp = bid >> 3;           // 0..624
  const int b = g >> 1, si = g & 1;
  const int w = threadIdx.x >> 6, lane = threadIdx.x & 63;
  const unsigned short* zb = Z + ((size_t)si*MROWS + b*10000)*256 + lane*4;
  const int* sp = ssrc + (size_t)g*NEDGES;
  const int* offg = off + g*(NNODES+1);

  #pragma unroll
  for (int i=0;i<4;i++){
    const int d = dgrp*16 + w*4 + i;
    const int j0 = offg[d], j1 = offg[d+1];
    float a0=0.f, a1=0.f, a2=0.f, a3=0.f;
    int j = j0;
    for (; j+4 <= j1; j+=4){
      int s0=sp[j], s1=sp[j+1], s2=sp[j+2], s3=sp[j+3];
      ushort4 u0 = *(const ushort4*)&zb[(size_t)s0*256];
      ushort4 u1 = *(const ushort4*)&zb[(size_t)s1*256];
      ushort4 u2 = *(const ushort4*)&zb[(size_t)s2*256];
      ushort4 u3 = *(const ushort4*)&zb[(size_t)s3*256];
      a0 += bfdec(u0.x)+bfdec(u1.x)+bfdec(u2.x)+bfdec(u3.x);
      a1 += bfdec(u0.y)+bfdec(u1.y)+bfdec(u2.y)+bfdec(u3.y);
      a2 += bfdec(u0.z)+bfdec(u1.z)+bfdec(u2.z)+bfdec(u3.z);
      a3 += bfdec(u0.w)+bfdec(u1.w)+bfdec(u2.w)+bfdec(u3.w);
    }
    for (; j < j1; j++){
      ushort4 u = *(const ushort4*)&zb[(size_t)sp[j]*256];
      a0 += bfdec(u.x); a1 += bfdec(u.y); a2 += bfdec(u.z); a3 += bfdec(u.w);
    }
    size_t so = (size_t)(b*10000 + d)*512 + si*256 + lane*4;
    ushort4 h;
    h.x = f2bf_u(a0); h.y = f2bf_u(a1); h.z = f2bf_u(a2); h.w = f2bf_u(a3);
    *(ushort4*)&Sb[so] = h;
  }
}

// ---- ihcat.ib = S @ W2k^T (2-term K'=1024) + deg.b2: grid (626, 2) ----
__global__ __launch_bounds__(256) void w264_kernel(
    const unsigned short* __restrict__ Sb, const unsigned short* __restrict__ w2k,
    const float* __restrict__ eb2, const int* __restrict__ off,
    unsigned short* __restrict__ ihcat)
{
  __shared__ unsigned short lds[12288];
  const int row0 = blockIdx.x*64, col0 = blockIdx.y*128;
  MMPRO
  mm64_core<1024,512,511>(Sb + (size_t)row0*512, w2k + (size_t)col0*1024, lds, acc);

  float b20[2], b21[2];
  #pragma unroll
  for (int ni=0;ni<2;ni++){
    int n = col0 + wc + ni*16 + col;
    b20[ni] = eb2[n];
    b21[ni] = eb2[256 + n];
  }
  #pragma unroll
  for (int mi=0;mi<4;mi++)
    #pragma unroll
    for (int rr=0;rr<4;rr++){
      int row = row0 + mi*16 + q*4 + rr;
      int b = row / 10000, d = row - b*10000;
      float dg0 = 0.f, dg1 = 0.f;
      if (row < 40000){
        int o0 = (b*2)*(NNODES+1) + d;
        int o1 = (b*2+1)*(NNODES+1) + d;
        dg0 = (float)(off[o0+1] - off[o0]);
        dg1 = (float)(off[o1+1] - off[o1]);
      }
      #pragma unroll
      for (int ni=0;ni<2;ni++){
        int n = col0 + wc + ni*16 + col;
        ihcat[(size_t)row*512 + n] = f2bf_u(acc[mi][ni][rr] + dg0*b20[ni] + dg1*b21[ni]);
      }
    }
}

// ---- gruA: combined r,z GEMM -> u16 gates. grid (626,4) ----
__global__ __launch_bounds__(256) void gruA_kernel(
    const unsigned short* __restrict__ ihcat, const unsigned short* __restrict__ wcomb,
    const float* __restrict__ b_ih, const float* __restrict__ b_hh,
    unsigned short* __restrict__ rz_r, unsigned short* __restrict__ rz_z)
{
  __shared__ unsigned short lds[12288];
  const int row0 = blockIdx.x*64, col0 = blockIdx.y*128;
  MMPRO
  mm64_core<1024,512,511>(ihcat + (size_t)row0*512, wcomb + (size_t)col0*1024, lds, acc);

  float bb[2];
  #pragma unroll
  for (int ni=0;ni<2;ni++){
    int n = col0 + wc + ni*16 + col;
    bb[ni] = b_ih[n] + b_hh[n];
  }
  unsigned short* dst = (col0 < 256) ? rz_r : rz_z;
  const int cbase = (col0 & 255) + wc;
  #pragma unroll
  for (int mi=0;mi<4;mi++)
    #pragma unroll
    for (int rr=0;rr<4;rr++){
      size_t row = (size_t)(row0 + mi*16 + q*4 + rr);
      #pragma unroll
      for (int ni=0;ni<2;ni++){
        float v = fsig(acc[mi][ni][rr] + bb[ni]);
        dst[row*256 + cbase + ni*16 + col] = (unsigned short)(v*GATE_SCL + 0.5f);
      }
    }
}

// ---- gruB: n gate + GRU update. grid (626,2). Writes ihcat_nxt h-half + h_lo ----
__global__ __launch_bounds__(256) void gruB_kernel(
    const unsigned short* __restrict__ ihcat, unsigned short* __restrict__ h_lo,
    const unsigned short* __restrict__ wihk, const unsigned short* __restrict__ whhk,
    const float* __restrict__ b_ih, const float* __restrict__ b_hh,
    const unsigned short* __restrict__ rz_r, const unsigned short* __restrict__ rz_z,
    unsigned short* __restrict__ ihcat_nxt)
{
  __shared__ unsigned short lds[12288];
  const int row0 = blockIdx.x*64, dcol0 = blockIdx.y*128;   // n-gate W cols = 512 + dcol0
  const int t = threadIdx.x, w = t >> 6, lane = t & 63;
  const int q = lane >> 4, col = lane & 15;
  const int wc = w*32;

  floatx4 ai[4][2], ah[4][2];
  #pragma unroll
  for (int mi=0;mi<4;mi++)
    #pragma unroll
    for (int ni=0;ni<2;ni++){ ai[mi][ni] = (floatx4){0.f,0.f,0.f,0.f}; ah[mi][ni] = (floatx4){0.f,0.f,0.f,0.f}; }

  mm64_core<512,512,255>(ihcat + (size_t)row0*512,       wihk + (size_t)(512 + dcol0)*512, lds, ai);
  mm64_core<512,512,255>(ihcat + (size_t)row0*512 + 256, whhk + (size_t)(512 + dcol0)*512, lds, ah);

  float bi[2], bh[2];
  #pragma unroll
  for (int ni=0;ni<2;ni++){
    int n = 512 + dcol0 + wc + ni*16 + col;
    bi[ni] = b_ih[n]; bh[ni] = b_hh[n];
  }
  #pragma unroll
  for (int mi=0;mi<4;mi++)
    #pragma unroll
    for (int rr=0;rr<4;rr++){
      size_t row = (size_t)(row0 + mi*16 + q*4 + rr);
      #pragma unroll
      for (int ni=0;ni<2;ni++){
        int dn = dcol0 + wc + ni*16 + col;
        float rg = (float)rz_r[row*256 + dn] * GATE_INV;
        float zg = (float)rz_z[row*256 + dn] * GATE_INV;
        float ng = ftanh(ai[mi][ni][rr] + bi[ni] + rg*(ah[mi][ni][rr] + bh[ni]));
        float hv = bfdec(ihcat[row*512 + 256 + dn]) + bfdec(h_lo[row*256 + dn]);
        float hnew = (1.f - zg)*ng + zg*hv;
        unsigned short hh = f2bf_u(hnew);
        ihcat_nxt[row*512 + 256 + dn] = hh;
        h_lo[row*256 + dn] = f2bf_u(hnew - bfdec(hh));
      }
    }
}

__global__ void reduce_kernel(const unsigned short* __restrict__ ihcat,
                              const unsigned short* __restrict__ h_lo,
                              float* __restrict__ sbuf){
  int b  = blockIdx.x / 50;
  int s0 = (blockIdx.x % 50) * 200;
  int d  = threadIdx.x;
  size_t row = (size_t)b*NNODES + s0;
  float acc = 0.f;
  for (int i=0;i<200;i++){
    acc += bfdec(ihcat[(row+i)*512 + 256 + d]) + bfdec(h_lo[(row+i)*256 + d]);
  }
  atomicAdd(&sbuf[b*DIM + d], acc);
}

__global__ __launch_bounds__(320) void head_kernel(
    const float* __restrict__ sbuf, const float* __restrict__ pt,
    const float* __restrict__ fc1w, const float* __restrict__ fc1b,
    const float* __restrict__ fc2w, const float* __restrict__ fc2b,
    const float* __restrict__ fc3w, const float* __restrict__ fc3b,
    float* __restrict__ out)
{
  __shared__ float L[4][257];
  __shared__ float T1[4][80];
  __shared__ float T2[4][80];
  __shared__ float fmx[4];
  int t = threadIdx.x;
  if (t < 256){
    for (int b=0;b<4;b++){
      float v = sbuf[b*DIM + t];
      float ll = logf(v);
      if (ll != ll) ll = 0.f;
      ll = fmaxf(ll, 0.f);
      L[b][t] = ll;
    }
  }
  __syncthreads();
  int w = t >> 6, lane = t & 63;
  if (w < 4){
    float m = -INFINITY;
    for (int i=lane;i<256;i+=64){ float v = L[w][i]; if (v != INFINITY) m = fmaxf(m, v); }
    #pragma unroll
    for (int o=32;o>=1;o>>=1) m = fmaxf(m, __shfl_xor(m, o, 64));
    if (lane==0) fmx[w] = m;
  }
  __syncthreads();
  if (t < 256){
    for (int b=0;b<4;b++) if (L[b][t] == INFINITY) L[b][t] = fmx[b];
  }
  if (t < 4) L[t][256] = pt[t];
  __syncthreads();
  if (t < 320){
    int b = t/80, i = t%80;
    float a = fc1b[i];
    for (int k=0;k<257;k++) a += L[b][k]*fc1w[i*257+k];
    T1[b][i] = leakyf(a);
  }
  __syncthreads();
  if (t < 320){
    int b = t/80, i = t%80;
    float a = fc2b[i];
    for (int k=0;k<80;k++) a += T1[b][k]*fc2w[i*80+k];
    T2[b][i] = leakyf(a);
  }
  __syncthreads();
  if (t < 40){
    int b = t/10, i = t%10;
    float a = fc3b[i];
    for (int k=0;k<80;k++) a += T2[b][k]*fc3w[i*80+k];
    out[b*10+i] = a;
  }
}

extern "C" void kernel_launch(void* const* d_in, const int* in_sizes, int n_in,
                              void* d_out, int out_size, void* d_ws, size_t ws_size,
                              hipStream_t stream) {
  const float* nodes = (const float*)d_in[0];
  const int*   edges = (const int*)d_in[1];
  const float* pt    = (const float*)d_in[2];
  const float* w_ih  = (const float*)d_in[3];
  const float* w_hh  = (const float*)d_in[4];
  const float* b_ih  = (const float*)d_in[5];
  const float* b_hh  = (const float*)d_in[6];
  const float* ew1   = (const float*)d_in[7];
  const float* eb1   = (const float*)d_in[8];
  const float* ew2   = (const float*)d_in[9];
  const float* eb2   = (const float*)d_in[10];
  const float* fc1w  = (const float*)d_in[11];
  const float* fc1b  = (const float*)d_in[12];
  const float* fc2w  = (const float*)d_in[13];
  const float* fc2b  = (const float*)d_in[14];
  const float* fc3w  = (const float*)d_in[15];
  const float* fc3b  = (const float*)d_in[16];

  const size_t HN  = (size_t)BATCH*NNODES*DIM;    // 10,240,000 (real rows)
  const size_t HNP = (size_t)MROWS*DIM;
  char* p = (char*)d_ws;
  float* sbuf = (float*)p;                        p += BATCH*DIM*4;
  unsigned short* ihcat0 = (unsigned short*)p;    p += (size_t)MROWS*512*2;  // [ib | h]
  unsigned short* ihcat1 = (unsigned short*)p;    p += (size_t)MROWS*512*2;
  unsigned short* h_lo   = (unsigned short*)p;    p += HNP*2;
  unsigned short* Zb   = (unsigned short*)p;      p += 2*HNP*2;              // z/agg scratch
  unsigned short* Sb   = (unsigned short*)p;      p += (size_t)MROWS*512*2;  // dead after w2 -> rz
  unsigned short* w1cat= (unsigned short*)p;      p += 512*256*2;
  unsigned short* w2k  = (unsigned short*)p;      p += 256*1024*2;
  unsigned short* wihk = (unsigned short*)p;      p += 768*512*2;
  unsigned short* whhk = (unsigned short*)p;      p += 768*512*2;
  unsigned short* wcomb= (unsigned short*)p;      p += 512*1024*2;
  int* off  = (int*)p;                            p += NG*(NNODES+1)*4;
  int* cur  = (int*)p;                            p += NG*NNODES*4;
  int* ssrc = (int*)p;                            p += (size_t)NG*NEDGES*4;

  unsigned short* rz_r = (unsigned short*)Sb;              // MROWS*256 u16
  unsigned short* rz_z = rz_r + (size_t)MROWS*256;         // MROWS*256 u16

  // weights
  w1cat_kernel<<<512,256,0,stream>>>(ew1, w1cat);
  w2k_kernel<<<1024,256,0,stream>>>(ew2, w2k);
  wk2_kernel<<<1536,256,0,stream>>>(w_ih, wihk);
  wk2_kernel<<<1536,256,0,stream>>>(w_hh, whhk);
  wcomb_kernel<<<2048,256,0,stream>>>(w_ih, w_hh, wcomb);

  // h0
  ihinit_kernel<<<(int)(HN/256),256,0,stream>>>(nodes, ihcat0, h_lo);

  // counting sort (CSR) of edges by dst, per stream g
  hipMemsetAsync(cur, 0, NG*NNODES*sizeof(int), stream);
  hist_kernel<<<(NG*NEDGES)/256,256,0,stream>>>(edges, cur);
  scan_kernel<<<NG,256,0,stream>>>(cur, off);
  hipMemsetAsync(cur, 0, NG*NNODES*sizeof(int), stream);
  scatter_kernel<<<(NG*NEDGES)/256,256,0,stream>>>(edges, off, cur, ssrc);

  hipMemsetAsync(sbuf, 0, BATCH*DIM*sizeof(float), stream);

  unsigned short* ih[2] = {ihcat0, ihcat1};

  for (int pass=0; pass<6; pass++){
    unsigned short* curb = ih[pass & 1];
    unsigned short* nxtb = ih[(pass+1) & 1];
    z64_kernel<<<dim3(MROWS/64,4),256,0,stream>>>(curb, w1cat, eb1, Zb);
    aggregate_kernel<<<5000,256,0,stream>>>(Zb, ssrc, off, Sb);
    w264_kernel<<<dim3(MROWS/64,2),256,0,stream>>>(Sb, w2k, eb2, off, curb);
    gruA_kernel<<<dim3(MROWS/64,4),256,0,stream>>>(curb, wcomb, b_ih, b_hh, rz_r, rz_z);
    gruB_kernel<<<dim3(MROWS/64,2),256,0,stream>>>(curb, h_lo, wihk, whhk, b_ih, b_hh,
                                                   rz_r, rz_z, nxtb);
  }
  reduce_kernel<<<200,256,0,stream>>>(ih[0], h_lo, sbuf);
  head_kernel<<<1,320,0,stream>>>(sbuf, pt, fc1w,fc1b,fc2w,fc2b,fc3w,fc3b,(float*)d_out);
}